// Round 1
// baseline (5057.744 us; speedup 1.0000x reference)
//
#include <hip/hip_runtime.h>
#include <stdint.h>

#define DI __device__ __forceinline__

static constexpr int B_   = 512;
static constexpr int CIN_ = 200;
static constexpr int M_   = 128;
static constexpr int N3_  = 381;

DI float bf2f(uint32_t u) { union { uint32_t i; float f; } v; v.i = u << 16; return v.f; }
DI uint16_t f2bf(float f) {
  union { float f; uint32_t i; } v; v.f = f;
  uint32_t x = v.i;
  return (uint16_t)((x + 0x7fffu + ((x >> 16) & 1u)) >> 16);
}
DI void unpack8(uint4 u, float* v) {
  v[0] = bf2f(u.x & 0xffffu); v[1] = bf2f(u.x >> 16);
  v[2] = bf2f(u.y & 0xffffu); v[3] = bf2f(u.y >> 16);
  v[4] = bf2f(u.z & 0xffffu); v[5] = bf2f(u.z >> 16);
  v[6] = bf2f(u.w & 0xffffu); v[7] = bf2f(u.w >> 16);
}

// ---------------- dtype probe: flag=0 -> bf16 inputs, flag=1 -> f32 inputs ----
__global__ void probe_kernel(const uint16_t* __restrict__ trees, int* __restrict__ flag) {
  __shared__ int cnt;
  if (threadIdx.x == 0) cnt = 0;
  __syncthreads();
  int local = 0;
  #pragma unroll
  for (int q = 0; q < 2; q++) {
    uint16_t u = trees[threadIdx.x * 2 + q];
    int ex = (u >> 7) & 0xff;
    if (ex >= 110 && ex <= 133) local++;   // |x| in ~[2^-17, 2^6]
  }
  atomicAdd(&cnt, local);
  __syncthreads();
  if (threadIdx.x == 0) *flag = (cnt >= 450) ? 0 : 1;
}

// ---------------- conversions -------------------------------------------------
__global__ void cvt_to_bf16(const void* __restrict__ src, uint16_t* __restrict__ dst,
                            int n, const int* __restrict__ flag) {
  int isf32 = *flag;
  int stride = gridDim.x * blockDim.x;
  for (int i = blockIdx.x * blockDim.x + threadIdx.x; i < n; i += stride) {
    dst[i] = isf32 ? f2bf(((const float*)src)[i]) : ((const uint16_t*)src)[i];
  }
}

struct CvtJob { const void* src; float* dst; int n; };
struct CvtJobs { CvtJob j[16]; };
__global__ void cvt_many(CvtJobs jobs, const int* __restrict__ flag) {
  int isf32 = *flag;
  int stride = gridDim.x * blockDim.x;
  for (int k = 0; k < 16; k++) {
    const void* src = jobs.j[k].src;
    float* dst = jobs.j[k].dst;
    int n = jobs.j[k].n;
    for (int i = blockIdx.x * blockDim.x + threadIdx.x; i < n; i += stride)
      dst[i] = isf32 ? ((const float*)src)[i] : bf2f(((const uint16_t*)src)[i]);
  }
}

__global__ void zero_kernel(float* __restrict__ p, int n) {
  int stride = gridDim.x * blockDim.x;
  for (int i = blockIdx.x * blockDim.x + threadIdx.x; i < n; i += stride) p[i] = 0.f;
}

// ---------------- tree_conv ---------------------------------------------------
// y[b,o,j] = sum_{c,k} x[b,c,idx[b,3(j-1)+k]] * w[o,c,k] + bias[o]   (j>=1)
// y[b,o,0] = 0.   Optional per-batch (sum,sumsq) accumulation incl. bias.
__global__ __launch_bounds__(256)
void conv_kernel(const uint16_t* __restrict__ xin, int C,
                 const float* __restrict__ w, const float* __restrict__ bias,
                 const int* __restrict__ idxg,
                 uint16_t* __restrict__ yout, int O,
                 float* __restrict__ statsAcc) {
  __shared__ __align__(16) float sX[32][128];
  __shared__ __align__(16) float sW[96 * 32];   // [e=(c2*3+k)][oo]
  __shared__ int sIdx[N3_ + 3];
  __shared__ float2 sRed[256];

  const int b     = blockIdx.y;
  const int obase = blockIdx.x * 32;
  const int tx    = threadIdx.x;
  const int ogr   = tx >> 5;       // 0..7
  const int jgr   = tx & 31;       // 0..31
  const int olocal = ogr * 4;
  const int jbase  = jgr * 4;

  for (int t = tx; t < N3_; t += 256) sIdx[t] = idxg[b * N3_ + t];
  __syncthreads();

  int g[4][3];
  #pragma unroll
  for (int q = 0; q < 4; q++) {
    int col = jbase + q;
    if (col == 0) { g[q][0] = 0; g[q][1] = 0; g[q][2] = 0; }
    else {
      int n = col - 1;
      g[q][0] = sIdx[3 * n]; g[q][1] = sIdx[3 * n + 1]; g[q][2] = sIdx[3 * n + 2];
    }
  }

  float acc[4][4];
  #pragma unroll
  for (int oo = 0; oo < 4; oo++)
    #pragma unroll
    for (int q = 0; q < 4; q++) acc[oo][q] = 0.f;

  const int wrow = tx >> 3;   // 0..31
  const int wr   = tx & 7;

  for (int cc = 0; cc < C; cc += 32) {
    int cur = min(32, C - cc);
    __syncthreads();
    // stage x rows (bf16 -> f32)
    {
      const uint32_t* x32 = (const uint32_t*)(xin + (size_t)(b * C + cc) * 128);
      int npair = cur * 64;
      for (int t = tx; t < npair; t += 256) {
        uint32_t u = x32[t];
        int c2 = t >> 6, col = (t & 63) << 1;
        sX[c2][col]     = bf2f(u & 0xffffu);
        sX[c2][col + 1] = bf2f(u >> 16);
      }
    }
    // stage w tile: sW[e][oo] = w[(obase+oo)*C*3 + cc*3 + e]
    {
      int rowlen = cur * 3;
      const float* wbase = w + (size_t)(obase + wrow) * (C * 3) + cc * 3;
      for (int e = wr; e < rowlen; e += 8) sW[e * 32 + wrow] = wbase[e];
    }
    __syncthreads();

    for (int c2 = 0; c2 < cur; c2++) {
      float xv[4][3];
      #pragma unroll
      for (int q = 0; q < 4; q++) {
        xv[q][0] = sX[c2][g[q][0]];
        xv[q][1] = sX[c2][g[q][1]];
        xv[q][2] = sX[c2][g[q][2]];
      }
      const float* wp = &sW[c2 * 96];
      float4 w0 = *(const float4*)(wp + olocal);
      float4 w1 = *(const float4*)(wp + 32 + olocal);
      float4 w2 = *(const float4*)(wp + 64 + olocal);
      float a0[4] = {w0.x, w0.y, w0.z, w0.w};
      float a1[4] = {w1.x, w1.y, w1.z, w1.w};
      float a2[4] = {w2.x, w2.y, w2.z, w2.w};
      #pragma unroll
      for (int oo = 0; oo < 4; oo++) {
        #pragma unroll
        for (int q = 0; q < 4; q++) {
          acc[oo][q] = fmaf(a0[oo], xv[q][0], acc[oo][q]);
          acc[oo][q] = fmaf(a1[oo], xv[q][1], acc[oo][q]);
          acc[oo][q] = fmaf(a2[oo], xv[q][2], acc[oo][q]);
        }
      }
    }
  }

  float s1 = 0.f, s2 = 0.f;
  #pragma unroll
  for (int oo = 0; oo < 4; oo++) {
    float bo = bias[obase + olocal + oo];
    uint16_t pk[4];
    #pragma unroll
    for (int q = 0; q < 4; q++) {
      float v = (jbase + q == 0) ? 0.f : (acc[oo][q] + bo);
      s1 += v; s2 += v * v;
      pk[q] = f2bf(v);
    }
    uint2 st;
    st.x = (uint32_t)pk[0] | ((uint32_t)pk[1] << 16);
    st.y = (uint32_t)pk[2] | ((uint32_t)pk[3] << 16);
    *(uint2*)(yout + (size_t)(b * O + obase + olocal + oo) * 128 + jbase) = st;
  }

  if (statsAcc) {
    sRed[tx] = make_float2(s1, s2);
    __syncthreads();
    for (int s = 128; s > 0; s >>= 1) {
      if (tx < s) { sRed[tx].x += sRed[tx + s].x; sRed[tx].y += sRed[tx + s].y; }
      __syncthreads();
    }
    if (tx == 0) {
      atomicAdd(&statsAcc[b * 2],     sRed[0].x);
      atomicAdd(&statsAcc[b * 2 + 1], sRed[0].y);
    }
  }
}

__global__ void stats_finalize(const float* __restrict__ acc, float* __restrict__ ms,
                               int count, int nb) {
  int b = blockIdx.x * blockDim.x + threadIdx.x;
  if (b < nb) {
    float s = acc[b * 2], ss = acc[b * 2 + 1];
    float n = (float)count;
    float mean = s / n;
    float var = (ss - s * s / n) / (n - 1.0f);
    var = fmaxf(var, 0.f);
    float scale = 1.0f / (sqrtf(var) + 1e-5f);
    ms[b * 2] = mean; ms[b * 2 + 1] = scale;
  }
}

__global__ __launch_bounds__(256)
void ln_relu_kernel(uint16_t* __restrict__ y, const float* __restrict__ ms,
                    int perB8, int total8) {
  int stride = gridDim.x * blockDim.x;
  for (int i = blockIdx.x * blockDim.x + threadIdx.x; i < total8; i += stride) {
    int b = i / perB8;
    float mean = ms[b * 2], scale = ms[b * 2 + 1];
    uint4 u = ((const uint4*)y)[i];
    float v[8]; unpack8(u, v);
    uint32_t r[4];
    #pragma unroll
    for (int k = 0; k < 4; k++) {
      float a  = fmaxf((v[2 * k]     - mean) * scale, 0.f);
      float bb = fmaxf((v[2 * k + 1] - mean) * scale, 0.f);
      r[k] = (uint32_t)f2bf(a) | ((uint32_t)f2bf(bb) << 16);
    }
    ((uint4*)y)[i] = make_uint4(r[0], r[1], r[2], r[3]);
  }
}

// ---------------- gate + softmax + pool + combined ---------------------------
__global__ __launch_bounds__(256)
void gate_kernel(const uint16_t* __restrict__ emb,     // (B,256,128) bf16
                 const float* __restrict__ gw1,        // (128,256)
                 const float* __restrict__ gb1,        // (128)
                 const float* __restrict__ gw2,        // (128)
                 const float* __restrict__ gb2,        // (1)
                 float* __restrict__ combined,         // (B,512) f32
                 void* __restrict__ dout, const int* __restrict__ flag) {
  __shared__ __align__(16) float sG[128][65];
  __shared__ float sRed2[128];
  __shared__ float sAttn[128];
  __shared__ float sG2[128];

  const int b = blockIdx.x;
  const int tx = threadIdx.x;
  const int hg = tx >> 4, mg = tx & 15;
  const int h0 = hg * 8, m0 = mg * 8;
  const uint16_t* embB = emb + (size_t)b * 256 * 128;

  float acc[8][8];
  #pragma unroll
  for (int i = 0; i < 8; i++)
    #pragma unroll
    for (int j = 0; j < 8; j++) acc[i][j] = 0.f;

  for (int fc = 0; fc < 256; fc += 64) {
    __syncthreads();
    for (int t = tx; t < 128 * 64; t += 256) {
      int h = t >> 6, f2 = t & 63;
      sG[h][f2] = gw1[h * 256 + fc + f2];
    }
    __syncthreads();
    for (int f2 = 0; f2 < 64; f2++) {
      uint4 u = *(const uint4*)(embB + (fc + f2) * 128 + m0);
      float ev[8]; unpack8(u, ev);
      #pragma unroll
      for (int i = 0; i < 8; i++) {
        float gv = sG[h0 + i][f2];
        #pragma unroll
        for (int j = 0; j < 8; j++) acc[i][j] = fmaf(gv, ev[j], acc[i][j]);
      }
    }
  }

  __syncthreads();
  if (tx < 128) sG2[tx] = 0.f;
  __syncthreads();

  float p[8];
  #pragma unroll
  for (int j = 0; j < 8; j++) p[j] = 0.f;
  #pragma unroll
  for (int i = 0; i < 8; i++) {
    float bb = gb1[h0 + i];
    float wv = gw2[h0 + i];
    #pragma unroll
    for (int j = 0; j < 8; j++) {
      float c = fmaxf(acc[i][j] + bb, 0.f);
      p[j] = fmaf(c, wv, p[j]);
    }
  }
  #pragma unroll
  for (int j = 0; j < 8; j++) atomicAdd(&sG2[m0 + j], p[j]);
  __syncthreads();

  float v = 0.f, e = 0.f;
  if (tx < 128) { v = sG2[tx] + gb2[0]; sRed2[tx] = v; }
  __syncthreads();
  for (int s = 64; s > 0; s >>= 1) {
    if (tx < s) sRed2[tx] = fmaxf(sRed2[tx], sRed2[tx + s]);
    __syncthreads();
  }
  float mx = sRed2[0];
  __syncthreads();
  if (tx < 128) { e = expf(v - mx); sRed2[tx] = e; }
  __syncthreads();
  for (int s = 64; s > 0; s >>= 1) {
    if (tx < s) sRed2[tx] += sRed2[tx + s];
    __syncthreads();
  }
  float denom = sRed2[0];
  __syncthreads();
  if (tx < 128) sAttn[tx] = e / denom;
  __syncthreads();

  // pool + root; tx == feature f (0..255)
  const uint16_t* row = embB + (size_t)tx * 128;
  float pool = 0.f;
  for (int mc = 0; mc < 128; mc += 8) {
    uint4 u = *(const uint4*)(row + mc);
    float ev[8]; unpack8(u, ev);
    #pragma unroll
    for (int jj = 0; jj < 8; jj++) pool = fmaf(sAttn[mc + jj], ev[jj], pool);
  }
  float root = bf2f(row[1]);

  combined[b * 512 + tx]       = root;
  combined[b * 512 + 256 + tx] = pool;
  if (*flag == 0) {
    uint16_t* o = ((uint16_t*)dout) + 512;
    o[b * 512 + tx]       = f2bf(root);
    o[b * 512 + 256 + tx] = f2bf(pool);
  } else {
    float* o = ((float*)dout) + 512;
    o[b * 512 + tx]       = root;
    o[b * 512 + 256 + tx] = pool;
  }
}

// ---------------- MLP head ---------------------------------------------------
__global__ __launch_bounds__(128)
void head_kernel(const float* __restrict__ combined,
                 const float* __restrict__ rw1, const float* __restrict__ rb1,
                 const float* __restrict__ rw2, const float* __restrict__ rb2,
                 const float* __restrict__ rw3, const float* __restrict__ rb3,
                 void* __restrict__ dout, const int* __restrict__ flag) {
  __shared__ __align__(16) float sC[512];
  __shared__ __align__(16) float sH1[128];
  __shared__ float sH2[64];
  const int b = blockIdx.x, tx = threadIdx.x;

  for (int i = tx; i < 512; i += 128) sC[i] = combined[b * 512 + i];
  __syncthreads();

  float a = rb1[tx];
  const float4* wr = (const float4*)(rw1 + (size_t)tx * 512);
  for (int i = 0; i < 128; i++) {
    float4 w4 = wr[i];
    float4 c4 = *(const float4*)&sC[i * 4];
    a = fmaf(w4.x, c4.x, a); a = fmaf(w4.y, c4.y, a);
    a = fmaf(w4.z, c4.z, a); a = fmaf(w4.w, c4.w, a);
  }
  sH1[tx] = fmaxf(a, 0.f);
  __syncthreads();

  if (tx < 64) {
    float a2 = rb2[tx];
    const float4* wr2 = (const float4*)(rw2 + (size_t)tx * 128);
    for (int i = 0; i < 32; i++) {
      float4 w4 = wr2[i];
      float4 h4 = *(const float4*)&sH1[i * 4];
      a2 = fmaf(w4.x, h4.x, a2); a2 = fmaf(w4.y, h4.y, a2);
      a2 = fmaf(w4.z, h4.z, a2); a2 = fmaf(w4.w, h4.w, a2);
    }
    sH2[tx] = fmaxf(a2, 0.f);
  }
  __syncthreads();

  if (tx < 64) {
    float pv = sH2[tx] * rw3[tx];
    for (int off = 32; off > 0; off >>= 1) pv += __shfl_down(pv, off);
    if (tx == 0) {
      float o = pv + rb3[0];
      if (*flag == 0) ((uint16_t*)dout)[b] = f2bf(o);
      else            ((float*)dout)[b]    = o;
    }
  }
}

// ---------------- launch -----------------------------------------------------
extern "C" void kernel_launch(void* const* d_in, const int* in_sizes, int n_in,
                              void* d_out, int out_size, void* d_ws, size_t ws_size,
                              hipStream_t stream) {
  const void* trees   = d_in[0];
  const int*  indexes = (const int*)d_in[1];
  const void* w1 = d_in[2];  const void* b1 = d_in[3];
  const void* w2 = d_in[4];  const void* b2 = d_in[5];
  const void* w3 = d_in[6];  const void* b3 = d_in[7];
  const void* gw1 = d_in[8]; const void* gb1 = d_in[9];
  const void* gw2 = d_in[10]; const void* gb2 = d_in[11];
  const void* rw1 = d_in[12]; const void* rb1 = d_in[13];
  const void* rw2 = d_in[14]; const void* rb2 = d_in[15];
  const void* rw3 = d_in[16]; const void* rb3 = d_in[17];

  char* ws = (char*)d_ws;
  size_t off = 0;
  auto alloc = [&](size_t bytes) -> char* {
    char* p = ws + off;
    off += (bytes + 255) & ~(size_t)255;
    return p;
  };

  int*   flagp    = (int*)alloc(256);
  float* statsAcc = (float*)alloc(4 * B_ * sizeof(float));  // acc1 | acc2
  float* statsMS  = (float*)alloc(4 * B_ * sizeof(float));  // ms1 | ms2
  uint16_t* treesBF = (uint16_t*)alloc((size_t)B_ * CIN_ * M_ * 2);
  uint16_t* x1   = (uint16_t*)alloc((size_t)B_ * 512 * 128 * 2);
  uint16_t* x2   = (uint16_t*)alloc((size_t)B_ * 512 * 128 * 2);
  uint16_t* embB = (uint16_t*)alloc((size_t)B_ * 256 * 128 * 2);
  float* w1f = (float*)alloc((size_t)512 * 600 * 4);
  float* b1f = (float*)alloc(512 * 4);
  float* w2f = (float*)alloc((size_t)512 * 1536 * 4);
  float* b2f = (float*)alloc(512 * 4);
  float* w3f = (float*)alloc((size_t)256 * 1536 * 4);
  float* b3f = (float*)alloc(256 * 4);
  float* gw1f = (float*)alloc(128 * 256 * 4);
  float* gb1f = (float*)alloc(128 * 4);
  float* gw2f = (float*)alloc(128 * 4);
  float* gb2f = (float*)alloc(4);
  float* rw1f = (float*)alloc(128 * 512 * 4);
  float* rb1f = (float*)alloc(128 * 4);
  float* rw2f = (float*)alloc(64 * 128 * 4);
  float* rb2f = (float*)alloc(64 * 4);
  float* rw3f = (float*)alloc(64 * 4);
  float* rb3f = (float*)alloc(4);
  float* combined = (float*)alloc((size_t)B_ * 512 * 4);

  probe_kernel<<<1, 256, 0, stream>>>((const uint16_t*)trees, flagp);
  zero_kernel<<<2, 256, 0, stream>>>(statsAcc, 4 * B_);
  cvt_to_bf16<<<4096, 256, 0, stream>>>(trees, treesBF, B_ * CIN_ * M_, flagp);

  CvtJobs jobs;
  int ji = 0;
  auto addjob = [&](const void* s, float* d, int n) { jobs.j[ji].src = s; jobs.j[ji].dst = d; jobs.j[ji].n = n; ji++; };
  addjob(w1, w1f, 512 * 600);  addjob(b1, b1f, 512);
  addjob(w2, w2f, 512 * 1536); addjob(b2, b2f, 512);
  addjob(w3, w3f, 256 * 1536); addjob(b3, b3f, 256);
  addjob(gw1, gw1f, 128 * 256); addjob(gb1, gb1f, 128);
  addjob(gw2, gw2f, 128);       addjob(gb2, gb2f, 1);
  addjob(rw1, rw1f, 128 * 512); addjob(rb1, rb1f, 128);
  addjob(rw2, rw2f, 64 * 128);  addjob(rb2, rb2f, 64);
  addjob(rw3, rw3f, 64);        addjob(rb3, rb3f, 1);
  cvt_many<<<256, 256, 0, stream>>>(jobs, flagp);

  // layer 1
  conv_kernel<<<dim3(16, B_), 256, 0, stream>>>(treesBF, CIN_, w1f, b1f, indexes, x1, 512, statsAcc);
  stats_finalize<<<2, 256, 0, stream>>>(statsAcc, statsMS, 512 * 128, B_);
  ln_relu_kernel<<<2048, 256, 0, stream>>>(x1, statsMS, 512 * 128 / 8, B_ * 512 * 128 / 8);
  // layer 2
  conv_kernel<<<dim3(16, B_), 256, 0, stream>>>(x1, 512, w2f, b2f, indexes, x2, 512, statsAcc + 2 * B_);
  stats_finalize<<<2, 256, 0, stream>>>(statsAcc + 2 * B_, statsMS + 2 * B_, 512 * 128, B_);
  ln_relu_kernel<<<2048, 256, 0, stream>>>(x2, statsMS + 2 * B_, 512 * 128 / 8, B_ * 512 * 128 / 8);
  // layer 3 (no LN)
  conv_kernel<<<dim3(8, B_), 256, 0, stream>>>(x2, 512, w3f, b3f, indexes, embB, 256, nullptr);
  // gate + pool + combined
  gate_kernel<<<B_, 256, 0, stream>>>(embB, gw1f, gb1f, gw2f, gb2f, combined, d_out, flagp);
  // head
  head_kernel<<<B_, 128, 0, stream>>>(combined, rw1f, rb1f, rw2f, rb2f, rw3f, rb3f, d_out, flagp);

  (void)in_sizes; (void)n_in; (void)out_size; (void)ws_size;
}

// Round 2
// 912.600 us; speedup vs baseline: 5.5421x; 5.5421x over previous
//
#include <hip/hip_runtime.h>
#include <stdint.h>

#define DI __device__ __forceinline__

static constexpr int B_   = 512;
static constexpr int CIN_ = 200;
static constexpr int N3_  = 381;
static constexpr int HB_  = 256;   // batch half

typedef short bf16x8 __attribute__((ext_vector_type(8)));
typedef float f32x4  __attribute__((ext_vector_type(4)));

DI float bf2f(uint32_t u) { union { uint32_t i; float f; } v; v.i = u << 16; return v.f; }
DI uint16_t f2bf(float f) {
  union { float f; uint32_t i; } v; v.f = f;
  uint32_t x = v.i;
  return (uint16_t)((x + 0x7fffu + ((x >> 16) & 1u)) >> 16);
}
DI void unpack8(uint4 u, float* v) {
  v[0] = bf2f(u.x & 0xffffu); v[1] = bf2f(u.x >> 16);
  v[2] = bf2f(u.y & 0xffffu); v[3] = bf2f(u.y >> 16);
  v[4] = bf2f(u.z & 0xffffu); v[5] = bf2f(u.z >> 16);
  v[6] = bf2f(u.w & 0xffffu); v[7] = bf2f(u.w >> 16);
}

DI void ldsload16(const uint16_t* g, uint16_t* l) {
  __builtin_amdgcn_global_load_lds((const __attribute__((address_space(1))) void*)g,
                                   (__attribute__((address_space(3))) void*)l,
                                   16, 0, 0);
}

// ---------------- dtype probe: flag=0 -> bf16 inputs, flag=1 -> f32 ----------
__global__ void probe_kernel(const uint16_t* __restrict__ trees, int* __restrict__ flag) {
  __shared__ int cnt;
  if (threadIdx.x == 0) cnt = 0;
  __syncthreads();
  int local = 0;
  #pragma unroll
  for (int q = 0; q < 2; q++) {
    uint16_t u = trees[threadIdx.x * 2 + q];
    int ex = (u >> 7) & 0xff;
    if (ex >= 110 && ex <= 133) local++;
  }
  atomicAdd(&cnt, local);
  __syncthreads();
  if (threadIdx.x == 0) *flag = (cnt >= 450) ? 0 : 1;
}

// ---------------- conversions ------------------------------------------------
__global__ void cvt_to_bf16(const void* __restrict__ src, uint16_t* __restrict__ dst,
                            int n, const int* __restrict__ flag) {
  int isf32 = *flag;
  int stride = gridDim.x * blockDim.x;
  for (int i = blockIdx.x * blockDim.x + threadIdx.x; i < n; i += stride)
    dst[i] = isf32 ? f2bf(((const float*)src)[i]) : ((const uint16_t*)src)[i];
}

// W [O][3C] (f32 or bf16) -> bf16 [O][Kpad], zero-padded on K
__global__ void wcvt_kernel(const void* __restrict__ src, uint16_t* __restrict__ dst,
                            int O, int threeC, int Kpad, const int* __restrict__ flag) {
  int isf32 = *flag;
  int n = O * Kpad;
  int stride = gridDim.x * blockDim.x;
  for (int i = blockIdx.x * blockDim.x + threadIdx.x; i < n; i += stride) {
    int o = i / Kpad, e = i - o * Kpad;
    uint16_t v = 0;
    if (e < threeC) {
      int s = o * threeC + e;
      v = isf32 ? f2bf(((const float*)src)[s]) : ((const uint16_t*)src)[s];
    }
    dst[i] = v;
  }
}

struct CvtJob { const void* src; float* dst; int n; };
struct CvtJobs { CvtJob j[13]; };
__global__ void cvt_many(CvtJobs jobs, const int* __restrict__ flag) {
  int isf32 = *flag;
  int stride = gridDim.x * blockDim.x;
  for (int k = 0; k < 13; k++) {
    const void* src = jobs.j[k].src;
    float* dst = jobs.j[k].dst;
    int n = jobs.j[k].n;
    for (int i = blockIdx.x * blockDim.x + threadIdx.x; i < n; i += stride)
      dst[i] = isf32 ? ((const float*)src)[i] : bf2f(((const uint16_t*)src)[i]);
  }
}

__global__ void zero_kernel(float* __restrict__ p, int n) {
  int stride = gridDim.x * blockDim.x;
  for (int i = blockIdx.x * blockDim.x + threadIdx.x; i < n; i += stride) p[i] = 0.f;
}

// ---------------- gather (+ optional LN/ReLU) --------------------------------
// Builds Xg[b][j][e] = LN(x[b][e/3][ idx[b, 3(j-1)+e%3] ]), j=0 row -> 0.
// grid (ceil(C/32), HB). Xg rows are Kpad elements, K-contiguous.
__global__ __launch_bounds__(256)
void gather_kernel(const uint16_t* __restrict__ x, const int* __restrict__ idxg,
                   uint16_t* __restrict__ Xg, int C, int Kpad,
                   const float* __restrict__ ms) {
  __shared__ int sIdx[384];
  __shared__ uint16_t sX[32][128];
  __shared__ uint16_t sT[128][96];

  const int b  = blockIdx.y;
  const int c0 = blockIdx.x * 32;
  const int cn = min(32, C - c0);
  const int ecnt = cn * 3;
  const int tx = threadIdx.x;

  float mean = 0.f, scale = 0.f;
  const bool doLN = (ms != nullptr);
  if (doLN) { mean = ms[b * 2]; scale = ms[b * 2 + 1]; }

  for (int t = tx; t < N3_; t += 256) sIdx[t] = idxg[(size_t)b * N3_ + t];

  // load rows, optional LN+ReLU
  {
    const uint32_t* xr = (const uint32_t*)(x + ((size_t)b * C + c0) * 128);
    int nU = cn * 64;
    for (int t = tx; t < nU; t += 256) {
      uint32_t u = xr[t];
      if (doLN) {
        float a  = fmaxf((bf2f(u & 0xffffu) - mean) * scale, 0.f);
        float bb = fmaxf((bf2f(u >> 16)     - mean) * scale, 0.f);
        u = (uint32_t)f2bf(a) | ((uint32_t)f2bf(bb) << 16);
      }
      int c = t >> 6, p = t & 63;
      ((uint32_t*)&sX[c][0])[p] = u;
    }
  }
  __syncthreads();

  // transpose-gather into sT[j][e']
  {
    int total = 128 * ecnt;
    for (int p = tx; p < total; p += 256) {
      int j = p / ecnt, e = p - j * ecnt;
      uint16_t v = 0;
      if (j != 0) {
        int c = e / 3, k = e - c * 3;
        v = sX[c][sIdx[3 * (j - 1) + k]];
      }
      sT[j][e] = v;
    }
  }
  __syncthreads();

  // write out coalesced
  {
    int nU = ecnt >> 1;
    int total = 128 * nU;
    size_t ebase = (size_t)c0 * 3;
    for (int p = tx; p < total; p += 256) {
      int j = p / nU, u = p - j * nU;
      ((uint32_t*)(Xg + ((size_t)b * 128 + j) * Kpad + ebase))[u] =
          ((const uint32_t*)&sT[j][0])[u];
    }
  }
}

// ---------------- MFMA GEMM: Y[b] = W(O x Kpad) * Xg[b]^T --------------------
// grid (HB, O/128), block 256 (4 waves, 2x2 wave grid, 64x64 per wave)
__global__ __launch_bounds__(256)
void gemm_kernel(const uint16_t* __restrict__ A,    // [O][Kpad] bf16
                 const uint16_t* __restrict__ Xg,   // [HB][128][Kpad] bf16
                 const float* __restrict__ bias,    // [O]
                 uint16_t* __restrict__ Y,          // [HB][O][128] (pre-offset)
                 int O, int Kpad,
                 float* __restrict__ statsAcc) {    // pre-offset, or null
  __shared__ __align__(16) uint16_t sA[128 * 64];
  __shared__ __align__(16) uint16_t sB[128 * 64];
  __shared__ float sBias[128];
  __shared__ float2 sRed[256];

  const int b     = blockIdx.x;
  const int obase = blockIdx.y * 128;
  const int tx    = threadIdx.x;
  const int wave  = tx >> 6, lane = tx & 63;
  const int wm    = wave & 1, wn = wave >> 1;

  if (tx < 128) sBias[tx] = bias[obase + tx];

  const uint16_t* Abase = A + (size_t)obase * Kpad;
  const uint16_t* Bbase = Xg + (size_t)b * 128 * Kpad;

  const int srow = lane >> 3;      // 0..7
  const int schk = lane & 7;       // 0..7

  f32x4 zero4 = {0.f, 0.f, 0.f, 0.f};
  f32x4 acc[4][4];
  #pragma unroll
  for (int i = 0; i < 4; i++)
    #pragma unroll
    for (int j = 0; j < 4; j++) acc[i][j] = zero4;

  const int lm = lane & 15;
  const int kg = lane >> 4;        // 0..3

  for (int kc = 0; kc < Kpad; kc += 64) {
    __syncthreads();
    #pragma unroll
    for (int i = 0; i < 4; i++) {
      int r  = wave * 8 + i * 32 + srow;
      int ca = schk ^ (r & 7);
      ldsload16(Abase + (size_t)r * Kpad + kc + ca * 8, &sA[(wave * 8 + i * 32) * 64]);
      ldsload16(Bbase + (size_t)r * Kpad + kc + ca * 8, &sB[(wave * 8 + i * 32) * 64]);
    }
    __syncthreads();
    #pragma unroll
    for (int s = 0; s < 2; s++) {
      bf16x8 av[4], bv[4];
      #pragma unroll
      for (int f = 0; f < 4; f++) {
        int rm = wm * 64 + f * 16 + lm;
        int cm = (s * 4 + kg) ^ (rm & 7);
        av[f] = *(const bf16x8*)&sA[rm * 64 + cm * 8];
        int rn = wn * 64 + f * 16 + lm;
        int cn = (s * 4 + kg) ^ (rn & 7);
        bv[f] = *(const bf16x8*)&sB[rn * 64 + cn * 8];
      }
      #pragma unroll
      for (int fm = 0; fm < 4; fm++)
        #pragma unroll
        for (int fn = 0; fn < 4; fn++)
          acc[fm][fn] = __builtin_amdgcn_mfma_f32_16x16x32_bf16(av[fm], bv[fn], acc[fm][fn], 0, 0, 0);
    }
  }

  // epilogue: bias, zero col0, stats, store bf16
  float s1 = 0.f, s2 = 0.f;
  const int rb = (lane >> 4) * 4;
  #pragma unroll
  for (int fm = 0; fm < 4; fm++) {
    #pragma unroll
    for (int r = 0; r < 4; r++) {
      int olocal = wm * 64 + fm * 16 + rb + r;
      int o = obase + olocal;
      float bo = sBias[olocal];
      #pragma unroll
      for (int fn = 0; fn < 4; fn++) {
        int j = wn * 64 + fn * 16 + lm;
        float v = acc[fm][fn][r] + bo;
        if (j == 0) v = 0.f;
        s1 += v; s2 += v * v;
        Y[((size_t)b * O + o) * 128 + j] = f2bf(v);
      }
    }
  }

  if (statsAcc) {
    sRed[tx] = make_float2(s1, s2);
    __syncthreads();
    for (int s = 128; s > 0; s >>= 1) {
      if (tx < s) { sRed[tx].x += sRed[tx + s].x; sRed[tx].y += sRed[tx + s].y; }
      __syncthreads();
    }
    if (tx == 0) {
      atomicAdd(&statsAcc[b * 2],     sRed[0].x);
      atomicAdd(&statsAcc[b * 2 + 1], sRed[0].y);
    }
  }
}

__global__ void stats_finalize(const float* __restrict__ acc, float* __restrict__ ms,
                               int count, int nb) {
  int b = blockIdx.x * blockDim.x + threadIdx.x;
  if (b < nb) {
    float s = acc[b * 2], ss = acc[b * 2 + 1];
    float n = (float)count;
    float mean = s / n;
    float var = (ss - s * s / n) / (n - 1.0f);
    var = fmaxf(var, 0.f);
    ms[b * 2] = mean;
    ms[b * 2 + 1] = 1.0f / (sqrtf(var) + 1e-5f);
  }
}

// ---------------- gate + softmax + pool + combined ---------------------------
__global__ __launch_bounds__(256)
void gate_kernel(const uint16_t* __restrict__ emb,     // (B,256,128) bf16
                 const float* __restrict__ gw1, const float* __restrict__ gb1,
                 const float* __restrict__ gw2, const float* __restrict__ gb2,
                 float* __restrict__ combined,
                 void* __restrict__ dout, const int* __restrict__ flag) {
  __shared__ __align__(16) float sG[128][65];
  __shared__ float sRed2[128];
  __shared__ float sAttn[128];
  __shared__ float sG2[128];

  const int b = blockIdx.x;
  const int tx = threadIdx.x;
  const int hg = tx >> 4, mg = tx & 15;
  const int h0 = hg * 8, m0 = mg * 8;
  const uint16_t* embB = emb + (size_t)b * 256 * 128;

  float acc[8][8];
  #pragma unroll
  for (int i = 0; i < 8; i++)
    #pragma unroll
    for (int j = 0; j < 8; j++) acc[i][j] = 0.f;

  for (int fc = 0; fc < 256; fc += 64) {
    __syncthreads();
    for (int t = tx; t < 128 * 64; t += 256) {
      int h = t >> 6, f2 = t & 63;
      sG[h][f2] = gw1[h * 256 + fc + f2];
    }
    __syncthreads();
    for (int f2 = 0; f2 < 64; f2++) {
      uint4 u = *(const uint4*)(embB + (size_t)(fc + f2) * 128 + m0);
      float ev[8]; unpack8(u, ev);
      #pragma unroll
      for (int i = 0; i < 8; i++) {
        float gv = sG[h0 + i][f2];
        #pragma unroll
        for (int j = 0; j < 8; j++) acc[i][j] = fmaf(gv, ev[j], acc[i][j]);
      }
    }
  }

  __syncthreads();
  if (tx < 128) sG2[tx] = 0.f;
  __syncthreads();

  float p[8];
  #pragma unroll
  for (int j = 0; j < 8; j++) p[j] = 0.f;
  #pragma unroll
  for (int i = 0; i < 8; i++) {
    float bb = gb1[h0 + i];
    float wv = gw2[h0 + i];
    #pragma unroll
    for (int j = 0; j < 8; j++) {
      float c = fmaxf(acc[i][j] + bb, 0.f);
      p[j] = fmaf(c, wv, p[j]);
    }
  }
  #pragma unroll
  for (int j = 0; j < 8; j++) atomicAdd(&sG2[m0 + j], p[j]);
  __syncthreads();

  float v = 0.f, e = 0.f;
  if (tx < 128) { v = sG2[tx] + gb2[0]; sRed2[tx] = v; }
  __syncthreads();
  for (int s = 64; s > 0; s >>= 1) {
    if (tx < s) sRed2[tx] = fmaxf(sRed2[tx], sRed2[tx + s]);
    __syncthreads();
  }
  float mx = sRed2[0];
  __syncthreads();
  if (tx < 128) { e = expf(v - mx); sRed2[tx] = e; }
  __syncthreads();
  for (int s = 64; s > 0; s >>= 1) {
    if (tx < s) sRed2[tx] += sRed2[tx + s];
    __syncthreads();
  }
  float denom = sRed2[0];
  __syncthreads();
  if (tx < 128) sAttn[tx] = e / denom;
  __syncthreads();

  const uint16_t* row = embB + (size_t)tx * 128;
  float pool = 0.f;
  for (int mc = 0; mc < 128; mc += 8) {
    uint4 u = *(const uint4*)(row + mc);
    float ev[8]; unpack8(u, ev);
    #pragma unroll
    for (int jj = 0; jj < 8; jj++) pool = fmaf(sAttn[mc + jj], ev[jj], pool);
  }
  float root = bf2f(row[1]);

  combined[b * 512 + tx]       = root;
  combined[b * 512 + 256 + tx] = pool;
  if (*flag == 0) {
    uint16_t* o = ((uint16_t*)dout) + 512;
    o[b * 512 + tx]       = f2bf(root);
    o[b * 512 + 256 + tx] = f2bf(pool);
  } else {
    float* o = ((float*)dout) + 512;
    o[b * 512 + tx]       = root;
    o[b * 512 + 256 + tx] = pool;
  }
}

// ---------------- MLP head ---------------------------------------------------
__global__ __launch_bounds__(128)
void head_kernel(const float* __restrict__ combined,
                 const float* __restrict__ rw1, const float* __restrict__ rb1,
                 const float* __restrict__ rw2, const float* __restrict__ rb2,
                 const float* __restrict__ rw3, const float* __restrict__ rb3,
                 void* __restrict__ dout, const int* __restrict__ flag) {
  __shared__ __align__(16) float sC[512];
  __shared__ __align__(16) float sH1[128];
  __shared__ float sH2[64];
  const int b = blockIdx.x, tx = threadIdx.x;

  for (int i = tx; i < 512; i += 128) sC[i] = combined[b * 512 + i];
  __syncthreads();

  float a = rb1[tx];
  const float4* wr = (const float4*)(rw1 + (size_t)tx * 512);
  for (int i = 0; i < 128; i++) {
    float4 w4 = wr[i];
    float4 c4 = *(const float4*)&sC[i * 4];
    a = fmaf(w4.x, c4.x, a); a = fmaf(w4.y, c4.y, a);
    a = fmaf(w4.z, c4.z, a); a = fmaf(w4.w, c4.w, a);
  }
  sH1[tx] = fmaxf(a, 0.f);
  __syncthreads();

  if (tx < 64) {
    float a2 = rb2[tx];
    const float4* wr2 = (const float4*)(rw2 + (size_t)tx * 128);
    for (int i = 0; i < 32; i++) {
      float4 w4 = wr2[i];
      float4 h4 = *(const float4*)&sH1[i * 4];
      a2 = fmaf(w4.x, h4.x, a2); a2 = fmaf(w4.y, h4.y, a2);
      a2 = fmaf(w4.z, h4.z, a2); a2 = fmaf(w4.w, h4.w, a2);
    }
    sH2[tx] = fmaxf(a2, 0.f);
  }
  __syncthreads();

  if (tx < 64) {
    float pv = sH2[tx] * rw3[tx];
    for (int off = 32; off > 0; off >>= 1) pv += __shfl_down(pv, off);
    if (tx == 0) {
      float o = pv + rb3[0];
      if (*flag == 0) ((uint16_t*)dout)[b] = f2bf(o);
      else            ((float*)dout)[b]    = o;
    }
  }
}

// ---------------- launch -----------------------------------------------------
extern "C" void kernel_launch(void* const* d_in, const int* in_sizes, int n_in,
                              void* d_out, int out_size, void* d_ws, size_t ws_size,
                              hipStream_t stream) {
  const void* trees   = d_in[0];
  const int*  indexes = (const int*)d_in[1];
  const void* w1 = d_in[2];  const void* b1 = d_in[3];
  const void* w2 = d_in[4];  const void* b2 = d_in[5];
  const void* w3 = d_in[6];  const void* b3 = d_in[7];
  const void* gw1 = d_in[8]; const void* gb1 = d_in[9];
  const void* gw2 = d_in[10]; const void* gb2 = d_in[11];
  const void* rw1 = d_in[12]; const void* rb1 = d_in[13];
  const void* rw2 = d_in[14]; const void* rb2 = d_in[15];
  const void* rw3 = d_in[16]; const void* rb3 = d_in[17];

  char* ws = (char*)d_ws;
  size_t off = 0;
  auto alloc = [&](size_t bytes) -> char* {
    char* p = ws + off;
    off += (bytes + 255) & ~(size_t)255;
    return p;
  };

  int*   flagp    = (int*)alloc(256);
  float* statsAcc = (float*)alloc(4 * B_ * sizeof(float));
  float* statsMS  = (float*)alloc(4 * B_ * sizeof(float));
  float* b1f = (float*)alloc(512 * 4);
  float* b2f = (float*)alloc(512 * 4);
  float* b3f = (float*)alloc(256 * 4);
  float* gw1f = (float*)alloc(128 * 256 * 4);
  float* gb1f = (float*)alloc(128 * 4);
  float* gw2f = (float*)alloc(128 * 4);
  float* gb2f = (float*)alloc(4);
  float* rw1f = (float*)alloc(128 * 512 * 4);
  float* rb1f = (float*)alloc(128 * 4);
  float* rw2f = (float*)alloc(64 * 128 * 4);
  float* rb2f = (float*)alloc(64 * 4);
  float* rw3f = (float*)alloc(64 * 4);
  float* rb3f = (float*)alloc(4);
  float* combined = (float*)alloc((size_t)B_ * 512 * 4);
  uint16_t* W1b = (uint16_t*)alloc((size_t)512 * 640 * 2);
  uint16_t* W2b = (uint16_t*)alloc((size_t)512 * 1536 * 2);
  uint16_t* W3b = (uint16_t*)alloc((size_t)256 * 1536 * 2);
  uint16_t* ybuf = (uint16_t*)alloc((size_t)B_ * 512 * 128 * 2);             // 64 MiB
  uint16_t* Xg   = (uint16_t*)alloc((size_t)HB_ * 128 * 1536 * 2);           // 96 MiB
  uint16_t* treesBF = ybuf + ((size_t)16 * 1024 * 1024);                     // ybuf+32MiB

  probe_kernel<<<1, 256, 0, stream>>>((const uint16_t*)trees, flagp);
  zero_kernel<<<2, 256, 0, stream>>>(statsAcc, 4 * B_);
  cvt_to_bf16<<<2048, 256, 0, stream>>>(trees, treesBF, B_ * CIN_ * 128, flagp);
  wcvt_kernel<<<1024, 256, 0, stream>>>(w1, W1b, 512, 600, 640, flagp);
  wcvt_kernel<<<2048, 256, 0, stream>>>(w2, W2b, 512, 1536, 1536, flagp);
  wcvt_kernel<<<1024, 256, 0, stream>>>(w3, W3b, 256, 1536, 1536, flagp);

  CvtJobs jobs;
  int ji = 0;
  auto addjob = [&](const void* s, float* d, int n) { jobs.j[ji].src = s; jobs.j[ji].dst = d; jobs.j[ji].n = n; ji++; };
  addjob(b1, b1f, 512); addjob(b2, b2f, 512); addjob(b3, b3f, 256);
  addjob(gw1, gw1f, 128 * 256); addjob(gb1, gb1f, 128);
  addjob(gw2, gw2f, 128);       addjob(gb2, gb2f, 1);
  addjob(rw1, rw1f, 128 * 512); addjob(rb1, rb1f, 128);
  addjob(rw2, rw2f, 64 * 128);  addjob(rb2, rb2f, 64);
  addjob(rw3, rw3f, 64);        addjob(rb3, rb3f, 1);
  cvt_many<<<256, 256, 0, stream>>>(jobs, flagp);

  // ---- layer 1 (K=600 -> 640) ----
  for (int h = 0; h < 2; h++) {
    int b0 = h * HB_;
    gather_kernel<<<dim3(7, HB_), 256, 0, stream>>>(
        treesBF + (size_t)b0 * CIN_ * 128, indexes + (size_t)b0 * N3_, Xg, CIN_, 640, nullptr);
    gemm_kernel<<<dim3(HB_, 4), 256, 0, stream>>>(
        W1b, Xg, b1f, ybuf + (size_t)b0 * 512 * 128, 512, 640, statsAcc + b0 * 2);
  }
  stats_finalize<<<2, 256, 0, stream>>>(statsAcc, statsMS, 512 * 128, B_);

  // ---- layer 2 (K=1536) ----
  for (int h = 0; h < 2; h++) {
    int b0 = h * HB_;
    gather_kernel<<<dim3(16, HB_), 256, 0, stream>>>(
        ybuf + (size_t)b0 * 512 * 128, indexes + (size_t)b0 * N3_, Xg, 512, 1536,
        statsMS + b0 * 2);
    gemm_kernel<<<dim3(HB_, 4), 256, 0, stream>>>(
        W2b, Xg, b2f, ybuf + (size_t)b0 * 512 * 128, 512, 1536, statsAcc + 2 * B_ + b0 * 2);
  }
  stats_finalize<<<2, 256, 0, stream>>>(statsAcc + 2 * B_, statsMS + 2 * B_, 512 * 128, B_);

  // ---- layer 3 (K=1536, O=256, no LN after) ----
  for (int h = 0; h < 2; h++) {
    int b0 = h * HB_;
    gather_kernel<<<dim3(16, HB_), 256, 0, stream>>>(
        ybuf + (size_t)b0 * 512 * 128, indexes + (size_t)b0 * N3_, Xg, 512, 1536,
        statsMS + 2 * B_ + b0 * 2);
    gemm_kernel<<<dim3(HB_, 2), 256, 0, stream>>>(
        W3b, Xg, b3f, ybuf + (size_t)b0 * 256 * 128, 256, 1536, nullptr);
  }

  // ---- gate + pool + head ----
  gate_kernel<<<B_, 256, 0, stream>>>(ybuf, gw1f, gb1f, gw2f, gb2f, combined, d_out, flagp);
  head_kernel<<<B_, 128, 0, stream>>>(combined, rw1f, rb1f, rw2f, rb2f, rw3f, rb3f, d_out, flagp);

  (void)in_sizes; (void)n_in; (void)out_size; (void)ws_size;
}

// Round 3
// 842.324 us; speedup vs baseline: 6.0045x; 1.0834x over previous
//
#include <hip/hip_runtime.h>
#include <stdint.h>

#define DI __device__ __forceinline__

static constexpr int B_   = 512;
static constexpr int CIN_ = 200;
static constexpr int N3_  = 381;
static constexpr int HB_  = 256;   // batch half

typedef short bf16x8 __attribute__((ext_vector_type(8)));
typedef float f32x4  __attribute__((ext_vector_type(4)));

DI float bf2f(uint32_t u) { union { uint32_t i; float f; } v; v.i = u << 16; return v.f; }
DI uint16_t f2bf(float f) {
  union { float f; uint32_t i; } v; v.f = f;
  uint32_t x = v.i;
  return (uint16_t)((x + 0x7fffu + ((x >> 16) & 1u)) >> 16);
}
DI void unpack8(uint4 u, float* v) {
  v[0] = bf2f(u.x & 0xffffu); v[1] = bf2f(u.x >> 16);
  v[2] = bf2f(u.y & 0xffffu); v[3] = bf2f(u.y >> 16);
  v[4] = bf2f(u.z & 0xffffu); v[5] = bf2f(u.z >> 16);
  v[6] = bf2f(u.w & 0xffffu); v[7] = bf2f(u.w >> 16);
}

DI void ldsload16(const uint16_t* g, uint16_t* l) {
  __builtin_amdgcn_global_load_lds((const __attribute__((address_space(1))) void*)g,
                                   (__attribute__((address_space(3))) void*)l,
                                   16, 0, 0);
}

// ---------------- dtype probe: flag=0 -> bf16 inputs, flag=1 -> f32 ----------
__global__ void probe_kernel(const uint16_t* __restrict__ trees, int* __restrict__ flag) {
  __shared__ int cnt;
  if (threadIdx.x == 0) cnt = 0;
  __syncthreads();
  int local = 0;
  #pragma unroll
  for (int q = 0; q < 2; q++) {
    uint16_t u = trees[threadIdx.x * 2 + q];
    int ex = (u >> 7) & 0xff;
    if (ex >= 110 && ex <= 133) local++;
  }
  atomicAdd(&cnt, local);
  __syncthreads();
  if (threadIdx.x == 0) *flag = (cnt >= 450) ? 0 : 1;
}

// ---------------- conversions ------------------------------------------------
__global__ void cvt_to_bf16(const void* __restrict__ src, uint16_t* __restrict__ dst,
                            int n, const int* __restrict__ flag) {
  int isf32 = *flag;
  int stride = gridDim.x * blockDim.x;
  for (int i = blockIdx.x * blockDim.x + threadIdx.x; i < n; i += stride)
    dst[i] = isf32 ? f2bf(((const float*)src)[i]) : ((const uint16_t*)src)[i];
}

// W [O][threeC] (f32 or bf16) -> bf16 [O][Kpad], zero-padded on K
__global__ void wcvt_kernel(const void* __restrict__ src, uint16_t* __restrict__ dst,
                            int O, int threeC, int Kpad, const int* __restrict__ flag) {
  int isf32 = *flag;
  int n = O * Kpad;
  int stride = gridDim.x * blockDim.x;
  for (int i = blockIdx.x * blockDim.x + threadIdx.x; i < n; i += stride) {
    int o = i / Kpad, e = i - o * Kpad;
    uint16_t v = 0;
    if (e < threeC) {
      int s = o * threeC + e;
      v = isf32 ? f2bf(((const float*)src)[s]) : ((const uint16_t*)src)[s];
    }
    dst[i] = v;
  }
}

struct CvtJob { const void* src; float* dst; int n; };
struct CvtJobs { CvtJob j[13]; };
__global__ void cvt_many(CvtJobs jobs, int nj, const int* __restrict__ flag) {
  int isf32 = *flag;
  int stride = gridDim.x * blockDim.x;
  for (int k = 0; k < nj; k++) {
    const void* src = jobs.j[k].src;
    float* dst = jobs.j[k].dst;
    int n = jobs.j[k].n;
    for (int i = blockIdx.x * blockDim.x + threadIdx.x; i < n; i += stride)
      dst[i] = isf32 ? ((const float*)src)[i] : bf2f(((const uint16_t*)src)[i]);
  }
}

__global__ void zero_kernel(float* __restrict__ p, int n) {
  int stride = gridDim.x * blockDim.x;
  for (int i = blockIdx.x * blockDim.x + threadIdx.x; i < n; i += stride) p[i] = 0.f;
}

// ---------------- gather (+ optional LN/ReLU) --------------------------------
// Builds Xg[b][j][e] = LN(x[b][e/3][ idx[b, 3(j-1)+e%3] ]), j=0 row -> 0.
__global__ __launch_bounds__(256)
void gather_kernel(const uint16_t* __restrict__ x, const int* __restrict__ idxg,
                   uint16_t* __restrict__ Xg, int C, int Kpad,
                   const float* __restrict__ ms) {
  __shared__ int sIdx[384];
  __shared__ uint16_t sX[32][130];   // +2 pad: row stride 65 dwords, gcd(65,32)=1
  __shared__ uint16_t sT[128][96];

  const int b  = blockIdx.y;
  const int c0 = blockIdx.x * 32;
  const int cn = min(32, C - c0);
  const int ecnt = cn * 3;
  const int tx = threadIdx.x;

  float mean = 0.f, scale = 0.f;
  const bool doLN = (ms != nullptr);
  if (doLN) { mean = ms[b * 2]; scale = ms[b * 2 + 1]; }

  for (int t = tx; t < N3_; t += 256) sIdx[t] = idxg[(size_t)b * N3_ + t];

  {
    const uint32_t* xr = (const uint32_t*)(x + ((size_t)b * C + c0) * 128);
    int nU = cn * 64;
    for (int t = tx; t < nU; t += 256) {
      uint32_t u = xr[t];
      if (doLN) {
        float a  = fmaxf((bf2f(u & 0xffffu) - mean) * scale, 0.f);
        float bb = fmaxf((bf2f(u >> 16)     - mean) * scale, 0.f);
        u = (uint32_t)f2bf(a) | ((uint32_t)f2bf(bb) << 16);
      }
      int c = t >> 6, p = t & 63;
      ((uint32_t*)&sX[c][0])[p] = u;
    }
  }
  __syncthreads();

  {
    int total = 128 * ecnt;
    for (int p = tx; p < total; p += 256) {
      int j = p / ecnt, e = p - j * ecnt;
      uint16_t v = 0;
      if (j != 0) {
        int c = e / 3, k = e - c * 3;
        v = sX[c][sIdx[3 * (j - 1) + k]];
      }
      sT[j][e] = v;
    }
  }
  __syncthreads();

  {
    int nU = ecnt >> 1;
    int total = 128 * nU;
    size_t ebase = (size_t)c0 * 3;
    for (int p = tx; p < total; p += 256) {
      int j = p / nU, u = p - j * nU;
      ((uint32_t*)(Xg + ((size_t)b * 128 + j) * Kpad + ebase))[u] =
          ((const uint32_t*)&sT[j][0])[u];
    }
  }
}

// ---------------- MFMA GEMM: Y[b] = W(O x Kpad) * Xg[b]^T --------------------
__global__ __launch_bounds__(256)
void gemm_kernel(const uint16_t* __restrict__ A,
                 const uint16_t* __restrict__ Xg,
                 const float* __restrict__ bias,
                 uint16_t* __restrict__ Y,
                 int O, int Kpad,
                 float* __restrict__ statsAcc) {
  __shared__ __align__(16) uint16_t sA[128 * 64];
  __shared__ __align__(16) uint16_t sB[128 * 64];
  __shared__ float sBias[128];
  __shared__ float2 sRed[256];

  const int b     = blockIdx.x;
  const int obase = blockIdx.y * 128;
  const int tx    = threadIdx.x;
  const int wave  = tx >> 6, lane = tx & 63;
  const int wm    = wave & 1, wn = wave >> 1;

  if (tx < 128) sBias[tx] = bias[obase + tx];

  const uint16_t* Abase = A + (size_t)obase * Kpad;
  const uint16_t* Bbase = Xg + (size_t)b * 128 * Kpad;

  const int srow = lane >> 3;
  const int schk = lane & 7;

  f32x4 zero4 = {0.f, 0.f, 0.f, 0.f};
  f32x4 acc[4][4];
  #pragma unroll
  for (int i = 0; i < 4; i++)
    #pragma unroll
    for (int j = 0; j < 4; j++) acc[i][j] = zero4;

  const int lm = lane & 15;
  const int kg = lane >> 4;

  for (int kc = 0; kc < Kpad; kc += 64) {
    __syncthreads();
    #pragma unroll
    for (int i = 0; i < 4; i++) {
      int r  = wave * 8 + i * 32 + srow;
      int ca = schk ^ (r & 7);
      ldsload16(Abase + (size_t)r * Kpad + kc + ca * 8, &sA[(wave * 8 + i * 32) * 64]);
      ldsload16(Bbase + (size_t)r * Kpad + kc + ca * 8, &sB[(wave * 8 + i * 32) * 64]);
    }
    __syncthreads();
    #pragma unroll
    for (int s = 0; s < 2; s++) {
      bf16x8 av[4], bv[4];
      #pragma unroll
      for (int f = 0; f < 4; f++) {
        int rm = wm * 64 + f * 16 + lm;
        int cm = (s * 4 + kg) ^ (rm & 7);
        av[f] = *(const bf16x8*)&sA[rm * 64 + cm * 8];
        int rn = wn * 64 + f * 16 + lm;
        int cn = (s * 4 + kg) ^ (rn & 7);
        bv[f] = *(const bf16x8*)&sB[rn * 64 + cn * 8];
      }
      #pragma unroll
      for (int fm = 0; fm < 4; fm++)
        #pragma unroll
        for (int fn = 0; fn < 4; fn++)
          acc[fm][fn] = __builtin_amdgcn_mfma_f32_16x16x32_bf16(av[fm], bv[fn], acc[fm][fn], 0, 0, 0);
    }
  }

  float s1 = 0.f, s2 = 0.f;
  const int rb = (lane >> 4) * 4;
  #pragma unroll
  for (int fm = 0; fm < 4; fm++) {
    #pragma unroll
    for (int r = 0; r < 4; r++) {
      int olocal = wm * 64 + fm * 16 + rb + r;
      int o = obase + olocal;
      float bo = sBias[olocal];
      #pragma unroll
      for (int fn = 0; fn < 4; fn++) {
        int j = wn * 64 + fn * 16 + lm;
        float v = acc[fm][fn][r] + bo;
        if (j == 0) v = 0.f;
        s1 += v; s2 += v * v;
        Y[((size_t)b * O + o) * 128 + j] = f2bf(v);
      }
    }
  }

  if (statsAcc) {
    sRed[tx] = make_float2(s1, s2);
    __syncthreads();
    for (int s = 128; s > 0; s >>= 1) {
      if (tx < s) { sRed[tx].x += sRed[tx + s].x; sRed[tx].y += sRed[tx + s].y; }
      __syncthreads();
    }
    if (tx == 0) {
      atomicAdd(&statsAcc[b * 2],     sRed[0].x);
      atomicAdd(&statsAcc[b * 2 + 1], sRed[0].y);
    }
  }
}

__global__ void stats_finalize(const float* __restrict__ acc, float* __restrict__ ms,
                               int count, int nb) {
  int b = blockIdx.x * blockDim.x + threadIdx.x;
  if (b < nb) {
    float s = acc[b * 2], ss = acc[b * 2 + 1];
    float n = (float)count;
    float mean = s / n;
    float var = (ss - s * s / n) / (n - 1.0f);
    var = fmaxf(var, 0.f);
    ms[b * 2] = mean;
    ms[b * 2 + 1] = 1.0f / (sqrtf(var) + 1e-5f);
  }
}

// ---------------- gate v2: MFMA gate1 + softmax + pool -----------------------
// One block per batch. emb (256,128) bf16. gw1b (128,256) bf16.
__global__ __launch_bounds__(256)
void gate_kernel(const uint16_t* __restrict__ emb,
                 const uint16_t* __restrict__ gw1b,
                 const float* __restrict__ gb1,
                 const float* __restrict__ gw2, const float* __restrict__ gb2,
                 float* __restrict__ combined,
                 void* __restrict__ dout, const int* __restrict__ flag) {
  __shared__ __align__(16) uint16_t sEmb[128 * 128];  // 32 KB chunk [f_rel][m]
  __shared__ float sRed[4][128];
  __shared__ float sSm[128];
  __shared__ float sAttn[128];
  __shared__ float sPool[256];

  const int b = blockIdx.x;
  const int tx = threadIdx.x;
  const int wave = tx >> 6, lane = tx & 63;
  const int lm = lane & 15, kg = lane >> 4;
  const int h0 = wave * 32;
  const uint16_t* embB = emb + (size_t)b * 256 * 128;

  f32x4 zero4 = {0.f, 0.f, 0.f, 0.f};
  f32x4 acc[2][8];
  #pragma unroll
  for (int i = 0; i < 2; i++)
    #pragma unroll
    for (int t = 0; t < 8; t++) acc[i][t] = zero4;

  for (int kc = 0; kc < 256; kc += 128) {
    __syncthreads();
    #pragma unroll
    for (int i = 0; i < 8; i++) {
      int ofs = i * 2048 + wave * 512;           // shorts
      ldsload16(embB + (size_t)kc * 128 + ofs + lane * 8, &sEmb[ofs]);
    }
    __syncthreads();

    #pragma unroll
    for (int ks = 0; ks < 4; ks++) {
      bf16x8 a0 = *(const bf16x8*)(gw1b + (size_t)(h0 + lm) * 256 + kc + ks * 32 + kg * 8);
      bf16x8 a1 = *(const bf16x8*)(gw1b + (size_t)(h0 + 16 + lm) * 256 + kc + ks * 32 + kg * 8);
      #pragma unroll
      for (int t = 0; t < 8; t++) {
        bf16x8 bv;
        #pragma unroll
        for (int j = 0; j < 8; j++)
          ((short*)&bv)[j] = (short)sEmb[(ks * 32 + kg * 8 + j) * 128 + t * 16 + lm];
        acc[0][t] = __builtin_amdgcn_mfma_f32_16x16x32_bf16(a0, bv, acc[0][t], 0, 0, 0);
        acc[1][t] = __builtin_amdgcn_mfma_f32_16x16x32_bf16(a1, bv, acc[1][t], 0, 0, 0);
      }
    }
  }

  // epilogue: p[t] = sum over this wave's 32 h of relu(gate1+gb1)*gw2
  float gb[2][4], gv[2][4];
  #pragma unroll
  for (int ht = 0; ht < 2; ht++)
    #pragma unroll
    for (int r = 0; r < 4; r++) {
      int h = h0 + ht * 16 + kg * 4 + r;
      gb[ht][r] = gb1[h]; gv[ht][r] = gw2[h];
    }
  float p[8];
  #pragma unroll
  for (int t = 0; t < 8; t++) {
    float s = 0.f;
    #pragma unroll
    for (int ht = 0; ht < 2; ht++)
      #pragma unroll
      for (int r = 0; r < 4; r++)
        s += fmaxf(acc[ht][t][r] + gb[ht][r], 0.f) * gv[ht][r];
    s += __shfl_xor(s, 16);
    s += __shfl_xor(s, 32);
    p[t] = s;
  }
  if (lane < 16) {
    #pragma unroll
    for (int t = 0; t < 8; t++) sRed[wave][t * 16 + lane] = p[t];
  }
  __syncthreads();

  // softmax over m (128)
  if (tx < 128) {
    float v = sRed[0][tx] + sRed[1][tx] + sRed[2][tx] + sRed[3][tx] + gb2[0];
    sSm[tx] = v;
    sAttn[tx] = v;   // stash raw
  }
  __syncthreads();
  for (int s = 64; s > 0; s >>= 1) {
    if (tx < s) sSm[tx] = fmaxf(sSm[tx], sSm[tx + s]);
    __syncthreads();
  }
  float mx = sSm[0];
  __syncthreads();
  float e = 0.f;
  if (tx < 128) { e = expf(sAttn[tx] - mx); sSm[tx] = e; }
  __syncthreads();
  for (int s = 64; s > 0; s >>= 1) {
    if (tx < s) sSm[tx] += sSm[tx + s];
    __syncthreads();
  }
  float denom = sSm[0];
  __syncthreads();
  if (tx < 128) sAttn[tx] = e / denom;
  __syncthreads();

  // pool: 4 lanes per f-row, 4 passes (global reads, L2-hot)
  #pragma unroll
  for (int c = 0; c < 4; c++) {
    int f = c * 64 + (tx >> 2);
    int mbase = (tx & 3) * 32;
    const uint16_t* rowp = embB + (size_t)f * 128 + mbase;
    float pl = 0.f;
    #pragma unroll
    for (int i = 0; i < 4; i++) {
      uint4 u = *(const uint4*)(rowp + i * 8);
      float ev[8]; unpack8(u, ev);
      #pragma unroll
      for (int jj = 0; jj < 8; jj++) pl = fmaf(sAttn[mbase + i * 8 + jj], ev[jj], pl);
    }
    pl += __shfl_xor(pl, 1);
    pl += __shfl_xor(pl, 2);
    if ((tx & 3) == 0) sPool[f] = pl;
  }
  __syncthreads();

  float pool = sPool[tx];
  float root = bf2f(embB[(size_t)tx * 128 + 1]);
  combined[b * 512 + tx]       = root;
  combined[b * 512 + 256 + tx] = pool;
  if (*flag == 0) {
    uint16_t* o = ((uint16_t*)dout) + 512;
    o[b * 512 + tx]       = f2bf(root);
    o[b * 512 + 256 + tx] = f2bf(pool);
  } else {
    float* o = ((float*)dout) + 512;
    o[b * 512 + tx]       = root;
    o[b * 512 + 256 + tx] = pool;
  }
}

// ---------------- MLP head ---------------------------------------------------
__global__ __launch_bounds__(128)
void head_kernel(const float* __restrict__ combined,
                 const float* __restrict__ rw1, const float* __restrict__ rb1,
                 const float* __restrict__ rw2, const float* __restrict__ rb2,
                 const float* __restrict__ rw3, const float* __restrict__ rb3,
                 void* __restrict__ dout, const int* __restrict__ flag) {
  __shared__ __align__(16) float sC[512];
  __shared__ __align__(16) float sH1[128];
  __shared__ float sH2[64];
  const int b = blockIdx.x, tx = threadIdx.x;

  for (int i = tx; i < 512; i += 128) sC[i] = combined[b * 512 + i];
  __syncthreads();

  float a = rb1[tx];
  const float4* wr = (const float4*)(rw1 + (size_t)tx * 512);
  for (int i = 0; i < 128; i++) {
    float4 w4 = wr[i];
    float4 c4 = *(const float4*)&sC[i * 4];
    a = fmaf(w4.x, c4.x, a); a = fmaf(w4.y, c4.y, a);
    a = fmaf(w4.z, c4.z, a); a = fmaf(w4.w, c4.w, a);
  }
  sH1[tx] = fmaxf(a, 0.f);
  __syncthreads();

  if (tx < 64) {
    float a2 = rb2[tx];
    const float4* wr2 = (const float4*)(rw2 + (size_t)tx * 128);
    for (int i = 0; i < 32; i++) {
      float4 w4 = wr2[i];
      float4 h4 = *(const float4*)&sH1[i * 4];
      a2 = fmaf(w4.x, h4.x, a2); a2 = fmaf(w4.y, h4.y, a2);
      a2 = fmaf(w4.z, h4.z, a2); a2 = fmaf(w4.w, h4.w, a2);
    }
    sH2[tx] = fmaxf(a2, 0.f);
  }
  __syncthreads();

  if (tx < 64) {
    float pv = sH2[tx] * rw3[tx];
    for (int off = 32; off > 0; off >>= 1) pv += __shfl_down(pv, off);
    if (tx == 0) {
      float o = pv + rb3[0];
      if (*flag == 0) ((uint16_t*)dout)[b] = f2bf(o);
      else            ((float*)dout)[b]    = o;
    }
  }
}

// ---------------- launch -----------------------------------------------------
extern "C" void kernel_launch(void* const* d_in, const int* in_sizes, int n_in,
                              void* d_out, int out_size, void* d_ws, size_t ws_size,
                              hipStream_t stream) {
  const void* trees   = d_in[0];
  const int*  indexes = (const int*)d_in[1];
  const void* w1 = d_in[2];  const void* b1 = d_in[3];
  const void* w2 = d_in[4];  const void* b2 = d_in[5];
  const void* w3 = d_in[6];  const void* b3 = d_in[7];
  const void* gw1 = d_in[8]; const void* gb1 = d_in[9];
  const void* gw2 = d_in[10]; const void* gb2 = d_in[11];
  const void* rw1 = d_in[12]; const void* rb1 = d_in[13];
  const void* rw2 = d_in[14]; const void* rb2 = d_in[15];
  const void* rw3 = d_in[16]; const void* rb3 = d_in[17];

  char* ws = (char*)d_ws;
  size_t off = 0;
  auto alloc = [&](size_t bytes) -> char* {
    char* p = ws + off;
    off += (bytes + 255) & ~(size_t)255;
    return p;
  };

  int*   flagp    = (int*)alloc(256);
  float* statsAcc = (float*)alloc(4 * B_ * sizeof(float));
  float* statsMS  = (float*)alloc(4 * B_ * sizeof(float));
  float* b1f = (float*)alloc(512 * 4);
  float* b2f = (float*)alloc(512 * 4);
  float* b3f = (float*)alloc(256 * 4);
  float* gb1f = (float*)alloc(128 * 4);
  float* gw2f = (float*)alloc(128 * 4);
  float* gb2f = (float*)alloc(4);
  float* rw1f = (float*)alloc(128 * 512 * 4);
  float* rb1f = (float*)alloc(128 * 4);
  float* rw2f = (float*)alloc(64 * 128 * 4);
  float* rb2f = (float*)alloc(64 * 4);
  float* rw3f = (float*)alloc(64 * 4);
  float* rb3f = (float*)alloc(4);
  float* combined = (float*)alloc((size_t)B_ * 512 * 4);
  uint16_t* W1b  = (uint16_t*)alloc((size_t)512 * 640 * 2);
  uint16_t* W2b  = (uint16_t*)alloc((size_t)512 * 1536 * 2);
  uint16_t* W3b  = (uint16_t*)alloc((size_t)256 * 1536 * 2);
  uint16_t* GW1b = (uint16_t*)alloc((size_t)128 * 256 * 2);
  uint16_t* ybuf = (uint16_t*)alloc((size_t)B_ * 512 * 128 * 2);             // 64 MiB
  uint16_t* Xg   = (uint16_t*)alloc((size_t)HB_ * 128 * 1536 * 2);           // 96 MiB
  uint16_t* treesBF = ybuf + ((size_t)16 * 1024 * 1024);                     // ybuf+32MiB

  probe_kernel<<<1, 256, 0, stream>>>((const uint16_t*)trees, flagp);
  zero_kernel<<<2, 256, 0, stream>>>(statsAcc, 4 * B_);
  cvt_to_bf16<<<2048, 256, 0, stream>>>(trees, treesBF, B_ * CIN_ * 128, flagp);
  wcvt_kernel<<<1024, 256, 0, stream>>>(w1, W1b, 512, 600, 640, flagp);
  wcvt_kernel<<<2048, 256, 0, stream>>>(w2, W2b, 512, 1536, 1536, flagp);
  wcvt_kernel<<<1024, 256, 0, stream>>>(w3, W3b, 256, 1536, 1536, flagp);
  wcvt_kernel<<<256, 256, 0, stream>>>(gw1, GW1b, 128, 256, 256, flagp);

  CvtJobs jobs;
  int ji = 0;
  auto addjob = [&](const void* s, float* d, int n) { jobs.j[ji].src = s; jobs.j[ji].dst = d; jobs.j[ji].n = n; ji++; };
  addjob(b1, b1f, 512); addjob(b2, b2f, 512); addjob(b3, b3f, 256);
  addjob(gb1, gb1f, 128);
  addjob(gw2, gw2f, 128);       addjob(gb2, gb2f, 1);
  addjob(rw1, rw1f, 128 * 512); addjob(rb1, rb1f, 128);
  addjob(rw2, rw2f, 64 * 128);  addjob(rb2, rb2f, 64);
  addjob(rw3, rw3f, 64);        addjob(rb3, rb3f, 1);
  cvt_many<<<256, 256, 0, stream>>>(jobs, ji, flagp);

  // ---- layer 1 (K=600 -> 640) ----
  for (int h = 0; h < 2; h++) {
    int b0 = h * HB_;
    gather_kernel<<<dim3(7, HB_), 256, 0, stream>>>(
        treesBF + (size_t)b0 * CIN_ * 128, indexes + (size_t)b0 * N3_, Xg, CIN_, 640, nullptr);
    gemm_kernel<<<dim3(HB_, 4), 256, 0, stream>>>(
        W1b, Xg, b1f, ybuf + (size_t)b0 * 512 * 128, 512, 640, statsAcc + b0 * 2);
  }
  stats_finalize<<<2, 256, 0, stream>>>(statsAcc, statsMS, 512 * 128, B_);

  // ---- layer 2 (K=1536) ----
  for (int h = 0; h < 2; h++) {
    int b0 = h * HB_;
    gather_kernel<<<dim3(16, HB_), 256, 0, stream>>>(
        ybuf + (size_t)b0 * 512 * 128, indexes + (size_t)b0 * N3_, Xg, 512, 1536,
        statsMS + b0 * 2);
    gemm_kernel<<<dim3(HB_, 4), 256, 0, stream>>>(
        W2b, Xg, b2f, ybuf + (size_t)b0 * 512 * 128, 512, 1536, statsAcc + 2 * B_ + b0 * 2);
  }
  stats_finalize<<<2, 256, 0, stream>>>(statsAcc + 2 * B_, statsMS + 2 * B_, 512 * 128, B_);

  // ---- layer 3 (K=1536, O=256, no LN after) ----
  for (int h = 0; h < 2; h++) {
    int b0 = h * HB_;
    gather_kernel<<<dim3(16, HB_), 256, 0, stream>>>(
        ybuf + (size_t)b0 * 512 * 128, indexes + (size_t)b0 * N3_, Xg, 512, 1536,
        statsMS + 2 * B_ + b0 * 2);
    gemm_kernel<<<dim3(HB_, 2), 256, 0, stream>>>(
        W3b, Xg, b3f, ybuf + (size_t)b0 * 256 * 128, 256, 1536, nullptr);
  }

  // ---- gate + pool + head ----
  gate_kernel<<<B_, 256, 0, stream>>>(ybuf, GW1b, gb1f, gw2f, gb2f, combined, d_out, flagp);
  head_kernel<<<B_, 128, 0, stream>>>(combined, rw1f, rb1f, rw2f, rb2f, rw3f, rb3f, d_out, flagp);

  (void)in_sizes; (void)n_in; (void)out_size; (void)ws_size;
}

// Round 4
// 493.183 us; speedup vs baseline: 10.2553x; 1.7079x over previous
//
#include <hip/hip_runtime.h>
#include <stdint.h>

#define DI __device__ __forceinline__

static constexpr int B_   = 512;
static constexpr int N3_  = 381;

typedef short bf16x8 __attribute__((ext_vector_type(8)));
typedef float f32x4  __attribute__((ext_vector_type(4)));

DI float bf2f(uint32_t u) { union { uint32_t i; float f; } v; v.i = u << 16; return v.f; }
DI uint16_t f2bf(float f) {
  union { float f; uint32_t i; } v; v.f = f;
  uint32_t x = v.i;
  return (uint16_t)((x + 0x7fffu + ((x >> 16) & 1u)) >> 16);
}
DI void unpack8(uint4 u, float* v) {
  v[0] = bf2f(u.x & 0xffffu); v[1] = bf2f(u.x >> 16);
  v[2] = bf2f(u.y & 0xffffu); v[3] = bf2f(u.y >> 16);
  v[4] = bf2f(u.z & 0xffffu); v[5] = bf2f(u.z >> 16);
  v[6] = bf2f(u.w & 0xffffu); v[7] = bf2f(u.w >> 16);
}

DI void ldsload16(const uint16_t* g, uint16_t* l) {
  __builtin_amdgcn_global_load_lds((const __attribute__((address_space(1))) void*)g,
                                   (__attribute__((address_space(3))) void*)l,
                                   16, 0, 0);
}

// ---------------- dtype probe: flag=0 -> bf16 inputs, flag=1 -> f32 ----------
__global__ void probe_kernel(const uint16_t* __restrict__ trees, int* __restrict__ flag) {
  __shared__ int cnt;
  if (threadIdx.x == 0) cnt = 0;
  __syncthreads();
  int local = 0;
  #pragma unroll
  for (int q = 0; q < 2; q++) {
    uint16_t u = trees[threadIdx.x * 2 + q];
    int ex = (u >> 7) & 0xff;
    if (ex >= 110 && ex <= 133) local++;
  }
  atomicAdd(&cnt, local);
  __syncthreads();
  if (threadIdx.x == 0) *flag = (cnt >= 450) ? 0 : 1;
}

// ---------------- conversions ------------------------------------------------
__global__ void cvt_to_bf16(const void* __restrict__ src, uint16_t* __restrict__ dst,
                            int n, const int* __restrict__ flag) {
  int isf32 = *flag;
  int stride = gridDim.x * blockDim.x;
  for (int i = blockIdx.x * blockDim.x + threadIdx.x; i < n; i += stride)
    dst[i] = isf32 ? f2bf(((const float*)src)[i]) : ((const uint16_t*)src)[i];
}

// W [O][C][3] -> bf16 [O][k*Cpad + c] (K-reordered, zero-padded)
__global__ void wcvt_kernel(const void* __restrict__ src, uint16_t* __restrict__ dst,
                            int O, int C, int Cpad, const int* __restrict__ flag) {
  int isf32 = *flag;
  int Kpad = 3 * Cpad;
  int n = O * Kpad;
  int stride = gridDim.x * blockDim.x;
  for (int i = blockIdx.x * blockDim.x + threadIdx.x; i < n; i += stride) {
    int o = i / Kpad, e = i - o * Kpad;
    int reg = e / Cpad, c = e - reg * Cpad;
    uint16_t v = 0;
    if (c < C) {
      int s = (o * C + c) * 3 + reg;
      v = isf32 ? f2bf(((const float*)src)[s]) : ((const uint16_t*)src)[s];
    }
    dst[i] = v;
  }
}

struct CvtJob { const void* src; float* dst; int n; };
struct CvtJobs { CvtJob j[13]; };
__global__ void cvt_many(CvtJobs jobs, int nj, const int* __restrict__ flag) {
  int isf32 = *flag;
  int stride = gridDim.x * blockDim.x;
  for (int k = 0; k < nj; k++) {
    const void* src = jobs.j[k].src;
    float* dst = jobs.j[k].dst;
    int n = jobs.j[k].n;
    for (int i = blockIdx.x * blockDim.x + threadIdx.x; i < n; i += stride)
      dst[i] = isf32 ? ((const float*)src)[i] : bf2f(((const uint16_t*)src)[i]);
  }
}

__global__ void zero_kernel(float* __restrict__ p, int n) {
  int stride = gridDim.x * blockDim.x;
  for (int i = blockIdx.x * blockDim.x + threadIdx.x; i < n; i += stride) p[i] = 0.f;
}

// ---------------- trees transpose: trees[b][c][m] -> treesT[b][m(129)][256] --
__global__ __launch_bounds__(256)
void transpose_trees(const void* __restrict__ trees, uint16_t* __restrict__ dst,
                     const int* __restrict__ flag) {
  __shared__ uint16_t sX[32][130];
  const int b = blockIdx.y, c0 = blockIdx.x * 32, tx = threadIdx.x;
  const int cn = min(32, 200 - c0);
  const int isf32 = *flag;

  if (isf32) {
    const float* src = (const float*)trees + ((size_t)b * 200 + c0) * 128;
    for (int t = tx; t < cn * 128; t += 256) {
      int c = t >> 7, m = t & 127;
      sX[c][m] = f2bf(src[c * 128 + m]);
    }
  } else {
    const uint32_t* src = (const uint32_t*)((const uint16_t*)trees + ((size_t)b * 200 + c0) * 128);
    for (int t = tx; t < cn * 64; t += 256) {
      int c = t >> 6, p = t & 63;
      ((uint32_t*)&sX[c][0])[p] = src[c * 64 + p];
    }
  }
  __syncthreads();

  uint32_t* out = (uint32_t*)(dst + (size_t)b * 129 * 256 + c0);
  for (int p = tx; p < 129 * 16; p += 256) {
    int m = p >> 4, u = p & 15;
    int c = u * 2;
    uint32_t v = 0;
    if (m < 128) {
      uint16_t lo = (c     < cn) ? sX[c][m]     : (uint16_t)0;
      uint16_t hi = (c + 1 < cn) ? sX[c + 1][m] : (uint16_t)0;
      v = (uint32_t)lo | ((uint32_t)hi << 16);
    }
    out[(size_t)m * 128 + u] = v;
  }
}

// ---------------- fused gather+GEMM: yT[b][j][o] = conv(xT[b]) --------------
// A [O][3*Cpad] reordered weights; xT [B][129][Cpad] (row 128 = zeros).
// B-tile staged directly from xT rows via per-lane indexed global_load_lds.
// grid (O/128, B). Output transposed: yT[b][j(128)][O], row-stride outRS.
__global__ __launch_bounds__(256)
void gemm_kernel(const uint16_t* __restrict__ A,
                 const uint16_t* __restrict__ xT,
                 const int* __restrict__ idxg,
                 const float* __restrict__ bias,
                 uint16_t* __restrict__ Y,
                 int O, int Cpad, int outRS,
                 float* __restrict__ statsAcc) {
  __shared__ __align__(16) uint16_t sA[128 * 64];
  __shared__ __align__(16) uint16_t sB[128 * 64];
  __shared__ float sBias[128];
  __shared__ int sIdx[384];
  __shared__ float2 sRed[256];

  const int obase = blockIdx.x * 128;
  const int b     = blockIdx.y;
  const int tx    = threadIdx.x;
  const int wave  = tx >> 6, lane = tx & 63;
  const int wj    = wave & 1, wo = wave >> 1;
  const int Kpad  = 3 * Cpad;

  for (int t = tx; t < N3_; t += 256) sIdx[t] = idxg[(size_t)b * N3_ + t];
  if (tx < 128) sBias[tx] = bias[obase + tx];
  __syncthreads();

  const uint16_t* Abase = A + (size_t)obase * Kpad;
  const uint16_t* Bbase = xT + (size_t)b * 129 * Cpad;

  const int srow = lane >> 3;
  const int schk = lane & 7;
  const int lm = lane & 15;
  const int kg = lane >> 4;

  f32x4 zero4 = {0.f, 0.f, 0.f, 0.f};
  f32x4 acc[4][4];
  #pragma unroll
  for (int i = 0; i < 4; i++)
    #pragma unroll
    for (int j = 0; j < 4; j++) acc[i][j] = zero4;

  for (int reg = 0; reg < 3; reg++) {
    int ridx[4];
    #pragma unroll
    for (int i = 0; i < 4; i++) {
      int r = wave * 8 + i * 32 + srow;
      ridx[i] = (r == 0) ? 128 : sIdx[3 * (r - 1) + reg];
    }
    for (int co = 0; co < Cpad; co += 64) {
      __syncthreads();
      #pragma unroll
      for (int i = 0; i < 4; i++) {
        int r  = wave * 8 + i * 32 + srow;
        int ca = schk ^ (r & 7);
        ldsload16(Abase + (size_t)r * Kpad + reg * Cpad + co + ca * 8,
                  &sA[(wave * 8 + i * 32) * 64]);
        ldsload16(Bbase + (size_t)ridx[i] * Cpad + co + ca * 8,
                  &sB[(wave * 8 + i * 32) * 64]);
      }
      __syncthreads();
      #pragma unroll
      for (int s = 0; s < 2; s++) {
        bf16x8 xv[4], wv[4];
        #pragma unroll
        for (int f = 0; f < 4; f++) {
          int rj = wj * 64 + f * 16 + lm;
          int cj = (s * 4 + kg) ^ (rj & 7);
          xv[f] = *(const bf16x8*)&sB[rj * 64 + cj * 8];
          int ro = wo * 64 + f * 16 + lm;
          int cw = (s * 4 + kg) ^ (ro & 7);
          wv[f] = *(const bf16x8*)&sA[ro * 64 + cw * 8];
        }
        #pragma unroll
        for (int fj = 0; fj < 4; fj++)
          #pragma unroll
          for (int fo = 0; fo < 4; fo++)
            acc[fj][fo] = __builtin_amdgcn_mfma_f32_16x16x32_bf16(xv[fj], wv[fo], acc[fj][fo], 0, 0, 0);
      }
    }
  }

  // epilogue: C rows = j, cols = o. bias, zero row j==0, stats, store yT.
  float s1 = 0.f, s2 = 0.f;
  #pragma unroll
  for (int fj = 0; fj < 4; fj++) {
    #pragma unroll
    for (int fo = 0; fo < 4; fo++) {
      int olocal = wo * 64 + fo * 16 + lm;
      float bo = sBias[olocal];
      #pragma unroll
      for (int r = 0; r < 4; r++) {
        int j = wj * 64 + fj * 16 + kg * 4 + r;
        float v = acc[fj][fo][r] + bo;
        if (j == 0) v = 0.f;
        s1 += v; s2 += v * v;
        Y[((size_t)b * outRS + j) * O + obase + olocal] = f2bf(v);
      }
    }
  }

  if (statsAcc) {
    sRed[tx] = make_float2(s1, s2);
    __syncthreads();
    for (int s = 128; s > 0; s >>= 1) {
      if (tx < s) { sRed[tx].x += sRed[tx + s].x; sRed[tx].y += sRed[tx + s].y; }
      __syncthreads();
    }
    if (tx == 0) {
      atomicAdd(&statsAcc[b * 2],     sRed[0].x);
      atomicAdd(&statsAcc[b * 2 + 1], sRed[0].y);
    }
  }
}

__global__ void stats_finalize(const float* __restrict__ acc, float* __restrict__ ms,
                               int count, int nb) {
  int b = blockIdx.x * blockDim.x + threadIdx.x;
  if (b < nb) {
    float s = acc[b * 2], ss = acc[b * 2 + 1];
    float n = (float)count;
    float mean = s / n;
    float var = (ss - s * s / n) / (n - 1.0f);
    var = fmaxf(var, 0.f);
    ms[b * 2] = mean;
    ms[b * 2 + 1] = 1.0f / (sqrtf(var) + 1e-5f);
  }
}

// ---------------- LN+ReLU in place on yT [B][129][512]; row 128 -> 0 --------
__global__ __launch_bounds__(256)
void ln_relu_kernel(uint16_t* __restrict__ y, const float* __restrict__ ms) {
  const int u4PerRow = 64;                       // 512 shorts
  const int total = B_ * 129 * u4PerRow;
  int stride = gridDim.x * blockDim.x;
  for (int i = blockIdx.x * blockDim.x + threadIdx.x; i < total; i += stride) {
    int rowG = i >> 6;
    int b = rowG / 129;
    int r = rowG - b * 129;
    uint4 out;
    if (r == 128) {
      out = make_uint4(0, 0, 0, 0);
    } else {
      float mean = ms[b * 2], scale = ms[b * 2 + 1];
      uint4 u = ((const uint4*)y)[i];
      float v[8]; unpack8(u, v);
      uint32_t rr[4];
      #pragma unroll
      for (int k = 0; k < 4; k++) {
        float a  = fmaxf((v[2 * k]     - mean) * scale, 0.f);
        float bb = fmaxf((v[2 * k + 1] - mean) * scale, 0.f);
        rr[k] = (uint32_t)f2bf(a) | ((uint32_t)f2bf(bb) << 16);
      }
      out = make_uint4(rr[0], rr[1], rr[2], rr[3]);
    }
    ((uint4*)y)[i] = out;
  }
}

// ---------------- gate: MFMA gate1 + softmax + pool (emb = yT3 [B][128][256])
__global__ __launch_bounds__(256)
void gate_kernel(const uint16_t* __restrict__ emb,
                 const uint16_t* __restrict__ gw1b,    // [128][256] bf16
                 const float* __restrict__ gb1,
                 const float* __restrict__ gw2, const float* __restrict__ gb2,
                 float* __restrict__ combined,
                 void* __restrict__ dout, const int* __restrict__ flag) {
  __shared__ __align__(16) uint16_t sEmb[128 * 64];
  __shared__ float sRed[4][128];
  __shared__ float sSm[128];
  __shared__ float sAttn[128];
  __shared__ float sPool4[4 * 256];

  const int b = blockIdx.x;
  const int tx = threadIdx.x;
  const int wave = tx >> 6, lane = tx & 63;
  const int lm = lane & 15, kg = lane >> 4;
  const int srow = lane >> 3, schk = lane & 7;
  const int h0 = wave * 32;
  const uint16_t* embB = emb + (size_t)b * 128 * 256;

  f32x4 zero4 = {0.f, 0.f, 0.f, 0.f};
  f32x4 acc[2][8];
  #pragma unroll
  for (int i = 0; i < 2; i++)
    #pragma unroll
    for (int t = 0; t < 8; t++) acc[i][t] = zero4;

  for (int kc = 0; kc < 256; kc += 64) {
    __syncthreads();
    #pragma unroll
    for (int i = 0; i < 4; i++) {
      int r  = wave * 8 + i * 32 + srow;
      int ca = schk ^ (r & 7);
      ldsload16(embB + (size_t)r * 256 + kc + ca * 8, &sEmb[(wave * 8 + i * 32) * 64]);
    }
    __syncthreads();
    #pragma unroll
    for (int s = 0; s < 2; s++) {
      bf16x8 a0 = *(const bf16x8*)(gw1b + (size_t)(h0 + lm) * 256 + kc + s * 32 + kg * 8);
      bf16x8 a1 = *(const bf16x8*)(gw1b + (size_t)(h0 + 16 + lm) * 256 + kc + s * 32 + kg * 8);
      #pragma unroll
      for (int t = 0; t < 8; t++) {
        int rn = t * 16 + lm;
        int cn = (s * 4 + kg) ^ (rn & 7);
        bf16x8 bv = *(const bf16x8*)&sEmb[rn * 64 + cn * 8];
        acc[0][t] = __builtin_amdgcn_mfma_f32_16x16x32_bf16(a0, bv, acc[0][t], 0, 0, 0);
        acc[1][t] = __builtin_amdgcn_mfma_f32_16x16x32_bf16(a1, bv, acc[1][t], 0, 0, 0);
      }
    }
  }

  // epilogue: p[t] = sum over wave's 32 h of relu(gate1+gb1)*gw2
  float gb[2][4], gv[2][4];
  #pragma unroll
  for (int ht = 0; ht < 2; ht++)
    #pragma unroll
    for (int r = 0; r < 4; r++) {
      int h = h0 + ht * 16 + kg * 4 + r;
      gb[ht][r] = gb1[h]; gv[ht][r] = gw2[h];
    }
  float p[8];
  #pragma unroll
  for (int t = 0; t < 8; t++) {
    float s = 0.f;
    #pragma unroll
    for (int ht = 0; ht < 2; ht++)
      #pragma unroll
      for (int r = 0; r < 4; r++)
        s += fmaxf(acc[ht][t][r] + gb[ht][r], 0.f) * gv[ht][r];
    s += __shfl_xor(s, 16);
    s += __shfl_xor(s, 32);
    p[t] = s;
  }
  if (lane < 16) {
    #pragma unroll
    for (int t = 0; t < 8; t++) sRed[wave][t * 16 + lane] = p[t];
  }
  __syncthreads();

  // softmax over m
  float e = 0.f;
  if (tx < 128) {
    float v = sRed[0][tx] + sRed[1][tx] + sRed[2][tx] + sRed[3][tx] + gb2[0];
    sSm[tx] = v;
    sAttn[tx] = v;
  }
  __syncthreads();
  for (int s = 64; s > 0; s >>= 1) {
    if (tx < s) sSm[tx] = fmaxf(sSm[tx], sSm[tx + s]);
    __syncthreads();
  }
  float mx = sSm[0];
  __syncthreads();
  if (tx < 128) { e = expf(sAttn[tx] - mx); sSm[tx] = e; }
  __syncthreads();
  for (int s = 64; s > 0; s >>= 1) {
    if (tx < s) sSm[tx] += sSm[tx + s];
    __syncthreads();
  }
  float denom = sSm[0];
  __syncthreads();
  if (tx < 128) sAttn[tx] = e / denom;
  __syncthreads();

  // pool: wave covers 32 m rows, lane covers dwords {lane, lane+64} (f-pairs)
  float pl00 = 0.f, pl01 = 0.f, pl10 = 0.f, pl11 = 0.f;
  const uint32_t* base = (const uint32_t*)embB;
  const int mw = wave * 32;
  for (int mi = 0; mi < 32; mi++) {
    float a = sAttn[mw + mi];
    uint32_t u0 = base[(size_t)(mw + mi) * 128 + lane];
    uint32_t u1 = base[(size_t)(mw + mi) * 128 + 64 + lane];
    pl00 = fmaf(a, bf2f(u0 & 0xffffu), pl00);
    pl01 = fmaf(a, bf2f(u0 >> 16),     pl01);
    pl10 = fmaf(a, bf2f(u1 & 0xffffu), pl10);
    pl11 = fmaf(a, bf2f(u1 >> 16),     pl11);
  }
  sPool4[wave * 256 + lane * 2]           = pl00;
  sPool4[wave * 256 + lane * 2 + 1]       = pl01;
  sPool4[wave * 256 + 128 + lane * 2]     = pl10;
  sPool4[wave * 256 + 128 + lane * 2 + 1] = pl11;
  __syncthreads();

  float pool = sPool4[tx] + sPool4[256 + tx] + sPool4[512 + tx] + sPool4[768 + tx];
  float root = bf2f(embB[256 + tx]);       // row m=1, f=tx
  combined[b * 512 + tx]       = root;
  combined[b * 512 + 256 + tx] = pool;
  if (*flag == 0) {
    uint16_t* o = ((uint16_t*)dout) + 512;
    o[b * 512 + tx]       = f2bf(root);
    o[b * 512 + 256 + tx] = f2bf(pool);
  } else {
    float* o = ((float*)dout) + 512;
    o[b * 512 + tx]       = root;
    o[b * 512 + 256 + tx] = pool;
  }
}

// ---------------- MLP head ---------------------------------------------------
__global__ __launch_bounds__(128)
void head_kernel(const float* __restrict__ combined,
                 const float* __restrict__ rw1, const float* __restrict__ rb1,
                 const float* __restrict__ rw2, const float* __restrict__ rb2,
                 const float* __restrict__ rw3, const float* __restrict__ rb3,
                 void* __restrict__ dout, const int* __restrict__ flag) {
  __shared__ __align__(16) float sC[512];
  __shared__ __align__(16) float sH1[128];
  __shared__ float sH2[64];
  const int b = blockIdx.x, tx = threadIdx.x;

  for (int i = tx; i < 512; i += 128) sC[i] = combined[b * 512 + i];
  __syncthreads();

  float a = rb1[tx];
  const float4* wr = (const float4*)(rw1 + (size_t)tx * 512);
  for (int i = 0; i < 128; i++) {
    float4 w4 = wr[i];
    float4 c4 = *(const float4*)&sC[i * 4];
    a = fmaf(w4.x, c4.x, a); a = fmaf(w4.y, c4.y, a);
    a = fmaf(w4.z, c4.z, a); a = fmaf(w4.w, c4.w, a);
  }
  sH1[tx] = fmaxf(a, 0.f);
  __syncthreads();

  if (tx < 64) {
    float a2 = rb2[tx];
    const float4* wr2 = (const float4*)(rw2 + (size_t)tx * 128);
    for (int i = 0; i < 32; i++) {
      float4 w4 = wr2[i];
      float4 h4 = *(const float4*)&sH1[i * 4];
      a2 = fmaf(w4.x, h4.x, a2); a2 = fmaf(w4.y, h4.y, a2);
      a2 = fmaf(w4.z, h4.z, a2); a2 = fmaf(w4.w, h4.w, a2);
    }
    sH2[tx] = fmaxf(a2, 0.f);
  }
  __syncthreads();

  if (tx < 64) {
    float pv = sH2[tx] * rw3[tx];
    for (int off = 32; off > 0; off >>= 1) pv += __shfl_down(pv, off);
    if (tx == 0) {
      float o = pv + rb3[0];
      if (*flag == 0) ((uint16_t*)dout)[b] = f2bf(o);
      else            ((float*)dout)[b]    = o;
    }
  }
}

// ---------------- launch -----------------------------------------------------
extern "C" void kernel_launch(void* const* d_in, const int* in_sizes, int n_in,
                              void* d_out, int out_size, void* d_ws, size_t ws_size,
                              hipStream_t stream) {
  const void* trees   = d_in[0];
  const int*  indexes = (const int*)d_in[1];
  const void* w1 = d_in[2];  const void* b1 = d_in[3];
  const void* w2 = d_in[4];  const void* b2 = d_in[5];
  const void* w3 = d_in[6];  const void* b3 = d_in[7];
  const void* gw1 = d_in[8]; const void* gb1 = d_in[9];
  const void* gw2 = d_in[10]; const void* gb2 = d_in[11];
  const void* rw1 = d_in[12]; const void* rb1 = d_in[13];
  const void* rw2 = d_in[14]; const void* rb2 = d_in[15];
  const void* rw3 = d_in[16]; const void* rb3 = d_in[17];

  char* ws = (char*)d_ws;
  size_t off = 0;
  auto alloc = [&](size_t bytes) -> char* {
    char* p = ws + off;
    off += (bytes + 255) & ~(size_t)255;
    return p;
  };

  int*   flagp    = (int*)alloc(256);
  float* statsAcc = (float*)alloc(4 * B_ * sizeof(float));
  float* statsMS  = (float*)alloc(4 * B_ * sizeof(float));
  float* b1f = (float*)alloc(512 * 4);
  float* b2f = (float*)alloc(512 * 4);
  float* b3f = (float*)alloc(256 * 4);
  float* gb1f = (float*)alloc(128 * 4);
  float* gw2f = (float*)alloc(128 * 4);
  float* gb2f = (float*)alloc(4);
  float* rw1f = (float*)alloc(128 * 512 * 4);
  float* rb1f = (float*)alloc(128 * 4);
  float* rw2f = (float*)alloc(64 * 128 * 4);
  float* rb2f = (float*)alloc(64 * 4);
  float* rw3f = (float*)alloc(64 * 4);
  float* rb3f = (float*)alloc(4);
  float* combined = (float*)alloc((size_t)B_ * 512 * 4);
  uint16_t* W1b  = (uint16_t*)alloc((size_t)512 * 768 * 2);
  uint16_t* W2b  = (uint16_t*)alloc((size_t)512 * 1536 * 2);
  uint16_t* W3b  = (uint16_t*)alloc((size_t)256 * 1536 * 2);
  uint16_t* GW1b = (uint16_t*)alloc((size_t)128 * 256 * 2);
  uint16_t* bufA = (uint16_t*)alloc((size_t)B_ * 129 * 512 * 2);   // y1T, later yT3
  uint16_t* bufB = (uint16_t*)alloc((size_t)B_ * 129 * 512 * 2);   // treesT, later y2T

  uint16_t* treesT = bufB;            // [B][129][256]
  uint16_t* y1T    = bufA;            // [B][129][512]
  uint16_t* y2T    = bufB;            // [B][129][512]
  uint16_t* yT3    = bufA;            // [B][128][256]

  probe_kernel<<<1, 256, 0, stream>>>((const uint16_t*)trees, flagp);
  zero_kernel<<<2, 256, 0, stream>>>(statsAcc, 4 * B_);
  transpose_trees<<<dim3(7, B_), 256, 0, stream>>>(trees, treesT, flagp);
  wcvt_kernel<<<1024, 256, 0, stream>>>(w1, W1b, 512, 200, 256, flagp);
  wcvt_kernel<<<2048, 256, 0, stream>>>(w2, W2b, 512, 512, 512, flagp);
  wcvt_kernel<<<1024, 256, 0, stream>>>(w3, W3b, 256, 512, 512, flagp);
  cvt_to_bf16<<<256, 256, 0, stream>>>(gw1, GW1b, 128 * 256, flagp);

  CvtJobs jobs;
  int ji = 0;
  auto addjob = [&](const void* s, float* d, int n) { jobs.j[ji].src = s; jobs.j[ji].dst = d; jobs.j[ji].n = n; ji++; };
  addjob(b1, b1f, 512); addjob(b2, b2f, 512); addjob(b3, b3f, 256);
  addjob(gb1, gb1f, 128);
  addjob(gw2, gw2f, 128);       addjob(gb2, gb2f, 1);
  addjob(rw1, rw1f, 128 * 512); addjob(rb1, rb1f, 128);
  addjob(rw2, rw2f, 64 * 128);  addjob(rb2, rb2f, 64);
  addjob(rw3, rw3f, 64);        addjob(rb3, rb3f, 1);
  cvt_many<<<256, 256, 0, stream>>>(jobs, ji, flagp);

  // ---- layer 1: Cpad=256 (K=768), in treesT, out y1T ----
  gemm_kernel<<<dim3(4, B_), 256, 0, stream>>>(
      W1b, treesT, indexes, b1f, y1T, 512, 256, 129, statsAcc);
  stats_finalize<<<2, 256, 0, stream>>>(statsAcc, statsMS, 512 * 128, B_);
  ln_relu_kernel<<<2048, 256, 0, stream>>>(y1T, statsMS);

  // ---- layer 2: Cpad=512 (K=1536), in y1T, out y2T ----
  gemm_kernel<<<dim3(4, B_), 256, 0, stream>>>(
      W2b, y1T, indexes, b2f, y2T, 512, 512, 129, statsAcc + 2 * B_);
  stats_finalize<<<2, 256, 0, stream>>>(statsAcc + 2 * B_, statsMS + 2 * B_, 512 * 128, B_);
  ln_relu_kernel<<<2048, 256, 0, stream>>>(y2T, statsMS + 2 * B_);

  // ---- layer 3: Cpad=512, O=256, out yT3 (no LN) ----
  gemm_kernel<<<dim3(2, B_), 256, 0, stream>>>(
      W3b, y2T, indexes, b3f, yT3, 256, 512, 128, nullptr);

  // ---- gate + pool + head ----
  gate_kernel<<<B_, 256, 0, stream>>>(yT3, GW1b, gb1f, gw2f, gb2f, combined, d_out, flagp);
  head_kernel<<<B_, 128, 0, stream>>>(combined, rw1f, rb1f, rw2f, rb2f, rw3f, rb3f, d_out, flagp);

  (void)in_sizes; (void)n_in; (void)out_size; (void)ws_size;
}

// Round 5
// 465.479 us; speedup vs baseline: 10.8657x; 1.0595x over previous
//
#include <hip/hip_runtime.h>
#include <stdint.h>

#define DI __device__ __forceinline__

static constexpr int B_   = 512;
static constexpr int N3_  = 381;

typedef short bf16x8 __attribute__((ext_vector_type(8)));
typedef float f32x4  __attribute__((ext_vector_type(4)));

DI float bf2f(uint32_t u) { union { uint32_t i; float f; } v; v.i = u << 16; return v.f; }
DI uint16_t f2bf(float f) {
  union { float f; uint32_t i; } v; v.f = f;
  uint32_t x = v.i;
  return (uint16_t)((x + 0x7fffu + ((x >> 16) & 1u)) >> 16);
}
DI void unpack8(uint4 u, float* v) {
  v[0] = bf2f(u.x & 0xffffu); v[1] = bf2f(u.x >> 16);
  v[2] = bf2f(u.y & 0xffffu); v[3] = bf2f(u.y >> 16);
  v[4] = bf2f(u.z & 0xffffu); v[5] = bf2f(u.z >> 16);
  v[6] = bf2f(u.w & 0xffffu); v[7] = bf2f(u.w >> 16);
}

DI void ldsload16(const uint16_t* g, uint16_t* l) {
  __builtin_amdgcn_global_load_lds((const __attribute__((address_space(1))) void*)g,
                                   (__attribute__((address_space(3))) void*)l,
                                   16, 0, 0);
}

// ------- dtype probe (flag=0 bf16, flag=1 f32) + statsAcc zeroing fused ------
__global__ void probe_kernel(const uint16_t* __restrict__ trees, int* __restrict__ flag,
                             float* __restrict__ statsAcc) {
  __shared__ int cnt;
  if (threadIdx.x == 0) cnt = 0;
  __syncthreads();
  int local = 0;
  #pragma unroll
  for (int q = 0; q < 2; q++) {
    uint16_t u = trees[threadIdx.x * 2 + q];
    int ex = (u >> 7) & 0xff;
    if (ex >= 110 && ex <= 133) local++;
  }
  atomicAdd(&cnt, local);
  #pragma unroll
  for (int q = 0; q < 8; q++) statsAcc[q * 256 + threadIdx.x] = 0.f;
  __syncthreads();
  if (threadIdx.x == 0) *flag = (cnt >= 450) ? 0 : 1;
}

// ---------------- conversions ------------------------------------------------
__global__ void cvt_to_bf16(const void* __restrict__ src, uint16_t* __restrict__ dst,
                            int n, const int* __restrict__ flag) {
  int isf32 = *flag;
  int stride = gridDim.x * blockDim.x;
  for (int i = blockIdx.x * blockDim.x + threadIdx.x; i < n; i += stride)
    dst[i] = isf32 ? f2bf(((const float*)src)[i]) : ((const uint16_t*)src)[i];
}

// W [O][C][3] -> bf16 [O][k*Cpad + c] (K-reordered, zero-padded)
__global__ void wcvt_kernel(const void* __restrict__ src, uint16_t* __restrict__ dst,
                            int O, int C, int Cpad, const int* __restrict__ flag) {
  int isf32 = *flag;
  int Kpad = 3 * Cpad;
  int n = O * Kpad;
  int stride = gridDim.x * blockDim.x;
  for (int i = blockIdx.x * blockDim.x + threadIdx.x; i < n; i += stride) {
    int o = i / Kpad, e = i - o * Kpad;
    int reg = e / Cpad, c = e - reg * Cpad;
    uint16_t v = 0;
    if (c < C) {
      int s = (o * C + c) * 3 + reg;
      v = isf32 ? f2bf(((const float*)src)[s]) : ((const uint16_t*)src)[s];
    }
    dst[i] = v;
  }
}

struct CvtJob { const void* src; float* dst; int n; };
struct CvtJobs { CvtJob j[13]; };
__global__ void cvt_many(CvtJobs jobs, int nj, const int* __restrict__ flag) {
  int isf32 = *flag;
  int stride = gridDim.x * blockDim.x;
  for (int k = 0; k < nj; k++) {
    const void* src = jobs.j[k].src;
    float* dst = jobs.j[k].dst;
    int n = jobs.j[k].n;
    for (int i = blockIdx.x * blockDim.x + threadIdx.x; i < n; i += stride)
      dst[i] = isf32 ? ((const float*)src)[i] : bf2f(((const uint16_t*)src)[i]);
  }
}

// ---------------- trees transpose: trees[b][c][m] -> treesT[b][m(129)][256] --
__global__ __launch_bounds__(256)
void transpose_trees(const void* __restrict__ trees, uint16_t* __restrict__ dst,
                     const int* __restrict__ flag) {
  __shared__ uint16_t sX[32][130];
  const int b = blockIdx.y, c0 = blockIdx.x * 32, tx = threadIdx.x;
  const int cn = min(32, 200 - c0);
  const int isf32 = *flag;

  if (isf32) {
    const float* src = (const float*)trees + ((size_t)b * 200 + c0) * 128;
    for (int t = tx; t < cn * 128; t += 256) {
      int c = t >> 7, m = t & 127;
      sX[c][m] = f2bf(src[c * 128 + m]);
    }
  } else {
    const uint32_t* src = (const uint32_t*)((const uint16_t*)trees + ((size_t)b * 200 + c0) * 128);
    for (int t = tx; t < cn * 64; t += 256) {
      int c = t >> 6, p = t & 63;
      ((uint32_t*)&sX[c][0])[p] = src[c * 64 + p];
    }
  }
  __syncthreads();

  uint32_t* out = (uint32_t*)(dst + (size_t)b * 129 * 256 + c0);
  for (int p = tx; p < 129 * 16; p += 256) {
    int m = p >> 4, u = p & 15;
    int c = u * 2;
    uint32_t v = 0;
    if (m < 128) {
      uint16_t lo = (c     < cn) ? sX[c][m]     : (uint16_t)0;
      uint16_t hi = (c + 1 < cn) ? sX[c + 1][m] : (uint16_t)0;
      v = (uint32_t)lo | ((uint32_t)hi << 16);
    }
    out[(size_t)m * 128 + u] = v;
  }
}

// ---------------- fused gather+GEMM: yT[b][j][o] = conv(xT[b]) --------------
// 1D grid nO*B_, XCD-swizzled: all o-tiles of a batch land on one XCD.
__global__ __launch_bounds__(256, 3)
void gemm_kernel(const uint16_t* __restrict__ A,
                 const uint16_t* __restrict__ xT,
                 const int* __restrict__ idxg,
                 const float* __restrict__ bias,
                 uint16_t* __restrict__ Y,
                 int nO, int Cpad, int outRS,
                 float* __restrict__ statsAcc) {
  __shared__ __align__(16) uint16_t sA[128 * 64];
  __shared__ __align__(16) uint16_t sB[128 * 64];
  __shared__ float sBias[128];
  __shared__ int sIdx[384];
  __shared__ float2 sRed[256];

  const int id   = blockIdx.x;
  const int xcd  = id & 7;
  const int rest = id >> 3;
  const int ot   = rest % nO;
  const int b    = (rest / nO) * 8 + xcd;
  const int obase = ot * 128;
  const int O     = nO * 128;

  const int tx    = threadIdx.x;
  const int wave  = tx >> 6, lane = tx & 63;
  const int wj    = wave & 1, wo = wave >> 1;
  const int Kpad  = 3 * Cpad;

  for (int t = tx; t < N3_; t += 256) sIdx[t] = idxg[(size_t)b * N3_ + t];
  if (tx < 128) sBias[tx] = bias[obase + tx];
  __syncthreads();

  const uint16_t* Abase = A + (size_t)obase * Kpad;
  const uint16_t* Bbase = xT + (size_t)b * 129 * Cpad;

  const int srow = lane >> 3;
  const int schk = lane & 7;
  const int lm = lane & 15;
  const int kg = lane >> 4;

  f32x4 zero4 = {0.f, 0.f, 0.f, 0.f};
  f32x4 acc[4][4];
  #pragma unroll
  for (int i = 0; i < 4; i++)
    #pragma unroll
    for (int j = 0; j < 4; j++) acc[i][j] = zero4;

  for (int reg = 0; reg < 3; reg++) {
    int ridx[4];
    #pragma unroll
    for (int i = 0; i < 4; i++) {
      int r = wave * 8 + i * 32 + srow;
      ridx[i] = (r == 0) ? 128 : sIdx[3 * (r - 1) + reg];
    }
    for (int co = 0; co < Cpad; co += 64) {
      __syncthreads();
      #pragma unroll
      for (int i = 0; i < 4; i++) {
        int r  = wave * 8 + i * 32 + srow;
        int ca = schk ^ (r & 7);
        ldsload16(Abase + (size_t)r * Kpad + reg * Cpad + co + ca * 8,
                  &sA[(wave * 8 + i * 32) * 64]);
        ldsload16(Bbase + (size_t)ridx[i] * Cpad + co + ca * 8,
                  &sB[(wave * 8 + i * 32) * 64]);
      }
      __syncthreads();
      #pragma unroll
      for (int s = 0; s < 2; s++) {
        bf16x8 xv[4], wv[4];
        #pragma unroll
        for (int f = 0; f < 4; f++) {
          int rj = wj * 64 + f * 16 + lm;
          int cj = (s * 4 + kg) ^ (rj & 7);
          xv[f] = *(const bf16x8*)&sB[rj * 64 + cj * 8];
          int ro = wo * 64 + f * 16 + lm;
          int cw = (s * 4 + kg) ^ (ro & 7);
          wv[f] = *(const bf16x8*)&sA[ro * 64 + cw * 8];
        }
        #pragma unroll
        for (int fj = 0; fj < 4; fj++)
          #pragma unroll
          for (int fo = 0; fo < 4; fo++)
            acc[fj][fo] = __builtin_amdgcn_mfma_f32_16x16x32_bf16(xv[fj], wv[fo], acc[fj][fo], 0, 0, 0);
      }
    }
  }

  // epilogue: C rows = j, cols = o. bias, zero row j==0, stats, store yT.
  float s1 = 0.f, s2 = 0.f;
  #pragma unroll
  for (int fj = 0; fj < 4; fj++) {
    #pragma unroll
    for (int fo = 0; fo < 4; fo++) {
      int olocal = wo * 64 + fo * 16 + lm;
      float bo = sBias[olocal];
      #pragma unroll
      for (int r = 0; r < 4; r++) {
        int j = wj * 64 + fj * 16 + kg * 4 + r;
        float v = acc[fj][fo][r] + bo;
        if (j == 0) v = 0.f;
        s1 += v; s2 += v * v;
        Y[((size_t)b * outRS + j) * O + obase + olocal] = f2bf(v);
      }
    }
  }

  if (statsAcc) {
    sRed[tx] = make_float2(s1, s2);
    __syncthreads();
    for (int s = 128; s > 0; s >>= 1) {
      if (tx < s) { sRed[tx].x += sRed[tx + s].x; sRed[tx].y += sRed[tx + s].y; }
      __syncthreads();
    }
    if (tx == 0) {
      atomicAdd(&statsAcc[b * 2],     sRed[0].x);
      atomicAdd(&statsAcc[b * 2 + 1], sRed[0].y);
    }
  }
}

__global__ void stats_finalize(const float* __restrict__ acc, float* __restrict__ ms,
                               int count, int nb) {
  int b = blockIdx.x * blockDim.x + threadIdx.x;
  if (b < nb) {
    float s = acc[b * 2], ss = acc[b * 2 + 1];
    float n = (float)count;
    float mean = s / n;
    float var = (ss - s * s / n) / (n - 1.0f);
    var = fmaxf(var, 0.f);
    ms[b * 2] = mean;
    ms[b * 2 + 1] = 1.0f / (sqrtf(var) + 1e-5f);
  }
}

// ---------------- LN+ReLU in place on yT [B][129][512]; row 128 -> 0 --------
__global__ __launch_bounds__(256)
void ln_relu_kernel(uint16_t* __restrict__ y, const float* __restrict__ ms) {
  const int total = B_ * 129 * 64;
  int stride = gridDim.x * blockDim.x;
  for (int i = blockIdx.x * blockDim.x + threadIdx.x; i < total; i += stride) {
    int rowG = i >> 6;
    int b = rowG / 129;
    int r = rowG - b * 129;
    uint4 out;
    if (r == 128) {
      out = make_uint4(0, 0, 0, 0);
    } else {
      float mean = ms[b * 2], scale = ms[b * 2 + 1];
      uint4 u = ((const uint4*)y)[i];
      float v[8]; unpack8(u, v);
      uint32_t rr[4];
      #pragma unroll
      for (int k = 0; k < 4; k++) {
        float a  = fmaxf((v[2 * k]     - mean) * scale, 0.f);
        float bb = fmaxf((v[2 * k + 1] - mean) * scale, 0.f);
        rr[k] = (uint32_t)f2bf(a) | ((uint32_t)f2bf(bb) << 16);
      }
      out = make_uint4(rr[0], rr[1], rr[2], rr[3]);
    }
    ((uint4*)y)[i] = out;
  }
}

// ------ gate + softmax + pool + fused MLP head (emb = yT3 [B][128][256]) ----
__global__ __launch_bounds__(256)
void gate_kernel(const uint16_t* __restrict__ emb,
                 const uint16_t* __restrict__ gw1b,    // [128][256] bf16
                 const float* __restrict__ gb1,
                 const float* __restrict__ gw2, const float* __restrict__ gb2,
                 const float* __restrict__ rw1, const float* __restrict__ rb1,
                 const float* __restrict__ rw2, const float* __restrict__ rb2,
                 const float* __restrict__ rw3, const float* __restrict__ rb3,
                 void* __restrict__ dout, const int* __restrict__ flag) {
  __shared__ __align__(16) uint16_t sEmb[128 * 64];
  __shared__ float sRed[4][128];
  __shared__ float sSm[128];
  __shared__ float sAttn[128];
  __shared__ float sPool4[4 * 256];
  __shared__ __align__(16) float sC[512];
  __shared__ __align__(16) float sH1[128];
  __shared__ float sH2[64];

  const int b = blockIdx.x;
  const int tx = threadIdx.x;
  const int wave = tx >> 6, lane = tx & 63;
  const int lm = lane & 15, kg = lane >> 4;
  const int srow = lane >> 3, schk = lane & 7;
  const int h0 = wave * 32;
  const uint16_t* embB = emb + (size_t)b * 128 * 256;

  f32x4 zero4 = {0.f, 0.f, 0.f, 0.f};
  f32x4 acc[2][8];
  #pragma unroll
  for (int i = 0; i < 2; i++)
    #pragma unroll
    for (int t = 0; t < 8; t++) acc[i][t] = zero4;

  for (int kc = 0; kc < 256; kc += 64) {
    __syncthreads();
    #pragma unroll
    for (int i = 0; i < 4; i++) {
      int r  = wave * 8 + i * 32 + srow;
      int ca = schk ^ (r & 7);
      ldsload16(embB + (size_t)r * 256 + kc + ca * 8, &sEmb[(wave * 8 + i * 32) * 64]);
    }
    __syncthreads();
    #pragma unroll
    for (int s = 0; s < 2; s++) {
      bf16x8 a0 = *(const bf16x8*)(gw1b + (size_t)(h0 + lm) * 256 + kc + s * 32 + kg * 8);
      bf16x8 a1 = *(const bf16x8*)(gw1b + (size_t)(h0 + 16 + lm) * 256 + kc + s * 32 + kg * 8);
      #pragma unroll
      for (int t = 0; t < 8; t++) {
        int rn = t * 16 + lm;
        int cn = (s * 4 + kg) ^ (rn & 7);
        bf16x8 bv = *(const bf16x8*)&sEmb[rn * 64 + cn * 8];
        acc[0][t] = __builtin_amdgcn_mfma_f32_16x16x32_bf16(a0, bv, acc[0][t], 0, 0, 0);
        acc[1][t] = __builtin_amdgcn_mfma_f32_16x16x32_bf16(a1, bv, acc[1][t], 0, 0, 0);
      }
    }
  }

  float gb[2][4], gv[2][4];
  #pragma unroll
  for (int ht = 0; ht < 2; ht++)
    #pragma unroll
    for (int r = 0; r < 4; r++) {
      int h = h0 + ht * 16 + kg * 4 + r;
      gb[ht][r] = gb1[h]; gv[ht][r] = gw2[h];
    }
  float p[8];
  #pragma unroll
  for (int t = 0; t < 8; t++) {
    float s = 0.f;
    #pragma unroll
    for (int ht = 0; ht < 2; ht++)
      #pragma unroll
      for (int r = 0; r < 4; r++)
        s += fmaxf(acc[ht][t][r] + gb[ht][r], 0.f) * gv[ht][r];
    s += __shfl_xor(s, 16);
    s += __shfl_xor(s, 32);
    p[t] = s;
  }
  if (lane < 16) {
    #pragma unroll
    for (int t = 0; t < 8; t++) sRed[wave][t * 16 + lane] = p[t];
  }
  __syncthreads();

  float e = 0.f;
  if (tx < 128) {
    float v = sRed[0][tx] + sRed[1][tx] + sRed[2][tx] + sRed[3][tx] + gb2[0];
    sSm[tx] = v;
    sAttn[tx] = v;
  }
  __syncthreads();
  for (int s = 64; s > 0; s >>= 1) {
    if (tx < s) sSm[tx] = fmaxf(sSm[tx], sSm[tx + s]);
    __syncthreads();
  }
  float mx = sSm[0];
  __syncthreads();
  if (tx < 128) { e = expf(sAttn[tx] - mx); sSm[tx] = e; }
  __syncthreads();
  for (int s = 64; s > 0; s >>= 1) {
    if (tx < s) sSm[tx] += sSm[tx + s];
    __syncthreads();
  }
  float denom = sSm[0];
  __syncthreads();
  if (tx < 128) sAttn[tx] = e / denom;
  __syncthreads();

  // pool: wave covers 32 m rows, lane covers dwords {lane, lane+64}
  float pl00 = 0.f, pl01 = 0.f, pl10 = 0.f, pl11 = 0.f;
  const uint32_t* base = (const uint32_t*)embB;
  const int mw = wave * 32;
  for (int mi = 0; mi < 32; mi++) {
    float a = sAttn[mw + mi];
    uint32_t u0 = base[(size_t)(mw + mi) * 128 + lane];
    uint32_t u1 = base[(size_t)(mw + mi) * 128 + 64 + lane];
    pl00 = fmaf(a, bf2f(u0 & 0xffffu), pl00);
    pl01 = fmaf(a, bf2f(u0 >> 16),     pl01);
    pl10 = fmaf(a, bf2f(u1 & 0xffffu), pl10);
    pl11 = fmaf(a, bf2f(u1 >> 16),     pl11);
  }
  sPool4[wave * 256 + lane * 2]           = pl00;
  sPool4[wave * 256 + lane * 2 + 1]       = pl01;
  sPool4[wave * 256 + 128 + lane * 2]     = pl10;
  sPool4[wave * 256 + 128 + lane * 2 + 1] = pl11;
  __syncthreads();

  float pool = sPool4[tx] + sPool4[256 + tx] + sPool4[512 + tx] + sPool4[768 + tx];
  float root = bf2f(embB[256 + tx]);       // row m=1, f=tx
  sC[tx]       = root;
  sC[256 + tx] = pool;

  const int isf32 = (*flag != 0);
  if (!isf32) {
    uint16_t* o = ((uint16_t*)dout) + 512;
    o[b * 512 + tx]       = f2bf(root);
    o[b * 512 + 256 + tx] = f2bf(pool);
  } else {
    float* o = ((float*)dout) + 512;
    o[b * 512 + tx]       = root;
    o[b * 512 + 256 + tx] = pool;
  }
  __syncthreads();

  // fused MLP head
  if (tx < 128) {
    float a = rb1[tx];
    const float4* wr = (const float4*)(rw1 + (size_t)tx * 512);
    for (int i = 0; i < 128; i++) {
      float4 w4 = wr[i];
      float4 c4 = *(const float4*)&sC[i * 4];
      a = fmaf(w4.x, c4.x, a); a = fmaf(w4.y, c4.y, a);
      a = fmaf(w4.z, c4.z, a); a = fmaf(w4.w, c4.w, a);
    }
    sH1[tx] = fmaxf(a, 0.f);
  }
  __syncthreads();
  if (tx < 64) {
    float a2 = rb2[tx];
    const float4* wr2 = (const float4*)(rw2 + (size_t)tx * 128);
    for (int i = 0; i < 32; i++) {
      float4 w4 = wr2[i];
      float4 h4 = *(const float4*)&sH1[i * 4];
      a2 = fmaf(w4.x, h4.x, a2); a2 = fmaf(w4.y, h4.y, a2);
      a2 = fmaf(w4.z, h4.z, a2); a2 = fmaf(w4.w, h4.w, a2);
    }
    sH2[tx] = fmaxf(a2, 0.f);
  }
  __syncthreads();
  if (tx < 64) {
    float pv = sH2[tx] * rw3[tx];
    for (int off = 32; off > 0; off >>= 1) pv += __shfl_down(pv, off);
    if (tx == 0) {
      float o = pv + rb3[0];
      if (!isf32) ((uint16_t*)dout)[b] = f2bf(o);
      else        ((float*)dout)[b]    = o;
    }
  }
}

// ---------------- launch -----------------------------------------------------
extern "C" void kernel_launch(void* const* d_in, const int* in_sizes, int n_in,
                              void* d_out, int out_size, void* d_ws, size_t ws_size,
                              hipStream_t stream) {
  const void* trees   = d_in[0];
  const int*  indexes = (const int*)d_in[1];
  const void* w1 = d_in[2];  const void* b1 = d_in[3];
  const void* w2 = d_in[4];  const void* b2 = d_in[5];
  const void* w3 = d_in[6];  const void* b3 = d_in[7];
  const void* gw1 = d_in[8]; const void* gb1 = d_in[9];
  const void* gw2 = d_in[10]; const void* gb2 = d_in[11];
  const void* rw1 = d_in[12]; const void* rb1 = d_in[13];
  const void* rw2 = d_in[14]; const void* rb2 = d_in[15];
  const void* rw3 = d_in[16]; const void* rb3 = d_in[17];

  char* ws = (char*)d_ws;
  size_t off = 0;
  auto alloc = [&](size_t bytes) -> char* {
    char* p = ws + off;
    off += (bytes + 255) & ~(size_t)255;
    return p;
  };

  int*   flagp    = (int*)alloc(256);
  float* statsAcc = (float*)alloc(4 * B_ * sizeof(float));
  float* statsMS  = (float*)alloc(4 * B_ * sizeof(float));
  float* b1f = (float*)alloc(512 * 4);
  float* b2f = (float*)alloc(512 * 4);
  float* b3f = (float*)alloc(256 * 4);
  float* gb1f = (float*)alloc(128 * 4);
  float* gw2f = (float*)alloc(128 * 4);
  float* gb2f = (float*)alloc(4);
  float* rw1f = (float*)alloc(128 * 512 * 4);
  float* rb1f = (float*)alloc(128 * 4);
  float* rw2f = (float*)alloc(64 * 128 * 4);
  float* rb2f = (float*)alloc(64 * 4);
  float* rw3f = (float*)alloc(64 * 4);
  float* rb3f = (float*)alloc(4);
  uint16_t* W1b  = (uint16_t*)alloc((size_t)512 * 768 * 2);
  uint16_t* W2b  = (uint16_t*)alloc((size_t)512 * 1536 * 2);
  uint16_t* W3b  = (uint16_t*)alloc((size_t)256 * 1536 * 2);
  uint16_t* GW1b = (uint16_t*)alloc((size_t)128 * 256 * 2);
  uint16_t* bufA = (uint16_t*)alloc((size_t)B_ * 129 * 512 * 2);   // y1T, later yT3
  uint16_t* bufB = (uint16_t*)alloc((size_t)B_ * 129 * 512 * 2);   // treesT, later y2T

  uint16_t* treesT = bufB;            // [B][129][256]
  uint16_t* y1T    = bufA;            // [B][129][512]
  uint16_t* y2T    = bufB;            // [B][129][512]
  uint16_t* yT3    = bufA;            // [B][128][256]

  probe_kernel<<<1, 256, 0, stream>>>((const uint16_t*)trees, flagp, statsAcc);
  transpose_trees<<<dim3(7, B_), 256, 0, stream>>>(trees, treesT, flagp);
  wcvt_kernel<<<1024, 256, 0, stream>>>(w1, W1b, 512, 200, 256, flagp);
  wcvt_kernel<<<2048, 256, 0, stream>>>(w2, W2b, 512, 512, 512, flagp);
  wcvt_kernel<<<1024, 256, 0, stream>>>(w3, W3b, 256, 512, 512, flagp);
  cvt_to_bf16<<<256, 256, 0, stream>>>(gw1, GW1b, 128 * 256, flagp);

  CvtJobs jobs;
  int ji = 0;
  auto addjob = [&](const void* s, float* d, int n) { jobs.j[ji].src = s; jobs.j[ji].dst = d; jobs.j[ji].n = n; ji++; };
  addjob(b1, b1f, 512); addjob(b2, b2f, 512); addjob(b3, b3f, 256);
  addjob(gb1, gb1f, 128);
  addjob(gw2, gw2f, 128);       addjob(gb2, gb2f, 1);
  addjob(rw1, rw1f, 128 * 512); addjob(rb1, rb1f, 128);
  addjob(rw2, rw2f, 64 * 128);  addjob(rb2, rb2f, 64);
  addjob(rw3, rw3f, 64);        addjob(rb3, rb3f, 1);
  cvt_many<<<256, 256, 0, stream>>>(jobs, ji, flagp);

  // ---- layer 1: Cpad=256 (K=768), in treesT, out y1T ----
  gemm_kernel<<<4 * B_, 256, 0, stream>>>(
      W1b, treesT, indexes, b1f, y1T, 4, 256, 129, statsAcc);
  stats_finalize<<<2, 256, 0, stream>>>(statsAcc, statsMS, 512 * 128, B_);
  ln_relu_kernel<<<2048, 256, 0, stream>>>(y1T, statsMS);

  // ---- layer 2: Cpad=512 (K=1536), in y1T, out y2T ----
  gemm_kernel<<<4 * B_, 256, 0, stream>>>(
      W2b, y1T, indexes, b2f, y2T, 4, 512, 129, statsAcc + 2 * B_);
  stats_finalize<<<2, 256, 0, stream>>>(statsAcc + 2 * B_, statsMS + 2 * B_, 512 * 128, B_);
  ln_relu_kernel<<<2048, 256, 0, stream>>>(y2T, statsMS + 2 * B_);

  // ---- layer 3: Cpad=512, O=256, out yT3 (no LN) ----
  gemm_kernel<<<2 * B_, 256, 0, stream>>>(
      W3b, y2T, indexes, b3f, yT3, 2, 512, 128, nullptr);

  // ---- gate + pool + fused head ----
  gate_kernel<<<B_, 256, 0, stream>>>(yT3, GW1b, gb1f, gw2f, gb2f,
                                      rw1f, rb1f, rw2f, rb2f, rw3f, rb3f,
                                      d_out, flagp);

  (void)in_sizes; (void)n_in; (void)out_size; (void)ws_size;
}

// Round 6
// 429.319 us; speedup vs baseline: 11.7808x; 1.0842x over previous
//
#include <hip/hip_runtime.h>
#include <stdint.h>

#define DI __device__ __forceinline__

static constexpr int B_   = 512;
static constexpr int N3_  = 381;

typedef short bf16x8 __attribute__((ext_vector_type(8)));
typedef float f32x4  __attribute__((ext_vector_type(4)));

DI float bf2f(uint32_t u) { union { uint32_t i; float f; } v; v.i = u << 16; return v.f; }
DI uint16_t f2bf(float f) {
  union { float f; uint32_t i; } v; v.f = f;
  uint32_t x = v.i;
  return (uint16_t)((x + 0x7fffu + ((x >> 16) & 1u)) >> 16);
}
DI void unpack8(uint4 u, float* v) {
  v[0] = bf2f(u.x & 0xffffu); v[1] = bf2f(u.x >> 16);
  v[2] = bf2f(u.y & 0xffffu); v[3] = bf2f(u.y >> 16);
  v[4] = bf2f(u.z & 0xffffu); v[5] = bf2f(u.z >> 16);
  v[6] = bf2f(u.w & 0xffffu); v[7] = bf2f(u.w >> 16);
}

DI void ldsload16(const uint16_t* g, uint16_t* l) {
  __builtin_amdgcn_global_load_lds((const __attribute__((address_space(1))) void*)g,
                                   (__attribute__((address_space(3))) void*)l,
                                   16, 0, 0);
}

// ---------------- fused prep: probe + transpose + all conversions ------------
struct PrepArgs {
  const void* trees; const void* w1; const void* w2; const void* w3; const void* gw1;
  const void* b1; const void* b2; const void* b3; const void* gb1;
  const void* gw2; const void* gb2;
  const void* rw1; const void* rb1; const void* rw2; const void* rb2;
  const void* rw3; const void* rb3;
  uint16_t* treesT; uint16_t* W1b; uint16_t* W2b; uint16_t* W3b; uint16_t* GW1b;
  float* b1f; float* b2f; float* b3f; float* gb1f; float* gw2f; float* gb2f;
  float* rw1f; float* rb1f; float* rw2f; float* rb2f; float* rw3f; float* rb3f;
  int* flagp; float* statsAcc;
};

static constexpr int PREP_TRANS_END = 3584;   // 7 * 512 transpose blocks
static constexpr int PREP_W1_END    = 3840;   // 256 blocks
static constexpr int PREP_W2_END    = 4352;   // 512 blocks
static constexpr int PREP_W3_END    = 4608;   // 256 blocks
static constexpr int PREP_GW1_END   = 4640;   // 32 blocks
static constexpr int PREP_F32_END   = 4672;   // 32 blocks
  
DI void wcvt_range(const void* src, uint16_t* dst, int O, int C, int Cpad,
                   int isf32, int idx, int nb) {
  int Kpad = 3 * Cpad;
  int n = O * Kpad;
  int stride = nb * 256;
  for (int i = idx * 256 + (int)threadIdx.x; i < n; i += stride) {
    int o = i / Kpad, e = i - o * Kpad;
    int reg = e / Cpad, c = e - reg * Cpad;
    uint16_t v = 0;
    if (c < C) {
      int s = (o * C + c) * 3 + reg;
      v = isf32 ? f2bf(((const float*)src)[s]) : ((const uint16_t*)src)[s];
    }
    dst[i] = v;
  }
}

DI void fcvt_range(const void* src, float* dst, int n, int isf32, int idx, int nb) {
  int stride = nb * 256;
  for (int i = idx * 256 + (int)threadIdx.x; i < n; i += stride)
    dst[i] = isf32 ? ((const float*)src)[i] : bf2f(((const uint16_t*)src)[i]);
}

__global__ __launch_bounds__(256)
void prep_kernel(PrepArgs a) {
  __shared__ int cnt;
  __shared__ uint16_t sX[32][130];

  const int id = blockIdx.x;
  const int tx = threadIdx.x;

  // local dtype probe (cheap; trees head is L2-hot)
  if (tx == 0) cnt = 0;
  __syncthreads();
  {
    const uint16_t* t16 = (const uint16_t*)a.trees;
    int local = 0;
    #pragma unroll
    for (int q = 0; q < 2; q++) {
      uint16_t u = t16[tx * 2 + q];
      int ex = (u >> 7) & 0xff;
      if (ex >= 110 && ex <= 133) local++;
    }
    atomicAdd(&cnt, local);
  }
  __syncthreads();
  const int isf32 = (cnt >= 450) ? 0 : 1;

  if (id == 0) {
    if (tx == 0) *a.flagp = isf32;
    #pragma unroll
    for (int q = 0; q < 8; q++) a.statsAcc[q * 256 + tx] = 0.f;
  }

  if (id < PREP_TRANS_END) {
    // transpose trees[b][c][m] -> treesT[b][m(129)][256]
    const int b = id / 7, c0 = (id % 7) * 32;
    const int cn = min(32, 200 - c0);
    if (isf32) {
      const float* src = (const float*)a.trees + ((size_t)b * 200 + c0) * 128;
      for (int t = tx; t < cn * 128; t += 256) {
        int c = t >> 7, m = t & 127;
        sX[c][m] = f2bf(src[c * 128 + m]);
      }
    } else {
      const uint32_t* src = (const uint32_t*)((const uint16_t*)a.trees + ((size_t)b * 200 + c0) * 128);
      for (int t = tx; t < cn * 64; t += 256) {
        int c = t >> 6, p = t & 63;
        ((uint32_t*)&sX[c][0])[p] = src[c * 64 + p];
      }
    }
    __syncthreads();
    uint32_t* out = (uint32_t*)(a.treesT + (size_t)b * 129 * 256 + c0);
    for (int p = tx; p < 129 * 16; p += 256) {
      int m = p >> 4, u = p & 15;
      int c = u * 2;
      uint32_t v = 0;
      if (m < 128) {
        uint16_t lo = (c     < cn) ? sX[c][m]     : (uint16_t)0;
        uint16_t hi = (c + 1 < cn) ? sX[c + 1][m] : (uint16_t)0;
        v = (uint32_t)lo | ((uint32_t)hi << 16);
      }
      out[(size_t)m * 128 + u] = v;
    }
  } else if (id < PREP_W1_END) {
    wcvt_range(a.w1, a.W1b, 512, 200, 256, isf32, id - PREP_TRANS_END, PREP_W1_END - PREP_TRANS_END);
  } else if (id < PREP_W2_END) {
    wcvt_range(a.w2, a.W2b, 512, 512, 512, isf32, id - PREP_W1_END, PREP_W2_END - PREP_W1_END);
  } else if (id < PREP_W3_END) {
    wcvt_range(a.w3, a.W3b, 256, 512, 512, isf32, id - PREP_W2_END, PREP_W3_END - PREP_W2_END);
  } else if (id < PREP_GW1_END) {
    int idx = id - PREP_W3_END, nb = PREP_GW1_END - PREP_W3_END;
    int stride = nb * 256;
    for (int i = idx * 256 + tx; i < 128 * 256; i += stride)
      a.GW1b[i] = isf32 ? f2bf(((const float*)a.gw1)[i]) : ((const uint16_t*)a.gw1)[i];
  } else {
    int idx = id - PREP_GW1_END, nb = PREP_F32_END - PREP_GW1_END;
    fcvt_range(a.rw1, a.rw1f, 128 * 512, isf32, idx, nb);
    fcvt_range(a.rw2, a.rw2f, 64 * 128, isf32, idx, nb);
    if (idx == 0) {
      fcvt_range(a.b1, a.b1f, 512, isf32, 0, 1);
      fcvt_range(a.b2, a.b2f, 512, isf32, 0, 1);
      fcvt_range(a.b3, a.b3f, 256, isf32, 0, 1);
      fcvt_range(a.gb1, a.gb1f, 128, isf32, 0, 1);
      fcvt_range(a.gw2, a.gw2f, 128, isf32, 0, 1);
      fcvt_range(a.gb2, a.gb2f, 1, isf32, 0, 1);
      fcvt_range(a.rb1, a.rb1f, 128, isf32, 0, 1);
      fcvt_range(a.rb2, a.rb2f, 64, isf32, 0, 1);
      fcvt_range(a.rw3, a.rw3f, 64, isf32, 0, 1);
      fcvt_range(a.rb3, a.rb3f, 1, isf32, 0, 1);
    }
  }
}

// ---------------- fused gather+GEMM: yT[b][j][o] = conv(xT[b]) --------------
// 1D grid nO*B_, XCD-swizzled: all o-tiles of a batch land on one XCD.
__global__ __launch_bounds__(256, 4)
void gemm_kernel(const uint16_t* __restrict__ A,
                 const uint16_t* __restrict__ xT,
                 const int* __restrict__ idxg,
                 const float* __restrict__ bias,
                 uint16_t* __restrict__ Y,
                 int nO, int Cpad, int outRS,
                 float* __restrict__ statsAcc) {
  __shared__ __align__(16) uint16_t sA[128 * 64];
  __shared__ __align__(16) uint16_t sB[128 * 64];
  __shared__ float sBias[128];
  __shared__ int sIdx[384];
  __shared__ float2 sRed[256];

  const int id   = blockIdx.x;
  const int xcd  = id & 7;
  const int rest = id >> 3;
  const int ot   = rest % nO;
  const int b    = (rest / nO) * 8 + xcd;
  const int obase = ot * 128;
  const int O     = nO * 128;

  const int tx    = threadIdx.x;
  const int wave  = tx >> 6, lane = tx & 63;
  const int wj    = wave & 1, wo = wave >> 1;
  const int Kpad  = 3 * Cpad;

  for (int t = tx; t < N3_; t += 256) sIdx[t] = idxg[(size_t)b * N3_ + t];
  if (tx < 128) sBias[tx] = bias[obase + tx];
  __syncthreads();

  const uint16_t* Abase = A + (size_t)obase * Kpad;
  const uint16_t* Bbase = xT + (size_t)b * 129 * Cpad;

  const int srow = lane >> 3;
  const int schk = lane & 7;
  const int lm = lane & 15;
  const int kg = lane >> 4;

  f32x4 zero4 = {0.f, 0.f, 0.f, 0.f};
  f32x4 acc[4][4];
  #pragma unroll
  for (int i = 0; i < 4; i++)
    #pragma unroll
    for (int j = 0; j < 4; j++) acc[i][j] = zero4;

  for (int reg = 0; reg < 3; reg++) {
    int ridx[4];
    #pragma unroll
    for (int i = 0; i < 4; i++) {
      int r = wave * 8 + i * 32 + srow;
      ridx[i] = (r == 0) ? 128 : sIdx[3 * (r - 1) + reg];
    }
    for (int co = 0; co < Cpad; co += 64) {
      __syncthreads();
      #pragma unroll
      for (int i = 0; i < 4; i++) {
        int r  = wave * 8 + i * 32 + srow;
        int ca = schk ^ (r & 7);
        ldsload16(Abase + (size_t)r * Kpad + reg * Cpad + co + ca * 8,
                  &sA[(wave * 8 + i * 32) * 64]);
        ldsload16(Bbase + (size_t)ridx[i] * Cpad + co + ca * 8,
                  &sB[(wave * 8 + i * 32) * 64]);
      }
      __syncthreads();
      #pragma unroll
      for (int s = 0; s < 2; s++) {
        bf16x8 xv[4], wv[4];
        #pragma unroll
        for (int f = 0; f < 4; f++) {
          int rj = wj * 64 + f * 16 + lm;
          int cj = (s * 4 + kg) ^ (rj & 7);
          xv[f] = *(const bf16x8*)&sB[rj * 64 + cj * 8];
          int ro = wo * 64 + f * 16 + lm;
          int cw = (s * 4 + kg) ^ (ro & 7);
          wv[f] = *(const bf16x8*)&sA[ro * 64 + cw * 8];
        }
        #pragma unroll
        for (int fj = 0; fj < 4; fj++)
          #pragma unroll
          for (int fo = 0; fo < 4; fo++)
            acc[fj][fo] = __builtin_amdgcn_mfma_f32_16x16x32_bf16(xv[fj], wv[fo], acc[fj][fo], 0, 0, 0);
      }
    }
  }

  // epilogue: C rows = j, cols = o. bias, zero row j==0, stats, store yT.
  float s1 = 0.f, s2 = 0.f;
  #pragma unroll
  for (int fj = 0; fj < 4; fj++) {
    #pragma unroll
    for (int fo = 0; fo < 4; fo++) {
      int olocal = wo * 64 + fo * 16 + lm;
      float bo = sBias[olocal];
      #pragma unroll
      for (int r = 0; r < 4; r++) {
        int j = wj * 64 + fj * 16 + kg * 4 + r;
        float v = acc[fj][fo][r] + bo;
        if (j == 0) v = 0.f;
        s1 += v; s2 += v * v;
        Y[((size_t)b * outRS + j) * O + obase + olocal] = f2bf(v);
      }
    }
  }

  if (statsAcc) {
    sRed[tx] = make_float2(s1, s2);
    __syncthreads();
    for (int s = 128; s > 0; s >>= 1) {
      if (tx < s) { sRed[tx].x += sRed[tx + s].x; sRed[tx].y += sRed[tx + s].y; }
      __syncthreads();
    }
    if (tx == 0) {
      atomicAdd(&statsAcc[b * 2],     sRed[0].x);
      atomicAdd(&statsAcc[b * 2 + 1], sRed[0].y);
    }
  }
}

// ------- LN+ReLU in place on yT [B][129][512] (stats finalize inlined) ------
__global__ __launch_bounds__(256)
void ln_relu_kernel(uint16_t* __restrict__ y, const float* __restrict__ statsAcc,
                    float count) {
  const int total = B_ * 129 * 64;
  int stride = gridDim.x * blockDim.x;
  for (int i = blockIdx.x * blockDim.x + threadIdx.x; i < total; i += stride) {
    int rowG = i >> 6;
    int b = rowG / 129;
    int r = rowG - b * 129;
    uint4 out;
    if (r == 128) {
      out = make_uint4(0, 0, 0, 0);
    } else {
      float s = statsAcc[b * 2], ss = statsAcc[b * 2 + 1];
      float mean = s / count;
      float var = fmaxf((ss - s * s / count) / (count - 1.0f), 0.f);
      float scale = 1.0f / (sqrtf(var) + 1e-5f);
      uint4 u = ((const uint4*)y)[i];
      float v[8]; unpack8(u, v);
      uint32_t rr[4];
      #pragma unroll
      for (int k = 0; k < 4; k++) {
        float a  = fmaxf((v[2 * k]     - mean) * scale, 0.f);
        float bb = fmaxf((v[2 * k + 1] - mean) * scale, 0.f);
        rr[k] = (uint32_t)f2bf(a) | ((uint32_t)f2bf(bb) << 16);
      }
      out = make_uint4(rr[0], rr[1], rr[2], rr[3]);
    }
    ((uint4*)y)[i] = out;
  }
}

// ------ gate + softmax + pool + fused MLP head (emb = yT3 [B][128][256]) ----
__global__ __launch_bounds__(256)
void gate_kernel(const uint16_t* __restrict__ emb,
                 const uint16_t* __restrict__ gw1b,    // [128][256] bf16
                 const float* __restrict__ gb1,
                 const float* __restrict__ gw2, const float* __restrict__ gb2,
                 const float* __restrict__ rw1, const float* __restrict__ rb1,
                 const float* __restrict__ rw2, const float* __restrict__ rb2,
                 const float* __restrict__ rw3, const float* __restrict__ rb3,
                 void* __restrict__ dout, const int* __restrict__ flag) {
  __shared__ __align__(16) uint16_t sEmb[128 * 64];
  __shared__ float sRed[4][128];
  __shared__ float sSm[128];
  __shared__ float sAttn[128];
  __shared__ float sPool4[4 * 256];
  __shared__ __align__(16) float sC[512];
  __shared__ __align__(16) float sH1[128];
  __shared__ float sH2[64];

  const int b = blockIdx.x;
  const int tx = threadIdx.x;
  const int wave = tx >> 6, lane = tx & 63;
  const int lm = lane & 15, kg = lane >> 4;
  const int srow = lane >> 3, schk = lane & 7;
  const int h0 = wave * 32;
  const uint16_t* embB = emb + (size_t)b * 128 * 256;

  f32x4 zero4 = {0.f, 0.f, 0.f, 0.f};
  f32x4 acc[2][8];
  #pragma unroll
  for (int i = 0; i < 2; i++)
    #pragma unroll
    for (int t = 0; t < 8; t++) acc[i][t] = zero4;

  for (int kc = 0; kc < 256; kc += 64) {
    __syncthreads();
    #pragma unroll
    for (int i = 0; i < 4; i++) {
      int r  = wave * 8 + i * 32 + srow;
      int ca = schk ^ (r & 7);
      ldsload16(embB + (size_t)r * 256 + kc + ca * 8, &sEmb[(wave * 8 + i * 32) * 64]);
    }
    __syncthreads();
    #pragma unroll
    for (int s = 0; s < 2; s++) {
      bf16x8 a0 = *(const bf16x8*)(gw1b + (size_t)(h0 + lm) * 256 + kc + s * 32 + kg * 8);
      bf16x8 a1 = *(const bf16x8*)(gw1b + (size_t)(h0 + 16 + lm) * 256 + kc + s * 32 + kg * 8);
      #pragma unroll
      for (int t = 0; t < 8; t++) {
        int rn = t * 16 + lm;
        int cn = (s * 4 + kg) ^ (rn & 7);
        bf16x8 bv = *(const bf16x8*)&sEmb[rn * 64 + cn * 8];
        acc[0][t] = __builtin_amdgcn_mfma_f32_16x16x32_bf16(a0, bv, acc[0][t], 0, 0, 0);
        acc[1][t] = __builtin_amdgcn_mfma_f32_16x16x32_bf16(a1, bv, acc[1][t], 0, 0, 0);
      }
    }
  }

  float gb[2][4], gv[2][4];
  #pragma unroll
  for (int ht = 0; ht < 2; ht++)
    #pragma unroll
    for (int r = 0; r < 4; r++) {
      int h = h0 + ht * 16 + kg * 4 + r;
      gb[ht][r] = gb1[h]; gv[ht][r] = gw2[h];
    }
  float p[8];
  #pragma unroll
  for (int t = 0; t < 8; t++) {
    float s = 0.f;
    #pragma unroll
    for (int ht = 0; ht < 2; ht++)
      #pragma unroll
      for (int r = 0; r < 4; r++)
        s += fmaxf(acc[ht][t][r] + gb[ht][r], 0.f) * gv[ht][r];
    s += __shfl_xor(s, 16);
    s += __shfl_xor(s, 32);
    p[t] = s;
  }
  if (lane < 16) {
    #pragma unroll
    for (int t = 0; t < 8; t++) sRed[wave][t * 16 + lane] = p[t];
  }
  __syncthreads();

  float e = 0.f;
  if (tx < 128) {
    float v = sRed[0][tx] + sRed[1][tx] + sRed[2][tx] + sRed[3][tx] + gb2[0];
    sSm[tx] = v;
    sAttn[tx] = v;
  }
  __syncthreads();
  for (int s = 64; s > 0; s >>= 1) {
    if (tx < s) sSm[tx] = fmaxf(sSm[tx], sSm[tx + s]);
    __syncthreads();
  }
  float mx = sSm[0];
  __syncthreads();
  if (tx < 128) { e = expf(sAttn[tx] - mx); sSm[tx] = e; }
  __syncthreads();
  for (int s = 64; s > 0; s >>= 1) {
    if (tx < s) sSm[tx] += sSm[tx + s];
    __syncthreads();
  }
  float denom = sSm[0];
  __syncthreads();
  if (tx < 128) sAttn[tx] = e / denom;
  __syncthreads();

  // pool: wave covers 32 m rows, lane covers dwords {lane, lane+64}
  float pl00 = 0.f, pl01 = 0.f, pl10 = 0.f, pl11 = 0.f;
  const uint32_t* base = (const uint32_t*)embB;
  const int mw = wave * 32;
  for (int mi = 0; mi < 32; mi++) {
    float a = sAttn[mw + mi];
    uint32_t u0 = base[(size_t)(mw + mi) * 128 + lane];
    uint32_t u1 = base[(size_t)(mw + mi) * 128 + 64 + lane];
    pl00 = fmaf(a, bf2f(u0 & 0xffffu), pl00);
    pl01 = fmaf(a, bf2f(u0 >> 16),     pl01);
    pl10 = fmaf(a, bf2f(u1 & 0xffffu), pl10);
    pl11 = fmaf(a, bf2f(u1 >> 16),     pl11);
  }
  sPool4[wave * 256 + lane * 2]           = pl00;
  sPool4[wave * 256 + lane * 2 + 1]       = pl01;
  sPool4[wave * 256 + 128 + lane * 2]     = pl10;
  sPool4[wave * 256 + 128 + lane * 2 + 1] = pl11;
  __syncthreads();

  float pool = sPool4[tx] + sPool4[256 + tx] + sPool4[512 + tx] + sPool4[768 + tx];
  float root = bf2f(embB[256 + tx]);       // row m=1, f=tx
  sC[tx]       = root;
  sC[256 + tx] = pool;

  const int isf32 = (*flag != 0);
  if (!isf32) {
    uint16_t* o = ((uint16_t*)dout) + 512;
    o[b * 512 + tx]       = f2bf(root);
    o[b * 512 + 256 + tx] = f2bf(pool);
  } else {
    float* o = ((float*)dout) + 512;
    o[b * 512 + tx]       = root;
    o[b * 512 + 256 + tx] = pool;
  }
  __syncthreads();

  // fused MLP head
  if (tx < 128) {
    float a = rb1[tx];
    const float4* wr = (const float4*)(rw1 + (size_t)tx * 512);
    for (int i = 0; i < 128; i++) {
      float4 w4 = wr[i];
      float4 c4 = *(const float4*)&sC[i * 4];
      a = fmaf(w4.x, c4.x, a); a = fmaf(w4.y, c4.y, a);
      a = fmaf(w4.z, c4.z, a); a = fmaf(w4.w, c4.w, a);
    }
    sH1[tx] = fmaxf(a, 0.f);
  }
  __syncthreads();
  if (tx < 64) {
    float a2 = rb2[tx];
    const float4* wr2 = (const float4*)(rw2 + (size_t)tx * 128);
    for (int i = 0; i < 32; i++) {
      float4 w4 = wr2[i];
      float4 h4 = *(const float4*)&sH1[i * 4];
      a2 = fmaf(w4.x, h4.x, a2); a2 = fmaf(w4.y, h4.y, a2);
      a2 = fmaf(w4.z, h4.z, a2); a2 = fmaf(w4.w, h4.w, a2);
    }
    sH2[tx] = fmaxf(a2, 0.f);
  }
  __syncthreads();
  if (tx < 64) {
    float pv = sH2[tx] * rw3[tx];
    for (int off = 32; off > 0; off >>= 1) pv += __shfl_down(pv, off);
    if (tx == 0) {
      float o = pv + rb3[0];
      if (!isf32) ((uint16_t*)dout)[b] = f2bf(o);
      else        ((float*)dout)[b]    = o;
    }
  }
}

// ---------------- launch -----------------------------------------------------
extern "C" void kernel_launch(void* const* d_in, const int* in_sizes, int n_in,
                              void* d_out, int out_size, void* d_ws, size_t ws_size,
                              hipStream_t stream) {
  const void* trees   = d_in[0];
  const int*  indexes = (const int*)d_in[1];

  char* ws = (char*)d_ws;
  size_t off = 0;
  auto alloc = [&](size_t bytes) -> char* {
    char* p = ws + off;
    off += (bytes + 255) & ~(size_t)255;
    return p;
  };

  int*   flagp    = (int*)alloc(256);
  float* statsAcc = (float*)alloc(4 * B_ * sizeof(float));
  float* b1f = (float*)alloc(512 * 4);
  float* b2f = (float*)alloc(512 * 4);
  float* b3f = (float*)alloc(256 * 4);
  float* gb1f = (float*)alloc(128 * 4);
  float* gw2f = (float*)alloc(128 * 4);
  float* gb2f = (float*)alloc(4);
  float* rw1f = (float*)alloc(128 * 512 * 4);
  float* rb1f = (float*)alloc(128 * 4);
  float* rw2f = (float*)alloc(64 * 128 * 4);
  float* rb2f = (float*)alloc(64 * 4);
  float* rw3f = (float*)alloc(64 * 4);
  float* rb3f = (float*)alloc(4);
  uint16_t* W1b  = (uint16_t*)alloc((size_t)512 * 768 * 2);
  uint16_t* W2b  = (uint16_t*)alloc((size_t)512 * 1536 * 2);
  uint16_t* W3b  = (uint16_t*)alloc((size_t)256 * 1536 * 2);
  uint16_t* GW1b = (uint16_t*)alloc((size_t)128 * 256 * 2);
  uint16_t* bufA = (uint16_t*)alloc((size_t)B_ * 129 * 512 * 2);   // y1T, later yT3
  uint16_t* bufB = (uint16_t*)alloc((size_t)B_ * 129 * 512 * 2);   // treesT, later y2T

  uint16_t* treesT = bufB;            // [B][129][256]
  uint16_t* y1T    = bufA;            // [B][129][512]
  uint16_t* y2T    = bufB;            // [B][129][512]
  uint16_t* yT3    = bufA;            // [B][128][256]

  PrepArgs pa;
  pa.trees = trees;
  pa.w1 = d_in[2];  pa.b1 = d_in[3];
  pa.w2 = d_in[4];  pa.b2 = d_in[5];
  pa.w3 = d_in[6];  pa.b3 = d_in[7];
  pa.gw1 = d_in[8]; pa.gb1 = d_in[9];
  pa.gw2 = d_in[10]; pa.gb2 = d_in[11];
  pa.rw1 = d_in[12]; pa.rb1 = d_in[13];
  pa.rw2 = d_in[14]; pa.rb2 = d_in[15];
  pa.rw3 = d_in[16]; pa.rb3 = d_in[17];
  pa.treesT = treesT; pa.W1b = W1b; pa.W2b = W2b; pa.W3b = W3b; pa.GW1b = GW1b;
  pa.b1f = b1f; pa.b2f = b2f; pa.b3f = b3f; pa.gb1f = gb1f; pa.gw2f = gw2f; pa.gb2f = gb2f;
  pa.rw1f = rw1f; pa.rb1f = rb1f; pa.rw2f = rw2f; pa.rb2f = rb2f; pa.rw3f = rw3f; pa.rb3f = rb3f;
  pa.flagp = flagp; pa.statsAcc = statsAcc;

  prep_kernel<<<PREP_F32_END, 256, 0, stream>>>(pa);

  // ---- layer 1: Cpad=256 (K=768), in treesT, out y1T ----
  gemm_kernel<<<4 * B_, 256, 0, stream>>>(
      W1b, treesT, indexes, b1f, y1T, 4, 256, 129, statsAcc);
  ln_relu_kernel<<<2048, 256, 0, stream>>>(y1T, statsAcc, 65536.f);

  // ---- layer 2: Cpad=512 (K=1536), in y1T, out y2T ----
  gemm_kernel<<<4 * B_, 256, 0, stream>>>(
      W2b, y1T, indexes, b2f, y2T, 4, 512, 129, statsAcc + 2 * B_);
  ln_relu_kernel<<<2048, 256, 0, stream>>>(y2T, statsAcc + 2 * B_, 65536.f);

  // ---- layer 3: Cpad=512, O=256, out yT3 (no LN) ----
  gemm_kernel<<<2 * B_, 256, 0, stream>>>(
      W3b, y2T, indexes, b3f, yT3, 2, 512, 128, nullptr);

  // ---- gate + pool + fused head ----
  gate_kernel<<<B_, 256, 0, stream>>>(yT3, GW1b, gb1f, gw2f, gb2f,
                                      rw1f, rb1f, rw2f, rb2f, rw3f, rb3f,
                                      d_out, flagp);

  (void)in_sizes; (void)n_in; (void)out_size; (void)ws_size;
}

// Round 8
// 411.756 us; speedup vs baseline: 12.2834x; 1.0427x over previous
//
#include <hip/hip_runtime.h>
#include <stdint.h>

#define DI __device__ __forceinline__

static constexpr int B_   = 512;
static constexpr int N3_  = 381;

typedef short bf16x8 __attribute__((ext_vector_type(8)));
typedef float f32x4  __attribute__((ext_vector_type(4)));

DI float bf2f(uint32_t u) { union { uint32_t i; float f; } v; v.i = u << 16; return v.f; }
DI uint16_t f2bf(float f) {
  union { float f; uint32_t i; } v; v.f = f;
  uint32_t x = v.i;
  return (uint16_t)((x + 0x7fffu + ((x >> 16) & 1u)) >> 16);
}
DI void unpack8(uint4 u, float* v) {
  v[0] = bf2f(u.x & 0xffffu); v[1] = bf2f(u.x >> 16);
  v[2] = bf2f(u.y & 0xffffu); v[3] = bf2f(u.y >> 16);
  v[4] = bf2f(u.z & 0xffffu); v[5] = bf2f(u.z >> 16);
  v[6] = bf2f(u.w & 0xffffu); v[7] = bf2f(u.w >> 16);
}

DI void ldsload16(const uint16_t* g, uint16_t* l) {
  __builtin_amdgcn_global_load_lds((const __attribute__((address_space(1))) void*)g,
                                   (__attribute__((address_space(3))) void*)l,
                                   16, 0, 0);
}

// ---------------- fused prep: probe + transpose + all conversions ------------
struct PrepArgs {
  const void* trees; const void* w1; const void* w2; const void* w3; const void* gw1;
  const void* b1; const void* b2; const void* b3; const void* gb1;
  const void* gw2; const void* gb2;
  const void* rw1; const void* rb1; const void* rw2; const void* rb2;
  const void* rw3; const void* rb3;
  uint16_t* treesT; uint16_t* W1b; uint16_t* W2b; uint16_t* W3b; uint16_t* GW1b;
  float* b1f; float* b2f; float* b3f; float* gb1f; float* gw2f; float* gb2f;
  float* rw1f; float* rb1f; float* rw2f; float* rb2f; float* rw3f; float* rb3f;
  int* flagp; float* statsAcc;
};

static constexpr int PREP_TRANS_END = 3584;   // 7 * 512 transpose blocks
static constexpr int PREP_W1_END    = 3840;   // 256 blocks
static constexpr int PREP_W2_END    = 4352;   // 512 blocks
static constexpr int PREP_W3_END    = 4608;   // 256 blocks
static constexpr int PREP_GW1_END   = 4640;   // 32 blocks
static constexpr int PREP_F32_END   = 4672;   // 32 blocks

DI void wcvt_range(const void* src, uint16_t* dst, int O, int C, int Cpad,
                   int isf32, int idx, int nb) {
  int Kpad = 3 * Cpad;
  int n = O * Kpad;
  int stride = nb * 256;
  for (int i = idx * 256 + (int)threadIdx.x; i < n; i += stride) {
    int o = i / Kpad, e = i - o * Kpad;
    int reg = e / Cpad, c = e - reg * Cpad;
    uint16_t v = 0;
    if (c < C) {
      int s = (o * C + c) * 3 + reg;
      v = isf32 ? f2bf(((const float*)src)[s]) : ((const uint16_t*)src)[s];
    }
    dst[i] = v;
  }
}

DI void fcvt_range(const void* src, float* dst, int n, int isf32, int idx, int nb) {
  int stride = nb * 256;
  for (int i = idx * 256 + (int)threadIdx.x; i < n; i += stride)
    dst[i] = isf32 ? ((const float*)src)[i] : bf2f(((const uint16_t*)src)[i]);
}

__global__ __launch_bounds__(256)
void prep_kernel(PrepArgs a) {
  __shared__ int cnt;
  __shared__ uint16_t sX[32][130];

  const int id = blockIdx.x;
  const int tx = threadIdx.x;

  if (tx == 0) cnt = 0;
  __syncthreads();
  {
    const uint16_t* t16 = (const uint16_t*)a.trees;
    int local = 0;
    #pragma unroll
    for (int q = 0; q < 2; q++) {
      uint16_t u = t16[tx * 2 + q];
      int ex = (u >> 7) & 0xff;
      if (ex >= 110 && ex <= 133) local++;
    }
    atomicAdd(&cnt, local);
  }
  __syncthreads();
  const int isf32 = (cnt >= 450) ? 0 : 1;

  if (id == 0) {
    if (tx == 0) *a.flagp = isf32;
    #pragma unroll
    for (int q = 0; q < 8; q++) a.statsAcc[q * 256 + tx] = 0.f;
  }

  if (id < PREP_TRANS_END) {
    const int b = id / 7, c0 = (id % 7) * 32;
    const int cn = min(32, 200 - c0);
    if (isf32) {
      const float* src = (const float*)a.trees + ((size_t)b * 200 + c0) * 128;
      for (int t = tx; t < cn * 128; t += 256) {
        int c = t >> 7, m = t & 127;
        sX[c][m] = f2bf(src[c * 128 + m]);
      }
    } else {
      const uint32_t* src = (const uint32_t*)((const uint16_t*)a.trees + ((size_t)b * 200 + c0) * 128);
      for (int t = tx; t < cn * 64; t += 256) {
        int c = t >> 6, p = t & 63;
        ((uint32_t*)&sX[c][0])[p] = src[c * 64 + p];
      }
    }
    __syncthreads();
    uint32_t* out = (uint32_t*)(a.treesT + (size_t)b * 129 * 256 + c0);
    for (int p = tx; p < 129 * 16; p += 256) {
      int m = p >> 4, u = p & 15;
      int c = u * 2;
      uint32_t v = 0;
      if (m < 128) {
        uint16_t lo = (c     < cn) ? sX[c][m]     : (uint16_t)0;
        uint16_t hi = (c + 1 < cn) ? sX[c + 1][m] : (uint16_t)0;
        v = (uint32_t)lo | ((uint32_t)hi << 16);
      }
      out[(size_t)m * 128 + u] = v;
    }
  } else if (id < PREP_W1_END) {
    wcvt_range(a.w1, a.W1b, 512, 200, 256, isf32, id - PREP_TRANS_END, PREP_W1_END - PREP_TRANS_END);
  } else if (id < PREP_W2_END) {
    wcvt_range(a.w2, a.W2b, 512, 512, 512, isf32, id - PREP_W1_END, PREP_W2_END - PREP_W1_END);
  } else if (id < PREP_W3_END) {
    wcvt_range(a.w3, a.W3b, 256, 512, 512, isf32, id - PREP_W2_END, PREP_W3_END - PREP_W2_END);
  } else if (id < PREP_GW1_END) {
    int idx = id - PREP_W3_END, nb = PREP_GW1_END - PREP_W3_END;
    int stride = nb * 256;
    for (int i = idx * 256 + tx; i < 128 * 256; i += stride)
      a.GW1b[i] = isf32 ? f2bf(((const float*)a.gw1)[i]) : ((const uint16_t*)a.gw1)[i];
  } else {
    int idx = id - PREP_GW1_END, nb = PREP_F32_END - PREP_GW1_END;
    fcvt_range(a.rw1, a.rw1f, 128 * 512, isf32, idx, nb);
    fcvt_range(a.rw2, a.rw2f, 64 * 128, isf32, idx, nb);
    if (idx == 0) {
      fcvt_range(a.b1, a.b1f, 512, isf32, 0, 1);
      fcvt_range(a.b2, a.b2f, 512, isf32, 0, 1);
      fcvt_range(a.b3, a.b3f, 256, isf32, 0, 1);
      fcvt_range(a.gb1, a.gb1f, 128, isf32, 0, 1);
      fcvt_range(a.gw2, a.gw2f, 128, isf32, 0, 1);
      fcvt_range(a.gb2, a.gb2f, 1, isf32, 0, 1);
      fcvt_range(a.rb1, a.rb1f, 128, isf32, 0, 1);
      fcvt_range(a.rb2, a.rb2f, 64, isf32, 0, 1);
      fcvt_range(a.rw3, a.rw3f, 64, isf32, 0, 1);
      fcvt_range(a.rb3, a.rb3f, 1, isf32, 0, 1);
    }
  }
}

// ---------------- fused gather+GEMM: yT[b][j][o] = conv(xT[b]) --------------
// Block tile 128j x 256o, 4 waves in 2x2 grid, wave tile 64j x 128o.
// Staging: per 32-row set, wave w stages rows w*8..w*8+7 at a wave-uniform
// LDS base (global_load_lds requires wave-uniform dest + lane*16).
__global__ __launch_bounds__(256, 2)
void gemm_kernel(const uint16_t* __restrict__ A,     // weights [O][Kpad]
                 const uint16_t* __restrict__ xT,
                 const int* __restrict__ idxg,
                 const float* __restrict__ bias,
                 uint16_t* __restrict__ Y,
                 int nO, int Cpad, int outRS,
                 float* __restrict__ statsAcc) {
  __shared__ __align__(16) uint16_t sA[256 * 64];   // weight rows (o)
  __shared__ __align__(16) uint16_t sB[128 * 64];   // gathered x rows (j)
  __shared__ float sBias[256];
  __shared__ int sIdx[384];
  __shared__ float2 sRed[256];

  const int id   = blockIdx.x;
  const int xcd  = id & 7;
  const int rest = id >> 3;
  const int ot   = rest % nO;
  const int b    = (rest / nO) * 8 + xcd;
  const int obase = ot * 256;
  const int O     = nO * 256;

  const int tx    = threadIdx.x;
  const int wave  = tx >> 6, lane = tx & 63;
  const int wj    = wave & 1, wo = wave >> 1;
  const int Kpad  = 3 * Cpad;

  for (int t = tx; t < N3_; t += 256) sIdx[t] = idxg[(size_t)b * N3_ + t];
  sBias[tx] = bias[obase + tx];
  __syncthreads();

  const uint16_t* Abase = A + (size_t)obase * Kpad;
  const uint16_t* Bbase = xT + (size_t)b * 129 * Cpad;

  const int srow = lane >> 3;      // 0..7 within the wave's 8-row slice
  const int schk = lane & 7;       // chunk slot
  const int lm = lane & 15;
  const int kg = lane >> 4;

  f32x4 zero4 = {0.f, 0.f, 0.f, 0.f};
  f32x4 acc[4][8];
  #pragma unroll
  for (int i = 0; i < 4; i++)
    #pragma unroll
    for (int j = 0; j < 8; j++) acc[i][j] = zero4;

  for (int reg = 0; reg < 3; reg++) {
    int ridx[4];
    #pragma unroll
    for (int i = 0; i < 4; i++) {
      int r = i * 32 + wave * 8 + srow;
      ridx[i] = (r == 0) ? 128 : sIdx[3 * (r - 1) + reg];
    }
    for (int co = 0; co < Cpad; co += 64) {
      __syncthreads();
      #pragma unroll
      for (int i = 0; i < 8; i++) {        // A: 256 weight rows, 8 per wave/set
        int r  = i * 32 + wave * 8 + srow;
        int ca = schk ^ (r & 7);
        ldsload16(Abase + (size_t)r * Kpad + reg * Cpad + co + ca * 8,
                  &sA[(i * 32 + wave * 8) * 64]);
      }
      #pragma unroll
      for (int i = 0; i < 4; i++) {        // B: 128 gathered x rows
        int r  = i * 32 + wave * 8 + srow;
        int ca = schk ^ (r & 7);
        ldsload16(Bbase + (size_t)ridx[i] * Cpad + co + ca * 8,
                  &sB[(i * 32 + wave * 8) * 64]);
      }
      __syncthreads();
      #pragma unroll
      for (int s = 0; s < 2; s++) {
        bf16x8 xv[4], wv[8];
        #pragma unroll
        for (int f = 0; f < 4; f++) {
          int rj = wj * 64 + f * 16 + lm;
          int cj = (s * 4 + kg) ^ (rj & 7);
          xv[f] = *(const bf16x8*)&sB[rj * 64 + cj * 8];
        }
        #pragma unroll
        for (int f = 0; f < 8; f++) {
          int ro = wo * 128 + f * 16 + lm;
          int cw = (s * 4 + kg) ^ (ro & 7);
          wv[f] = *(const bf16x8*)&sA[ro * 64 + cw * 8];
        }
        #pragma unroll
        for (int fj = 0; fj < 4; fj++)
          #pragma unroll
          for (int fo = 0; fo < 8; fo++)
            acc[fj][fo] = __builtin_amdgcn_mfma_f32_16x16x32_bf16(xv[fj], wv[fo], acc[fj][fo], 0, 0, 0);
      }
    }
  }

  // epilogue: C rows = j, cols = o. bias, zero row j==0, stats, store yT.
  float s1 = 0.f, s2 = 0.f;
  #pragma unroll
  for (int fj = 0; fj < 4; fj++) {
    #pragma unroll
    for (int fo = 0; fo < 8; fo++) {
      int olocal = wo * 128 + fo * 16 + lm;
      float bo = sBias[olocal];
      #pragma unroll
      for (int r = 0; r < 4; r++) {
        int j = wj * 64 + fj * 16 + kg * 4 + r;
        float v = acc[fj][fo][r] + bo;
        if (j == 0) v = 0.f;
        s1 += v; s2 += v * v;
        Y[((size_t)b * outRS + j) * O + obase + olocal] = f2bf(v);
      }
    }
  }

  if (statsAcc) {
    sRed[tx] = make_float2(s1, s2);
    __syncthreads();
    for (int s = 128; s > 0; s >>= 1) {
      if (tx < s) { sRed[tx].x += sRed[tx + s].x; sRed[tx].y += sRed[tx + s].y; }
      __syncthreads();
    }
    if (tx == 0) {
      atomicAdd(&statsAcc[b * 2],     sRed[0].x);
      atomicAdd(&statsAcc[b * 2 + 1], sRed[0].y);
    }
  }
}

// ------- LN+ReLU in place on yT [B][129][512] (stats finalize inlined) ------
__global__ __launch_bounds__(256)
void ln_relu_kernel(uint16_t* __restrict__ y, const float* __restrict__ statsAcc,
                    float count) {
  const int total = B_ * 129 * 64;
  int stride = gridDim.x * blockDim.x;
  for (int i = blockIdx.x * blockDim.x + threadIdx.x; i < total; i += stride) {
    int rowG = i >> 6;
    int b = rowG / 129;
    int r = rowG - b * 129;
    uint4 out;
    if (r == 128) {
      out = make_uint4(0, 0, 0, 0);
    } else {
      float s = statsAcc[b * 2], ss = statsAcc[b * 2 + 1];
      float mean = s / count;
      float var = fmaxf((ss - s * s / count) / (count - 1.0f), 0.f);
      float scale = 1.0f / (sqrtf(var) + 1e-5f);
      uint4 u = ((const uint4*)y)[i];
      float v[8]; unpack8(u, v);
      uint32_t rr[4];
      #pragma unroll
      for (int k = 0; k < 4; k++) {
        float a  = fmaxf((v[2 * k]     - mean) * scale, 0.f);
        float bb = fmaxf((v[2 * k + 1] - mean) * scale, 0.f);
        rr[k] = (uint32_t)f2bf(a) | ((uint32_t)f2bf(bb) << 16);
      }
      out = make_uint4(rr[0], rr[1], rr[2], rr[3]);
    }
    ((uint4*)y)[i] = out;
  }
}

// ------ gate + softmax + pool + fused MLP head (emb = yT3 [B][128][256]) ----
__global__ __launch_bounds__(256)
void gate_kernel(const uint16_t* __restrict__ emb,
                 const uint16_t* __restrict__ gw1b,    // [128][256] bf16
                 const float* __restrict__ gb1,
                 const float* __restrict__ gw2, const float* __restrict__ gb2,
                 const float* __restrict__ rw1, const float* __restrict__ rb1,
                 const float* __restrict__ rw2, const float* __restrict__ rb2,
                 const float* __restrict__ rw3, const float* __restrict__ rb3,
                 void* __restrict__ dout, const int* __restrict__ flag) {
  __shared__ __align__(16) uint16_t sEmb[128 * 64];
  __shared__ float sRed[4][128];
  __shared__ float sSm[128];
  __shared__ float sAttn[128];
  __shared__ float sPool4[4 * 256];
  __shared__ __align__(16) float sC[512];
  __shared__ __align__(16) float sH1[128];
  __shared__ float sH2[64];

  const int b = blockIdx.x;
  const int tx = threadIdx.x;
  const int wave = tx >> 6, lane = tx & 63;
  const int lm = lane & 15, kg = lane >> 4;
  const int srow = lane >> 3, schk = lane & 7;
  const int h0 = wave * 32;
  const uint16_t* embB = emb + (size_t)b * 128 * 256;

  f32x4 zero4 = {0.f, 0.f, 0.f, 0.f};
  f32x4 acc[2][8];
  #pragma unroll
  for (int i = 0; i < 2; i++)
    #pragma unroll
    for (int t = 0; t < 8; t++) acc[i][t] = zero4;

  for (int kc = 0; kc < 256; kc += 64) {
    __syncthreads();
    #pragma unroll
    for (int i = 0; i < 4; i++) {
      int r  = wave * 8 + i * 32 + srow;
      int ca = schk ^ (r & 7);
      ldsload16(embB + (size_t)r * 256 + kc + ca * 8, &sEmb[(wave * 8 + i * 32) * 64]);
    }
    __syncthreads();
    #pragma unroll
    for (int s = 0; s < 2; s++) {
      bf16x8 a0 = *(const bf16x8*)(gw1b + (size_t)(h0 + lm) * 256 + kc + s * 32 + kg * 8);
      bf16x8 a1 = *(const bf16x8*)(gw1b + (size_t)(h0 + 16 + lm) * 256 + kc + s * 32 + kg * 8);
      #pragma unroll
      for (int t = 0; t < 8; t++) {
        int rn = t * 16 + lm;
        int cn = (s * 4 + kg) ^ (rn & 7);
        bf16x8 bv = *(const bf16x8*)&sEmb[rn * 64 + cn * 8];
        acc[0][t] = __builtin_amdgcn_mfma_f32_16x16x32_bf16(a0, bv, acc[0][t], 0, 0, 0);
        acc[1][t] = __builtin_amdgcn_mfma_f32_16x16x32_bf16(a1, bv, acc[1][t], 0, 0, 0);
      }
    }
  }

  float gb[2][4], gv[2][4];
  #pragma unroll
  for (int ht = 0; ht < 2; ht++)
    #pragma unroll
    for (int r = 0; r < 4; r++) {
      int h = h0 + ht * 16 + kg * 4 + r;
      gb[ht][r] = gb1[h]; gv[ht][r] = gw2[h];
    }
  float p[8];
  #pragma unroll
  for (int t = 0; t < 8; t++) {
    float s = 0.f;
    #pragma unroll
    for (int ht = 0; ht < 2; ht++)
      #pragma unroll
      for (int r = 0; r < 4; r++)
        s += fmaxf(acc[ht][t][r] + gb[ht][r], 0.f) * gv[ht][r];
    s += __shfl_xor(s, 16);
    s += __shfl_xor(s, 32);
    p[t] = s;
  }
  if (lane < 16) {
    #pragma unroll
    for (int t = 0; t < 8; t++) sRed[wave][t * 16 + lane] = p[t];
  }
  __syncthreads();

  float e = 0.f;
  if (tx < 128) {
    float v = sRed[0][tx] + sRed[1][tx] + sRed[2][tx] + sRed[3][tx] + gb2[0];
    sSm[tx] = v;
    sAttn[tx] = v;
  }
  __syncthreads();
  for (int s = 64; s > 0; s >>= 1) {
    if (tx < s) sSm[tx] = fmaxf(sSm[tx], sSm[tx + s]);
    __syncthreads();
  }
  float mx = sSm[0];
  __syncthreads();
  if (tx < 128) { e = expf(sAttn[tx] - mx); sSm[tx] = e; }
  __syncthreads();
  for (int s = 64; s > 0; s >>= 1) {
    if (tx < s) sSm[tx] += sSm[tx + s];
    __syncthreads();
  }
  float denom = sSm[0];
  __syncthreads();
  if (tx < 128) sAttn[tx] = e / denom;
  __syncthreads();

  float pl00 = 0.f, pl01 = 0.f, pl10 = 0.f, pl11 = 0.f;
  const uint32_t* base = (const uint32_t*)embB;
  const int mw = wave * 32;
  for (int mi = 0; mi < 32; mi++) {
    float a = sAttn[mw + mi];
    uint32_t u0 = base[(size_t)(mw + mi) * 128 + lane];
    uint32_t u1 = base[(size_t)(mw + mi) * 128 + 64 + lane];
    pl00 = fmaf(a, bf2f(u0 & 0xffffu), pl00);
    pl01 = fmaf(a, bf2f(u0 >> 16),     pl01);
    pl10 = fmaf(a, bf2f(u1 & 0xffffu), pl10);
    pl11 = fmaf(a, bf2f(u1 >> 16),     pl11);
  }
  sPool4[wave * 256 + lane * 2]           = pl00;
  sPool4[wave * 256 + lane * 2 + 1]       = pl01;
  sPool4[wave * 256 + 128 + lane * 2]     = pl10;
  sPool4[wave * 256 + 128 + lane * 2 + 1] = pl11;
  __syncthreads();

  float pool = sPool4[tx] + sPool4[256 + tx] + sPool4[512 + tx] + sPool4[768 + tx];
  float root = bf2f(embB[256 + tx]);       // row m=1, f=tx
  sC[tx]       = root;
  sC[256 + tx] = pool;

  const int isf32 = (*flag != 0);
  if (!isf32) {
    uint16_t* o = ((uint16_t*)dout) + 512;
    o[b * 512 + tx]       = f2bf(root);
    o[b * 512 + 256 + tx] = f2bf(pool);
  } else {
    float* o = ((float*)dout) + 512;
    o[b * 512 + tx]       = root;
    o[b * 512 + 256 + tx] = pool;
  }
  __syncthreads();

  if (tx < 128) {
    float a = rb1[tx];
    const float4* wr = (const float4*)(rw1 + (size_t)tx * 512);
    for (int i = 0; i < 128; i++) {
      float4 w4 = wr[i];
      float4 c4 = *(const float4*)&sC[i * 4];
      a = fmaf(w4.x, c4.x, a); a = fmaf(w4.y, c4.y, a);
      a = fmaf(w4.z, c4.z, a); a = fmaf(w4.w, c4.w, a);
    }
    sH1[tx] = fmaxf(a, 0.f);
  }
  __syncthreads();
  if (tx < 64) {
    float a2 = rb2[tx];
    const float4* wr2 = (const float4*)(rw2 + (size_t)tx * 128);
    for (int i = 0; i < 32; i++) {
      float4 w4 = wr2[i];
      float4 h4 = *(const float4*)&sH1[i * 4];
      a2 = fmaf(w4.x, h4.x, a2); a2 = fmaf(w4.y, h4.y, a2);
      a2 = fmaf(w4.z, h4.z, a2); a2 = fmaf(w4.w, h4.w, a2);
    }
    sH2[tx] = fmaxf(a2, 0.f);
  }
  __syncthreads();
  if (tx < 64) {
    float pv = sH2[tx] * rw3[tx];
    for (int off = 32; off > 0; off >>= 1) pv += __shfl_down(pv, off);
    if (tx == 0) {
      float o = pv + rb3[0];
      if (!isf32) ((uint16_t*)dout)[b] = f2bf(o);
      else        ((float*)dout)[b]    = o;
    }
  }
}

// ---------------- launch -----------------------------------------------------
extern "C" void kernel_launch(void* const* d_in, const int* in_sizes, int n_in,
                              void* d_out, int out_size, void* d_ws, size_t ws_size,
                              hipStream_t stream) {
  const void* trees   = d_in[0];
  const int*  indexes = (const int*)d_in[1];

  char* ws = (char*)d_ws;
  size_t off = 0;
  auto alloc = [&](size_t bytes) -> char* {
    char* p = ws + off;
    off += (bytes + 255) & ~(size_t)255;
    return p;
  };

  int*   flagp    = (int*)alloc(256);
  float* statsAcc = (float*)alloc(4 * B_ * sizeof(float));
  float* b1f = (float*)alloc(512 * 4);
  float* b2f = (float*)alloc(512 * 4);
  float* b3f = (float*)alloc(256 * 4);
  float* gb1f = (float*)alloc(128 * 4);
  float* gw2f = (float*)alloc(128 * 4);
  float* gb2f = (float*)alloc(4);
  float* rw1f = (float*)alloc(128 * 512 * 4);
  float* rb1f = (float*)alloc(128 * 4);
  float* rw2f = (float*)alloc(64 * 128 * 4);
  float* rb2f = (float*)alloc(64 * 4);
  float* rw3f = (float*)alloc(64 * 4);
  float* rb3f = (float*)alloc(4);
  uint16_t* W1b  = (uint16_t*)alloc((size_t)512 * 768 * 2);
  uint16_t* W2b  = (uint16_t*)alloc((size_t)512 * 1536 * 2);
  uint16_t* W3b  = (uint16_t*)alloc((size_t)256 * 1536 * 2);
  uint16_t* GW1b = (uint16_t*)alloc((size_t)128 * 256 * 2);
  uint16_t* bufA = (uint16_t*)alloc((size_t)B_ * 129 * 512 * 2);   // y1T, later yT3
  uint16_t* bufB = (uint16_t*)alloc((size_t)B_ * 129 * 512 * 2);   // treesT, later y2T

  uint16_t* treesT = bufB;            // [B][129][256]
  uint16_t* y1T    = bufA;            // [B][129][512]
  uint16_t* y2T    = bufB;            // [B][129][512]
  uint16_t* yT3    = bufA;            // [B][128][256]

  PrepArgs pa;
  pa.trees = trees;
  pa.w1 = d_in[2];  pa.b1 = d_in[3];
  pa.w2 = d_in[4];  pa.b2 = d_in[5];
  pa.w3 = d_in[6];  pa.b3 = d_in[7];
  pa.gw1 = d_in[8]; pa.gb1 = d_in[9];
  pa.gw2 = d_in[10]; pa.gb2 = d_in[11];
  pa.rw1 = d_in[12]; pa.rb1 = d_in[13];
  pa.rw2 = d_in[14]; pa.rb2 = d_in[15];
  pa.rw3 = d_in[16]; pa.rb3 = d_in[17];
  pa.treesT = treesT; pa.W1b = W1b; pa.W2b = W2b; pa.W3b = W3b; pa.GW1b = GW1b;
  pa.b1f = b1f; pa.b2f = b2f; pa.b3f = b3f; pa.gb1f = gb1f; pa.gw2f = gw2f; pa.gb2f = gb2f;
  pa.rw1f = rw1f; pa.rb1f = rb1f; pa.rw2f = rw2f; pa.rb2f = rb2f; pa.rw3f = rw3f; pa.rb3f = rb3f;
  pa.flagp = flagp; pa.statsAcc = statsAcc;

  prep_kernel<<<PREP_F32_END, 256, 0, stream>>>(pa);

  // ---- layer 1: Cpad=256 (K=768), in treesT, out y1T ----
  gemm_kernel<<<2 * B_, 256, 0, stream>>>(
      W1b, treesT, indexes, b1f, y1T, 2, 256, 129, statsAcc);
  ln_relu_kernel<<<2048, 256, 0, stream>>>(y1T, statsAcc, 65536.f);

  // ---- layer 2: Cpad=512 (K=1536), in y1T, out y2T ----
  gemm_kernel<<<2 * B_, 256, 0, stream>>>(
      W2b, y1T, indexes, b2f, y2T, 2, 512, 129, statsAcc + 2 * B_);
  ln_relu_kernel<<<2048, 256, 0, stream>>>(y2T, statsAcc + 2 * B_, 65536.f);

  // ---- layer 3: Cpad=512, O=256 (one 256-tile), out yT3 (no LN) ----
  gemm_kernel<<<B_, 256, 0, stream>>>(
      W3b, y2T, indexes, b3f, yT3, 1, 512, 128, nullptr);

  // ---- gate + pool + fused head ----
  gate_kernel<<<B_, 256, 0, stream>>>(yT3, GW1b, gb1f, gw2f, gb2f,
                                      rw1f, rb1f, rw2f, rb2f, rw3f, rb3f,
                                      d_out, flagp);

  (void)in_sizes; (void)n_in; (void)out_size; (void)ws_size;
}

// Round 9
// 386.146 us; speedup vs baseline: 13.0980x; 1.0663x over previous
//
#include <hip/hip_runtime.h>
#include <stdint.h>

#define DI __device__ __forceinline__

static constexpr int B_   = 512;
static constexpr int N3_  = 381;

typedef short bf16x8 __attribute__((ext_vector_type(8)));
typedef float f32x4  __attribute__((ext_vector_type(4)));

DI float bf2f(uint32_t u) { union { uint32_t i; float f; } v; v.i = u << 16; return v.f; }
DI uint16_t f2bf(float f) {
  union { float f; uint32_t i; } v; v.f = f;
  uint32_t x = v.i;
  return (uint16_t)((x + 0x7fffu + ((x >> 16) & 1u)) >> 16);
}
DI void unpack8(uint4 u, float* v) {
  v[0] = bf2f(u.x & 0xffffu); v[1] = bf2f(u.x >> 16);
  v[2] = bf2f(u.y & 0xffffu); v[3] = bf2f(u.y >> 16);
  v[4] = bf2f(u.z & 0xffffu); v[5] = bf2f(u.z >> 16);
  v[6] = bf2f(u.w & 0xffffu); v[7] = bf2f(u.w >> 16);
}

DI void ldsload16(const uint16_t* g, uint16_t* l) {
  __builtin_amdgcn_global_load_lds((const __attribute__((address_space(1))) void*)g,
                                   (__attribute__((address_space(3))) void*)l,
                                   16, 0, 0);
}

// ---------------- fused prep: probe + transpose + all conversions ------------
struct PrepArgs {
  const void* trees; const void* w1; const void* w2; const void* w3; const void* gw1;
  const void* b1; const void* b2; const void* b3; const void* gb1;
  const void* gw2; const void* gb2;
  const void* rw1; const void* rb1; const void* rw2; const void* rb2;
  const void* rw3; const void* rb3;
  uint16_t* treesT; uint16_t* W1b; uint16_t* W2b; uint16_t* W3b; uint16_t* GW1b;
  float* b1f; float* b2f; float* b3f; float* gb1f; float* gw2f; float* gb2f;
  float* rw1f; float* rb1f; float* rw2f; float* rb2f; float* rw3f; float* rb3f;
  int* flagp; float* statsAcc;
};

static constexpr int PREP_TRANS_END = 3584;   // 7 * 512 transpose blocks
static constexpr int PREP_W1_END    = 3840;
static constexpr int PREP_W2_END    = 4352;
static constexpr int PREP_W3_END    = 4608;
static constexpr int PREP_GW1_END   = 4640;
static constexpr int PREP_F32_END   = 4672;

DI void wcvt_range(const void* src, uint16_t* dst, int O, int C, int Cpad,
                   int isf32, int idx, int nb) {
  int Kpad = 3 * Cpad;
  int n = O * Kpad;
  int stride = nb * 256;
  for (int i = idx * 256 + (int)threadIdx.x; i < n; i += stride) {
    int o = i / Kpad, e = i - o * Kpad;
    int reg = e / Cpad, c = e - reg * Cpad;
    uint16_t v = 0;
    if (c < C) {
      int s = (o * C + c) * 3 + reg;
      v = isf32 ? f2bf(((const float*)src)[s]) : ((const uint16_t*)src)[s];
    }
    dst[i] = v;
  }
}

DI void fcvt_range(const void* src, float* dst, int n, int isf32, int idx, int nb) {
  int stride = nb * 256;
  for (int i = idx * 256 + (int)threadIdx.x; i < n; i += stride)
    dst[i] = isf32 ? ((const float*)src)[i] : bf2f(((const uint16_t*)src)[i]);
}

__global__ __launch_bounds__(256)
void prep_kernel(PrepArgs a) {
  __shared__ int cnt;
  __shared__ uint16_t sX[32][130];

  const int id = blockIdx.x;
  const int tx = threadIdx.x;

  if (tx == 0) cnt = 0;
  __syncthreads();
  {
    const uint16_t* t16 = (const uint16_t*)a.trees;
    int local = 0;
    #pragma unroll
    for (int q = 0; q < 2; q++) {
      uint16_t u = t16[tx * 2 + q];
      int ex = (u >> 7) & 0xff;
      if (ex >= 110 && ex <= 133) local++;
    }
    atomicAdd(&cnt, local);
  }
  __syncthreads();
  const int isf32 = (cnt >= 450) ? 0 : 1;

  if (id == 0) {
    if (tx == 0) *a.flagp = isf32;
    #pragma unroll
    for (int q = 0; q < 8; q++) a.statsAcc[q * 256 + tx] = 0.f;
  }

  if (id < PREP_TRANS_END) {
    const int b = id / 7, c0 = (id % 7) * 32;
    const int cn = min(32, 200 - c0);
    if (isf32) {
      const float* src = (const float*)a.trees + ((size_t)b * 200 + c0) * 128;
      for (int t = tx; t < cn * 128; t += 256) {
        int c = t >> 7, m = t & 127;
        sX[c][m] = f2bf(src[c * 128 + m]);
      }
    } else {
      const uint32_t* src = (const uint32_t*)((const uint16_t*)a.trees + ((size_t)b * 200 + c0) * 128);
      for (int t = tx; t < cn * 64; t += 256) {
        int c = t >> 6, p = t & 63;
        ((uint32_t*)&sX[c][0])[p] = src[c * 64 + p];
      }
    }
    __syncthreads();
    uint32_t* out = (uint32_t*)(a.treesT + (size_t)b * 129 * 256 + c0);
    for (int p = tx; p < 129 * 16; p += 256) {
      int m = p >> 4, u = p & 15;
      int c = u * 2;
      uint32_t v = 0;
      if (m < 128) {
        uint16_t lo = (c     < cn) ? sX[c][m]     : (uint16_t)0;
        uint16_t hi = (c + 1 < cn) ? sX[c + 1][m] : (uint16_t)0;
        v = (uint32_t)lo | ((uint32_t)hi << 16);
      }
      out[(size_t)m * 128 + u] = v;
    }
  } else if (id < PREP_W1_END) {
    wcvt_range(a.w1, a.W1b, 512, 200, 256, isf32, id - PREP_TRANS_END, PREP_W1_END - PREP_TRANS_END);
  } else if (id < PREP_W2_END) {
    wcvt_range(a.w2, a.W2b, 512, 512, 512, isf32, id - PREP_W1_END, PREP_W2_END - PREP_W1_END);
  } else if (id < PREP_W3_END) {
    wcvt_range(a.w3, a.W3b, 256, 512, 512, isf32, id - PREP_W2_END, PREP_W3_END - PREP_W2_END);
  } else if (id < PREP_GW1_END) {
    int idx = id - PREP_W3_END, nb = PREP_GW1_END - PREP_W3_END;
    int stride = nb * 256;
    for (int i = idx * 256 + tx; i < 128 * 256; i += stride)
      a.GW1b[i] = isf32 ? f2bf(((const float*)a.gw1)[i]) : ((const uint16_t*)a.gw1)[i];
  } else {
    int idx = id - PREP_GW1_END, nb = PREP_F32_END - PREP_GW1_END;
    fcvt_range(a.rw1, a.rw1f, 128 * 512, isf32, idx, nb);
    fcvt_range(a.rw2, a.rw2f, 64 * 128, isf32, idx, nb);
    if (idx == 0) {
      fcvt_range(a.b1, a.b1f, 512, isf32, 0, 1);
      fcvt_range(a.b2, a.b2f, 512, isf32, 0, 1);
      fcvt_range(a.b3, a.b3f, 256, isf32, 0, 1);
      fcvt_range(a.gb1, a.gb1f, 128, isf32, 0, 1);
      fcvt_range(a.gw2, a.gw2f, 128, isf32, 0, 1);
      fcvt_range(a.gb2, a.gb2f, 1, isf32, 0, 1);
      fcvt_range(a.rb1, a.rb1f, 128, isf32, 0, 1);
      fcvt_range(a.rb2, a.rb2f, 64, isf32, 0, 1);
      fcvt_range(a.rw3, a.rw3f, 64, isf32, 0, 1);
      fcvt_range(a.rb3, a.rb3f, 1, isf32, 0, 1);
    }
  }
}

// ---------------- fused gather+GEMM (layers 1,2): yT[b][j][o] ----------------
// Block tile 128j x 256o, 4 waves 2x2, wave tile 64j x 128o.
__global__ __launch_bounds__(256, 2)
void gemm_kernel(const uint16_t* __restrict__ A,
                 const uint16_t* __restrict__ xT,
                 const int* __restrict__ idxg,
                 const float* __restrict__ bias,
                 uint16_t* __restrict__ Y,
                 int nO, int Cpad, int outRS,
                 float* __restrict__ statsAcc) {
  __shared__ __align__(16) uint16_t sA[256 * 64];
  __shared__ __align__(16) uint16_t sB[128 * 64];
  __shared__ float sBias[256];
  __shared__ int sIdx[384];
  __shared__ float2 sRed[256];

  const int id   = blockIdx.x;
  const int xcd  = id & 7;
  const int rest = id >> 3;
  const int ot   = rest % nO;
  const int b    = (rest / nO) * 8 + xcd;
  const int obase = ot * 256;
  const int O     = nO * 256;

  const int tx    = threadIdx.x;
  const int wave  = tx >> 6, lane = tx & 63;
  const int wj    = wave & 1, wo = wave >> 1;
  const int Kpad  = 3 * Cpad;

  for (int t = tx; t < N3_; t += 256) sIdx[t] = idxg[(size_t)b * N3_ + t];
  sBias[tx] = bias[obase + tx];
  __syncthreads();

  const uint16_t* Abase = A + (size_t)obase * Kpad;
  const uint16_t* Bbase = xT + (size_t)b * 129 * Cpad;

  const int srow = lane >> 3;
  const int schk = lane & 7;
  const int lm = lane & 15;
  const int kg = lane >> 4;

  f32x4 zero4 = {0.f, 0.f, 0.f, 0.f};
  f32x4 acc[4][8];
  #pragma unroll
  for (int i = 0; i < 4; i++)
    #pragma unroll
    for (int j = 0; j < 8; j++) acc[i][j] = zero4;

  for (int reg = 0; reg < 3; reg++) {
    int ridx[4];
    #pragma unroll
    for (int i = 0; i < 4; i++) {
      int r = i * 32 + wave * 8 + srow;
      ridx[i] = (r == 0) ? 128 : sIdx[3 * (r - 1) + reg];
    }
    for (int co = 0; co < Cpad; co += 64) {
      __syncthreads();
      #pragma unroll
      for (int i = 0; i < 8; i++) {
        int r  = i * 32 + wave * 8 + srow;
        int ca = schk ^ (r & 7);
        ldsload16(Abase + (size_t)r * Kpad + reg * Cpad + co + ca * 8,
                  &sA[(i * 32 + wave * 8) * 64]);
      }
      #pragma unroll
      for (int i = 0; i < 4; i++) {
        int r  = i * 32 + wave * 8 + srow;
        int ca = schk ^ (r & 7);
        ldsload16(Bbase + (size_t)ridx[i] * Cpad + co + ca * 8,
                  &sB[(i * 32 + wave * 8) * 64]);
      }
      __syncthreads();
      #pragma unroll
      for (int s = 0; s < 2; s++) {
        bf16x8 xv[4], wv[8];
        #pragma unroll
        for (int f = 0; f < 4; f++) {
          int rj = wj * 64 + f * 16 + lm;
          int cj = (s * 4 + kg) ^ (rj & 7);
          xv[f] = *(const bf16x8*)&sB[rj * 64 + cj * 8];
        }
        #pragma unroll
        for (int f = 0; f < 8; f++) {
          int ro = wo * 128 + f * 16 + lm;
          int cw = (s * 4 + kg) ^ (ro & 7);
          wv[f] = *(const bf16x8*)&sA[ro * 64 + cw * 8];
        }
        #pragma unroll
        for (int fj = 0; fj < 4; fj++)
          #pragma unroll
          for (int fo = 0; fo < 8; fo++)
            acc[fj][fo] = __builtin_amdgcn_mfma_f32_16x16x32_bf16(xv[fj], wv[fo], acc[fj][fo], 0, 0, 0);
      }
    }
  }

  float s1 = 0.f, s2 = 0.f;
  #pragma unroll
  for (int fj = 0; fj < 4; fj++) {
    #pragma unroll
    for (int fo = 0; fo < 8; fo++) {
      int olocal = wo * 128 + fo * 16 + lm;
      float bo = sBias[olocal];
      #pragma unroll
      for (int r = 0; r < 4; r++) {
        int j = wj * 64 + fj * 16 + kg * 4 + r;
        float v = acc[fj][fo][r] + bo;
        if (j == 0) v = 0.f;
        s1 += v; s2 += v * v;
        Y[((size_t)b * outRS + j) * O + obase + olocal] = f2bf(v);
      }
    }
  }

  sRed[tx] = make_float2(s1, s2);
  __syncthreads();
  for (int s = 128; s > 0; s >>= 1) {
    if (tx < s) { sRed[tx].x += sRed[tx + s].x; sRed[tx].y += sRed[tx + s].y; }
    __syncthreads();
  }
  if (tx == 0) {
    atomicAdd(&statsAcc[b * 2],     sRed[0].x);
    atomicAdd(&statsAcc[b * 2 + 1], sRed[0].y);
  }
}

// ------- LN+ReLU in place on yT [B][129][512]; b from blockIdx --------------
__global__ __launch_bounds__(256)
void ln_relu_kernel(uint16_t* __restrict__ y, const float* __restrict__ statsAcc,
                    float count) {
  const int b    = blockIdx.x >> 2;
  const int part = blockIdx.x & 3;
  float s = statsAcc[b * 2], ss = statsAcc[b * 2 + 1];
  float mean = s / count;
  float var = fmaxf((ss - s * s / count) / (count - 1.0f), 0.f);
  float scale = 1.0f / (sqrtf(var) + 1e-5f);

  uint4* yb = (uint4*)y + (size_t)b * 8256;       // 129*64 uint4 per batch
  for (int i = part * 2064 + threadIdx.x; i < (part + 1) * 2064; i += 256) {
    int r = i >> 6;
    uint4 out;
    if (r == 128) {
      out = make_uint4(0, 0, 0, 0);
    } else {
      uint4 u = yb[i];
      float v[8]; unpack8(u, v);
      uint32_t rr[4];
      #pragma unroll
      for (int k = 0; k < 4; k++) {
        float a  = fmaxf((v[2 * k]     - mean) * scale, 0.f);
        float bb = fmaxf((v[2 * k + 1] - mean) * scale, 0.f);
        rr[k] = (uint32_t)f2bf(a) | ((uint32_t)f2bf(bb) << 16);
      }
      out = make_uint4(rr[0], rr[1], rr[2], rr[3]);
    }
    yb[i] = out;
  }
}

// ------ tail: layer-3 gemm (emb stays in LDS) + gate + softmax + pool + head
// One block per batch. emb[128j][256o] built in LDS in gate's swizzled layout.
__global__ __launch_bounds__(256, 2)
void tail_kernel(const uint16_t* __restrict__ W3,      // [256][1536]
                 const uint16_t* __restrict__ xT,      // y2T [B][129][512]
                 const int* __restrict__ idxg,
                 const float* __restrict__ b3,
                 const uint16_t* __restrict__ gw1b,    // [128][256] bf16
                 const float* __restrict__ gb1,
                 const float* __restrict__ gw2, const float* __restrict__ gb2,
                 const float* __restrict__ rw1, const float* __restrict__ rb1,
                 const float* __restrict__ rw2, const float* __restrict__ rb2,
                 const float* __restrict__ rw3, const float* __restrict__ rb3,
                 void* __restrict__ dout, const int* __restrict__ flag) {
  __shared__ __align__(16) uint16_t sEmbF[4][128][64];   // 64 KB; aliases sA/sB
  __shared__ float sBias[256];
  __shared__ int sIdx[384];
  __shared__ float sRedG[4][128];
  __shared__ float sSm[128];
  __shared__ float sAttn[128];
  __shared__ float sPool4[4 * 256];
  __shared__ __align__(16) float sC[512];
  __shared__ __align__(16) float sH1[128];
  __shared__ float sH2[64];

  uint16_t* sA = &sEmbF[0][0][0];          // 256*64 shorts = 32 KB
  uint16_t* sB = sA + 256 * 64;            // 128*64 shorts = 16 KB

  const int b  = blockIdx.x;
  const int tx = threadIdx.x;
  const int wave = tx >> 6, lane = tx & 63;
  const int wj = wave & 1, wo = wave >> 1;
  const int lm = lane & 15, kg = lane >> 4;
  const int srow = lane >> 3, schk = lane & 7;
  const int Kpad = 1536, Cpad = 512;

  for (int t = tx; t < N3_; t += 256) sIdx[t] = idxg[(size_t)b * N3_ + t];
  sBias[tx] = b3[tx];
  __syncthreads();

  const uint16_t* Bbase = xT + (size_t)b * 129 * Cpad;

  // ---- phase 1: layer-3 GEMM (128j x 256o), acc in regs ----
  f32x4 zero4 = {0.f, 0.f, 0.f, 0.f};
  f32x4 acc[4][8];
  #pragma unroll
  for (int i = 0; i < 4; i++)
    #pragma unroll
    for (int j = 0; j < 8; j++) acc[i][j] = zero4;

  for (int reg = 0; reg < 3; reg++) {
    int ridx[4];
    #pragma unroll
    for (int i = 0; i < 4; i++) {
      int r = i * 32 + wave * 8 + srow;
      ridx[i] = (r == 0) ? 128 : sIdx[3 * (r - 1) + reg];
    }
    for (int co = 0; co < Cpad; co += 64) {
      __syncthreads();
      #pragma unroll
      for (int i = 0; i < 8; i++) {
        int r  = i * 32 + wave * 8 + srow;
        int ca = schk ^ (r & 7);
        ldsload16(W3 + (size_t)r * Kpad + reg * Cpad + co + ca * 8,
                  &sA[(i * 32 + wave * 8) * 64]);
      }
      #pragma unroll
      for (int i = 0; i < 4; i++) {
        int r  = i * 32 + wave * 8 + srow;
        int ca = schk ^ (r & 7);
        ldsload16(Bbase + (size_t)ridx[i] * Cpad + co + ca * 8,
                  &sB[(i * 32 + wave * 8) * 64]);
      }
      __syncthreads();
      #pragma unroll
      for (int s = 0; s < 2; s++) {
        bf16x8 xv[4], wv[8];
        #pragma unroll
        for (int f = 0; f < 4; f++) {
          int rj = wj * 64 + f * 16 + lm;
          int cj = (s * 4 + kg) ^ (rj & 7);
          xv[f] = *(const bf16x8*)&sB[rj * 64 + cj * 8];
        }
        #pragma unroll
        for (int f = 0; f < 8; f++) {
          int ro = wo * 128 + f * 16 + lm;
          int cw = (s * 4 + kg) ^ (ro & 7);
          wv[f] = *(const bf16x8*)&sA[ro * 64 + cw * 8];
        }
        #pragma unroll
        for (int fj = 0; fj < 4; fj++)
          #pragma unroll
          for (int fo = 0; fo < 8; fo++)
            acc[fj][fo] = __builtin_amdgcn_mfma_f32_16x16x32_bf16(xv[fj], wv[fo], acc[fj][fo], 0, 0, 0);
      }
    }
  }

  // ---- phase 2: epilogue -> LDS emb in swizzled layout ----
  __syncthreads();   // sA/sB dead; reuse as sEmbF
  #pragma unroll
  for (int fj = 0; fj < 4; fj++) {
    #pragma unroll
    for (int fo = 0; fo < 8; fo++) {
      int olocal = wo * 128 + fo * 16 + lm;
      int sec = olocal >> 6, oc = olocal & 63;
      float bo = sBias[olocal];
      #pragma unroll
      for (int r = 0; r < 4; r++) {
        int j = wj * 64 + fj * 16 + kg * 4 + r;
        float v = acc[fj][fo][r] + bo;
        if (j == 0) v = 0.f;
        int chunk = (oc >> 3) ^ (j & 7);
        sEmbF[sec][j][chunk * 8 + (oc & 7)] = f2bf(v);
      }
    }
  }
  __syncthreads();

  // ---- phase 3: gate1 MFMA from LDS emb ----
  const int h0 = wave * 32;
  f32x4 acc2[2][8];
  #pragma unroll
  for (int i = 0; i < 2; i++)
    #pragma unroll
    for (int t = 0; t < 8; t++) acc2[i][t] = zero4;

  #pragma unroll
  for (int s4 = 0; s4 < 4; s4++) {
    #pragma unroll
    for (int s = 0; s < 2; s++) {
      bf16x8 a0 = *(const bf16x8*)(gw1b + (size_t)(h0 + lm) * 256 + s4 * 64 + s * 32 + kg * 8);
      bf16x8 a1 = *(const bf16x8*)(gw1b + (size_t)(h0 + 16 + lm) * 256 + s4 * 64 + s * 32 + kg * 8);
      #pragma unroll
      for (int t = 0; t < 8; t++) {
        int rn = t * 16 + lm;
        int cn = (s * 4 + kg) ^ (rn & 7);
        bf16x8 bv = *(const bf16x8*)&sEmbF[s4][rn][cn * 8];
        acc2[0][t] = __builtin_amdgcn_mfma_f32_16x16x32_bf16(a0, bv, acc2[0][t], 0, 0, 0);
        acc2[1][t] = __builtin_amdgcn_mfma_f32_16x16x32_bf16(a1, bv, acc2[1][t], 0, 0, 0);
      }
    }
  }

  float gb[2][4], gv[2][4];
  #pragma unroll
  for (int ht = 0; ht < 2; ht++)
    #pragma unroll
    for (int r = 0; r < 4; r++) {
      int h = h0 + ht * 16 + kg * 4 + r;
      gb[ht][r] = gb1[h]; gv[ht][r] = gw2[h];
    }
  float p[8];
  #pragma unroll
  for (int t = 0; t < 8; t++) {
    float s = 0.f;
    #pragma unroll
    for (int ht = 0; ht < 2; ht++)
      #pragma unroll
      for (int r = 0; r < 4; r++)
        s += fmaxf(acc2[ht][t][r] + gb[ht][r], 0.f) * gv[ht][r];
    s += __shfl_xor(s, 16);
    s += __shfl_xor(s, 32);
    p[t] = s;
  }
  if (lane < 16) {
    #pragma unroll
    for (int t = 0; t < 8; t++) sRedG[wave][t * 16 + lane] = p[t];
  }
  __syncthreads();

  // ---- softmax over m ----
  float e = 0.f;
  if (tx < 128) {
    float v = sRedG[0][tx] + sRedG[1][tx] + sRedG[2][tx] + sRedG[3][tx] + gb2[0];
    sSm[tx] = v;
    sAttn[tx] = v;
  }
  __syncthreads();
  for (int s = 64; s > 0; s >>= 1) {
    if (tx < s) sSm[tx] = fmaxf(sSm[tx], sSm[tx + s]);
    __syncthreads();
  }
  float mx = sSm[0];
  __syncthreads();
  if (tx < 128) { e = expf(sAttn[tx] - mx); sSm[tx] = e; }
  __syncthreads();
  for (int s = 64; s > 0; s >>= 1) {
    if (tx < s) sSm[tx] += sSm[tx + s];
    __syncthreads();
  }
  float denom = sSm[0];
  __syncthreads();
  if (tx < 128) sAttn[tx] = e / denom;
  __syncthreads();

  // ---- pool from LDS emb: wave covers 32 m rows; lane -> f pairs ----
  {
    const int f0 = 2 * lane;           // 0..126
    const int sec0 = f0 >> 6, oc0 = f0 & 63;
    const int sec2 = sec0 + 2;         // f+128
    float pl00 = 0.f, pl01 = 0.f, pl10 = 0.f, pl11 = 0.f;
    const int mw = wave * 32;
    for (int mi = 0; mi < 32; mi++) {
      int m = mw + mi;
      float a = sAttn[m];
      int idx = ((oc0 >> 3) ^ (m & 7)) * 8 + (oc0 & 7);
      uint32_t u0 = *(const uint32_t*)&sEmbF[sec0][m][idx];
      uint32_t u1 = *(const uint32_t*)&sEmbF[sec2][m][idx];
      pl00 = fmaf(a, bf2f(u0 & 0xffffu), pl00);
      pl01 = fmaf(a, bf2f(u0 >> 16),     pl01);
      pl10 = fmaf(a, bf2f(u1 & 0xffffu), pl10);
      pl11 = fmaf(a, bf2f(u1 >> 16),     pl11);
    }
    sPool4[wave * 256 + lane * 2]           = pl00;
    sPool4[wave * 256 + lane * 2 + 1]       = pl01;
    sPool4[wave * 256 + 128 + lane * 2]     = pl10;
    sPool4[wave * 256 + 128 + lane * 2 + 1] = pl11;
  }
  __syncthreads();

  float pool = sPool4[tx] + sPool4[256 + tx] + sPool4[512 + tx] + sPool4[768 + tx];
  // root = emb[m=1][f=tx]
  float root;
  {
    int sec = tx >> 6, oc = tx & 63;
    int idx = ((oc >> 3) ^ 1) * 8 + (oc & 7);
    root = bf2f(sEmbF[sec][1][idx]);
  }
  sC[tx]       = root;
  sC[256 + tx] = pool;

  const int isf32 = (*flag != 0);
  if (!isf32) {
    uint16_t* o = ((uint16_t*)dout) + 512;
    o[b * 512 + tx]       = f2bf(root);
    o[b * 512 + 256 + tx] = f2bf(pool);
  } else {
    float* o = ((float*)dout) + 512;
    o[b * 512 + tx]       = root;
    o[b * 512 + 256 + tx] = pool;
  }
  __syncthreads();

  // ---- fused MLP head ----
  if (tx < 128) {
    float a = rb1[tx];
    const float4* wr = (const float4*)(rw1 + (size_t)tx * 512);
    for (int i = 0; i < 128; i++) {
      float4 w4 = wr[i];
      float4 c4 = *(const float4*)&sC[i * 4];
      a = fmaf(w4.x, c4.x, a); a = fmaf(w4.y, c4.y, a);
      a = fmaf(w4.z, c4.z, a); a = fmaf(w4.w, c4.w, a);
    }
    sH1[tx] = fmaxf(a, 0.f);
  }
  __syncthreads();
  if (tx < 64) {
    float a2 = rb2[tx];
    const float4* wr2 = (const float4*)(rw2 + (size_t)tx * 128);
    for (int i = 0; i < 32; i++) {
      float4 w4 = wr2[i];
      float4 h4 = *(const float4*)&sH1[i * 4];
      a2 = fmaf(w4.x, h4.x, a2); a2 = fmaf(w4.y, h4.y, a2);
      a2 = fmaf(w4.z, h4.z, a2); a2 = fmaf(w4.w, h4.w, a2);
    }
    sH2[tx] = fmaxf(a2, 0.f);
  }
  __syncthreads();
  if (tx < 64) {
    float pv = sH2[tx] * rw3[tx];
    for (int off = 32; off > 0; off >>= 1) pv += __shfl_down(pv, off);
    if (tx == 0) {
      float o = pv + rb3[0];
      if (!isf32) ((uint16_t*)dout)[b] = f2bf(o);
      else        ((float*)dout)[b]    = o;
    }
  }
}

// ---------------- launch -----------------------------------------------------
extern "C" void kernel_launch(void* const* d_in, const int* in_sizes, int n_in,
                              void* d_out, int out_size, void* d_ws, size_t ws_size,
                              hipStream_t stream) {
  const void* trees   = d_in[0];
  const int*  indexes = (const int*)d_in[1];

  char* ws = (char*)d_ws;
  size_t off = 0;
  auto alloc = [&](size_t bytes) -> char* {
    char* p = ws + off;
    off += (bytes + 255) & ~(size_t)255;
    return p;
  };

  int*   flagp    = (int*)alloc(256);
  float* statsAcc = (float*)alloc(4 * B_ * sizeof(float));
  float* b1f = (float*)alloc(512 * 4);
  float* b2f = (float*)alloc(512 * 4);
  float* b3f = (float*)alloc(256 * 4);
  float* gb1f = (float*)alloc(128 * 4);
  float* gw2f = (float*)alloc(128 * 4);
  float* gb2f = (float*)alloc(4);
  float* rw1f = (float*)alloc(128 * 512 * 4);
  float* rb1f = (float*)alloc(128 * 4);
  float* rw2f = (float*)alloc(64 * 128 * 4);
  float* rb2f = (float*)alloc(64 * 4);
  float* rw3f = (float*)alloc(64 * 4);
  float* rb3f = (float*)alloc(4);
  uint16_t* W1b  = (uint16_t*)alloc((size_t)512 * 768 * 2);
  uint16_t* W2b  = (uint16_t*)alloc((size_t)512 * 1536 * 2);
  uint16_t* W3b  = (uint16_t*)alloc((size_t)256 * 1536 * 2);
  uint16_t* GW1b = (uint16_t*)alloc((size_t)128 * 256 * 2);
  uint16_t* bufA = (uint16_t*)alloc((size_t)B_ * 129 * 512 * 2);   // y1T
  uint16_t* bufB = (uint16_t*)alloc((size_t)B_ * 129 * 512 * 2);   // treesT, later y2T

  uint16_t* treesT = bufB;            // [B][129][256]
  uint16_t* y1T    = bufA;            // [B][129][512]
  uint16_t* y2T    = bufB;            // [B][129][512]

  PrepArgs pa;
  pa.trees = trees;
  pa.w1 = d_in[2];  pa.b1 = d_in[3];
  pa.w2 = d_in[4];  pa.b2 = d_in[5];
  pa.w3 = d_in[6];  pa.b3 = d_in[7];
  pa.gw1 = d_in[8]; pa.gb1 = d_in[9];
  pa.gw2 = d_in[10]; pa.gb2 = d_in[11];
  pa.rw1 = d_in[12]; pa.rb1 = d_in[13];
  pa.rw2 = d_in[14]; pa.rb2 = d_in[15];
  pa.rw3 = d_in[16]; pa.rb3 = d_in[17];
  pa.treesT = treesT; pa.W1b = W1b; pa.W2b = W2b; pa.W3b = W3b; pa.GW1b = GW1b;
  pa.b1f = b1f; pa.b2f = b2f; pa.b3f = b3f; pa.gb1f = gb1f; pa.gw2f = gw2f; pa.gb2f = gb2f;
  pa.rw1f = rw1f; pa.rb1f = rb1f; pa.rw2f = rw2f; pa.rb2f = rb2f; pa.rw3f = rw3f; pa.rb3f = rb3f;
  pa.flagp = flagp; pa.statsAcc = statsAcc;

  prep_kernel<<<PREP_F32_END, 256, 0, stream>>>(pa);

  // ---- layer 1: Cpad=256 (K=768), in treesT, out y1T ----
  gemm_kernel<<<2 * B_, 256, 0, stream>>>(
      W1b, treesT, indexes, b1f, y1T, 2, 256, 129, statsAcc);
  ln_relu_kernel<<<4 * B_, 256, 0, stream>>>(y1T, statsAcc, 65536.f);

  // ---- layer 2: Cpad=512 (K=1536), in y1T, out y2T ----
  gemm_kernel<<<2 * B_, 256, 0, stream>>>(
      W2b, y1T, indexes, b2f, y2T, 2, 512, 129, statsAcc + 2 * B_);
  ln_relu_kernel<<<4 * B_, 256, 0, stream>>>(y2T, statsAcc + 2 * B_, 65536.f);

  // ---- layer 3 + gate + pool + head fused (emb stays in LDS) ----
  tail_kernel<<<B_, 256, 0, stream>>>(W3b, y2T, indexes, b3f,
                                      GW1b, gb1f, gw2f, gb2f,
                                      rw1f, rb1f, rw2f, rb2f, rw3f, rb3f,
                                      d_out, flagp);

  (void)in_sizes; (void)n_in; (void)out_size; (void)ws_size;
}